// Round 1
// baseline (1297.878 us; speedup 1.0000x reference)
//
#include <hip/hip_runtime.h>
#include <hip/hip_bf16.h>

// Problem constants
constexpr int N_ = 50000;
constexpr int D_ = 128;
constexpr int E_ = 800000;
constexpr int P_ = 9;
constexpr int L_ = 3;
constexpr float EPS_ = 1e-5f;

constexpr int TM = 64;   // rows per GEMM block
constexpr int BK = 32;   // K chunk

// ---------------------------------------------------------------------------
// Setup kernels
// ---------------------------------------------------------------------------

__global__ void node_init(const int* __restrict__ ring, int* __restrict__ pol,
                          int* __restrict__ bcnt) {
    int n = blockIdx.x * 256 + threadIdx.x;
    if (n >= N_) return;
    int p = ring[n] % P_;
    pol[n] = p;
    atomicAdd(&bcnt[p], 1);
}

__global__ void edge_count(const int* __restrict__ ei, int* __restrict__ degS,
                           int* __restrict__ cntT) {
    int e = blockIdx.x * 256 + threadIdx.x;
    if (e >= E_) return;
    atomicAdd(&degS[ei[e]], 1);        // src (deg is over src in the reference)
    atomicAdd(&cntT[ei[E_ + e]], 1);   // tgt
}

// single-block exclusive scan of cntT -> offT; also bucket offsets + tile offsets
__global__ void scan_kernel(const int* __restrict__ cnt, int* __restrict__ off,
                            const int* __restrict__ bcnt, int* __restrict__ boff,
                            int* __restrict__ tileOff) {
    __shared__ int wsum[16];
    __shared__ int carry_s;
    int tid = threadIdx.x;
    int lane = tid & 63, wid = tid >> 6;
    if (tid == 0) carry_s = 0;
    __syncthreads();
    for (int base = 0; base < N_; base += 1024) {
        int idx = base + tid;
        int v = (idx < N_) ? cnt[idx] : 0;
        int inc = v;
#pragma unroll
        for (int o = 1; o < 64; o <<= 1) {
            int t = __shfl_up(inc, o, 64);
            if (lane >= o) inc += t;
        }
        if (lane == 63) wsum[wid] = inc;
        __syncthreads();
        if (tid < 16) {
            int s = wsum[tid];
#pragma unroll
            for (int o = 1; o < 16; o <<= 1) {
                int t = __shfl_up(s, o, 64);
                if (tid >= o) s += t;
            }
            wsum[tid] = s;  // inclusive over waves
        }
        __syncthreads();
        int wexcl = (wid == 0) ? 0 : wsum[wid - 1];
        int carry = carry_s;
        if (idx < N_) off[idx] = carry + wexcl + inc - v;  // exclusive
        __syncthreads();
        if (tid == 1023) carry_s = carry + wsum[15];
        __syncthreads();
    }
    if (tid == 0) {
        off[N_] = carry_s;
        boff[0] = 0;
        tileOff[0] = 0;
        for (int p = 0; p < P_; ++p) {
            boff[p + 1] = boff[p] + bcnt[p];
            tileOff[p + 1] = tileOff[p] + (bcnt[p] + TM - 1) / TM;
        }
    }
}

__global__ void fill_edges(const int* __restrict__ ei, const int* __restrict__ offT,
                           int* __restrict__ curT, int* __restrict__ eSrc) {
    int e = blockIdx.x * 256 + threadIdx.x;
    if (e >= E_) return;
    int t = ei[E_ + e];
    int pos = atomicAdd(&curT[t], 1);
    eSrc[offT[t] + pos] = ei[e];
}

__global__ void bucket_dnorm(const int* __restrict__ pol, const int* __restrict__ boff,
                             int* __restrict__ bcur, int* __restrict__ blist,
                             const int* __restrict__ degS, float* __restrict__ dnorm) {
    int n = blockIdx.x * 256 + threadIdx.x;
    if (n >= N_) return;
    int p = pol[n];
    int pos = atomicAdd(&bcur[p], 1);
    blist[boff[p] + pos] = n;
    int dg = degS[n];
    dnorm[n] = 1.f / (float)(dg > 1 ? dg : 1);
}

// ---------------------------------------------------------------------------
// Small per-layer matrix precompute:
//   T1[p][i][k] = sum_j (R+dR)[p][i][j] * W1[k][j]
//   Dm[p][d][k] = sum_i Wr[i][d] * T1[p][i][k]
// so that  t_pre = agg0 @ Dm[pol]  ==  ((agg0 @ Wr.T) @ (R+dR)[pol]) @ W1.T
// ---------------------------------------------------------------------------

__global__ void small_gemm1(const float* __restrict__ Rm, const float* __restrict__ dRm,
                            const float* __restrict__ W1, float* __restrict__ T1) {
    int idx = blockIdx.x * 256 + threadIdx.x;  // P*D*D threads
    int p = idx / (D_ * D_);
    int rem = idx % (D_ * D_);
    int i = rem / D_, k = rem % D_;
    const float* a = Rm + ((size_t)p * D_ + i) * D_;
    const float* a2 = dRm + ((size_t)p * D_ + i) * D_;
    const float* w = W1 + (size_t)k * D_;
    float acc = 0.f;
#pragma unroll 8
    for (int j = 0; j < D_; ++j) acc += (a[j] + a2[j]) * w[j];
    T1[idx] = acc;
}

__global__ void small_gemm2(const float* __restrict__ Wr, const float* __restrict__ T1,
                            float* __restrict__ Dm) {
    int idx = blockIdx.x * 256 + threadIdx.x;  // P*D*D threads
    int p = idx / (D_ * D_);
    int rem = idx % (D_ * D_);
    int d = rem / D_, k = rem % D_;
    const float* t = T1 + (size_t)p * D_ * D_;
    float acc = 0.f;
#pragma unroll 8
    for (int i = 0; i < D_; ++i) acc += Wr[i * D_ + d] * t[i * D_ + k];
    Dm[idx] = acc;
}

// ---------------------------------------------------------------------------
// CSR aggregation: agg[n] = sum over incoming edges of xt[src]
// one wave per node, 2 floats per lane
// ---------------------------------------------------------------------------

__global__ __launch_bounds__(256) void aggregate(const float* __restrict__ xt,
                                                 const int* __restrict__ offT,
                                                 const int* __restrict__ eSrc,
                                                 float* __restrict__ agg) {
    int n = blockIdx.x * 4 + (threadIdx.x >> 6);
    if (n >= N_) return;
    int lane = threadIdx.x & 63;
    int beg = offT[n], end = offT[n + 1];
    float ax = 0.f, ay = 0.f;
    int i = beg;
    for (; i + 1 < end; i += 2) {
        int s0 = eSrc[i], s1 = eSrc[i + 1];
        float2 v0 = ((const float2*)(xt + (size_t)s0 * D_))[lane];
        float2 v1 = ((const float2*)(xt + (size_t)s1 * D_))[lane];
        ax += v0.x + v1.x;
        ay += v0.y + v1.y;
    }
    if (i < end) {
        int s0 = eSrc[i];
        float2 v0 = ((const float2*)(xt + (size_t)s0 * D_))[lane];
        ax += v0.x;
        ay += v0.y;
    }
    float2 o;
    o.x = ax;
    o.y = ay;
    ((float2*)(agg + (size_t)n * D_))[lane] = o;
}

// ---------------------------------------------------------------------------
// Main tiled GEMM: 64 rows x 128 cols per block, 256 threads, 8x4 microtile.
// EPI 0: plain store (xt = X @ (S+dS)[p])
// EPI 1: t = dn*acc + b1; h = relu(LN(t; g,bb))                  [bucketed]
// EPI 2: v = rs*(acc + b2) + xres; o = LN(v; g,bb) (+x0 if last) [contiguous, B=W2 transposed]
// ---------------------------------------------------------------------------

template <int EPI, bool TRANSB, bool BUCKETED>
__global__ __launch_bounds__(256) void gemm_tile(
    const float* __restrict__ A, const float* __restrict__ B0,
    const float* __restrict__ B0b, float* __restrict__ Out,
    const int* __restrict__ blist, const int* __restrict__ boff,
    const int* __restrict__ tileOff, const float* __restrict__ dnorm,
    const float* __restrict__ bias, const float* __restrict__ g,
    const float* __restrict__ bbeta, const float* __restrict__ rs_ptr,
    const float* __restrict__ xres, const float* __restrict__ x0add) {
    constexpr int AS_LD = 66;                        // pad: 2-way bank alias max (free)
    constexpr int SMEM_MAIN = BK * AS_LD + 4224;     // A chunk + B chunk (both layouts 4224)
    constexpr int SMEM_TS = TM * 130;                // LN staging tile
    constexpr int SMEM_SZ = (EPI == 0) ? SMEM_MAIN : (SMEM_MAIN > SMEM_TS ? SMEM_MAIN : SMEM_TS);
    __shared__ float smem[SMEM_SZ];
    __shared__ int rid[TM];
    __shared__ float mrow[TM], rrow[TM];

    float* sA = smem;             // [BK][AS_LD], sA[k][r]
    float* sB = smem + BK * AS_LD;

    int tid = threadIdx.x;
    int b = blockIdx.x;

    int pp = 0, nrows, rowbase;
    if constexpr (BUCKETED) {
        if (b >= tileOff[P_]) return;
        while (pp < P_ - 1 && b >= tileOff[pp + 1]) ++pp;
        int tileBase = b - tileOff[pp];
        int cntp = boff[pp + 1] - boff[pp];
        int start = tileBase * TM;
        nrows = min(TM, cntp - start);
        rowbase = boff[pp] + start;
    } else {
        int start = b * TM;
        nrows = min(TM, N_ - start);
        rowbase = start;
    }
    const float* B = B0 + (BUCKETED ? (size_t)pp * D_ * D_ : 0);
    const float* Bb = (B0b != nullptr) ? (B0b + (BUCKETED ? (size_t)pp * D_ * D_ : 0)) : nullptr;

    if (tid < TM) {
        int r = -1;
        if (tid < nrows) r = BUCKETED ? blist[rowbase + tid] : (rowbase + tid);
        rid[tid] = r;
    }
    __syncthreads();

    int m = tid & 31, rg = tid >> 5;

    // staging rows for this thread (A-load): rows rg + 8*i, col m of each chunk
    int arow[8];
#pragma unroll
    for (int i = 0; i < 8; ++i) arow[i] = rid[rg + 8 * i];

    float acc[8][4];
#pragma unroll
    for (int i = 0; i < 8; ++i)
#pragma unroll
        for (int j = 0; j < 4; ++j) acc[i][j] = 0.f;

    for (int kc = 0; kc < D_; kc += BK) {
        // A stage: sA[k][r] = A[row(r)][kc+k]
#pragma unroll
        for (int i = 0; i < 8; ++i) {
            int row = arow[i];
            sA[m * AS_LD + rg + 8 * i] = (row >= 0) ? A[(size_t)row * D_ + kc + m] : 0.f;
        }
        // B stage
        if constexpr (!TRANSB) {
#pragma unroll
            for (int i = 0; i < 16; ++i) {
                int e = tid + i * 256;
                int k = e >> 7, c = e & 127;
                size_t be = (size_t)(kc + k) * D_ + c;
                float v = B[be];
                if (Bb) v += Bb[be];
                sB[k * 132 + c] = v;
            }
        } else {
#pragma unroll
            for (int i = 0; i < 16; ++i) {
                int e = tid + i * 256;
                int c = e >> 5, k = e & 31;
                sB[c * 33 + k] = B[(size_t)c * D_ + kc + k];  // B[k][c] = W2[c][k]
            }
        }
        __syncthreads();
#pragma unroll 4
        for (int k = 0; k < BK; ++k) {
            float a[8];
            const float2* ap = (const float2*)&sA[k * AS_LD + rg * 8];
            float2 a0 = ap[0], a1 = ap[1], a2 = ap[2], a3 = ap[3];
            a[0] = a0.x; a[1] = a0.y; a[2] = a1.x; a[3] = a1.y;
            a[4] = a2.x; a[5] = a2.y; a[6] = a3.x; a[7] = a3.y;
            float bv[4];
            if constexpr (!TRANSB) {
                float4 b4 = *(const float4*)&sB[k * 132 + 4 * m];
                bv[0] = b4.x; bv[1] = b4.y; bv[2] = b4.z; bv[3] = b4.w;
            } else {
#pragma unroll
                for (int j = 0; j < 4; ++j) bv[j] = sB[(m + 32 * j) * 33 + k];
            }
#pragma unroll
            for (int i = 0; i < 8; ++i)
#pragma unroll
                for (int j = 0; j < 4; ++j) acc[i][j] += a[i] * bv[j];
        }
        __syncthreads();
    }

    if constexpr (EPI == 0) {
#pragma unroll
        for (int i = 0; i < 8; ++i) {
            int row = rid[rg * 8 + i];
            if (row < 0) continue;
            float4 v;
            v.x = acc[i][0]; v.y = acc[i][1]; v.z = acc[i][2]; v.w = acc[i][3];
            *(float4*)&Out[(size_t)row * D_ + 4 * m] = v;
        }
        return;
    }

    // EPI 1/2: stage pre-LN tile in LDS, row stats, normalize, store
    float* Ts = smem;  // [TM][130]
    float bias_j[4], g_j[4], bb_j[4];
#pragma unroll
    for (int j = 0; j < 4; ++j) {
        int c = TRANSB ? (m + 32 * j) : (4 * m + j);
        bias_j[j] = bias[c];
        g_j[j] = g[c];
        bb_j[j] = bbeta[c];
    }
    float rs = (EPI == 2) ? *rs_ptr : 0.f;

#pragma unroll
    for (int i = 0; i < 8; ++i) {
        int r = rg * 8 + i;
        int row = rid[r];
        float pre[4];
        if constexpr (EPI == 1) {
            float dn = (row >= 0) ? dnorm[row] : 1.f;
#pragma unroll
            for (int j = 0; j < 4; ++j) pre[j] = dn * acc[i][j] + bias_j[j];
            // contiguous cols: two float2 stores
            float2 p0, p1;
            p0.x = pre[0]; p0.y = pre[1]; p1.x = pre[2]; p1.y = pre[3];
            *(float2*)&Ts[r * 130 + 4 * m] = p0;
            *(float2*)&Ts[r * 130 + 4 * m + 2] = p1;
        } else {
#pragma unroll
            for (int j = 0; j < 4; ++j) {
                int c = m + 32 * j;  // EPI2 is TRANSB
                float xr = (row >= 0) ? xres[(size_t)row * D_ + c] : 0.f;
                pre[j] = rs * (acc[i][j] + bias_j[j]) + xr;
                Ts[r * 130 + c] = pre[j];
            }
        }
    }
    __syncthreads();
    if (tid < TM) {
        float s1 = 0.f;
#pragma unroll 8
        for (int c = 0; c < D_; ++c) s1 += Ts[tid * 130 + c];
        float mm = s1 * (1.f / D_);
        float s2 = 0.f;
#pragma unroll 8
        for (int c = 0; c < D_; ++c) {
            float dl = Ts[tid * 130 + c] - mm;
            s2 += dl * dl;
        }
        mrow[tid] = mm;
        rrow[tid] = rsqrtf(s2 * (1.f / D_) + EPS_);
    }
    __syncthreads();
#pragma unroll
    for (int i = 0; i < 8; ++i) {
        int r = rg * 8 + i;
        int row = rid[r];
        if (row < 0) continue;
        float mm = mrow[r], rr = rrow[r];
        if constexpr (EPI == 1) {
            float vv[4];
#pragma unroll
            for (int j = 0; j < 4; ++j) {
                float v = Ts[r * 130 + 4 * m + j];
                float nv = (v - mm) * rr * g_j[j] + bb_j[j];
                vv[j] = fmaxf(nv, 0.f);
            }
            float4 o;
            o.x = vv[0]; o.y = vv[1]; o.z = vv[2]; o.w = vv[3];
            *(float4*)&Out[(size_t)row * D_ + 4 * m] = o;
        } else {
#pragma unroll
            for (int j = 0; j < 4; ++j) {
                int c = m + 32 * j;
                float v = Ts[r * 130 + c];
                float nv = (v - mm) * rr * g_j[j] + bb_j[j];
                if (x0add) nv += x0add[(size_t)row * D_ + c];
                Out[(size_t)row * D_ + c] = nv;
            }
        }
    }
}

// ---------------------------------------------------------------------------
// Host launch
// ---------------------------------------------------------------------------

extern "C" void kernel_launch(void* const* d_in, const int* in_sizes, int n_in,
                              void* d_out, int out_size, void* d_ws, size_t ws_size,
                              hipStream_t stream) {
    const float* x0 = (const float*)d_in[0];
    const int* ei = (const int*)d_in[1];
    const int* ring = (const int*)d_in[2];
    const float* Wr = (const float*)d_in[3];
    const float* S = (const float*)d_in[4];
    const float* dS = (const float*)d_in[5];
    const float* R = (const float*)d_in[6];
    const float* dR = (const float*)d_in[7];
    const float* rsc = (const float*)d_in[8];
    const float* W1 = (const float*)d_in[9];
    const float* b1 = (const float*)d_in[10];
    const float* lng = (const float*)d_in[11];
    const float* lnb = (const float*)d_in[12];
    const float* W2 = (const float*)d_in[13];
    const float* b2 = (const float*)d_in[14];
    const float* ng = (const float*)d_in[15];
    const float* nb = (const float*)d_in[16];
    float* out = (float*)d_out;

    char* w = (char*)d_ws;
    auto alloc = [&](size_t bytes) {
        char* p = w;
        w += (bytes + 15) & ~(size_t)15;
        return p;
    };
    float* xbuf = (float*)alloc((size_t)N_ * D_ * 4);
    float* bufA = (float*)alloc((size_t)N_ * D_ * 4);  // xt, then h
    float* bufB = (float*)alloc((size_t)N_ * D_ * 4);  // agg0
    float* T1 = (float*)alloc((size_t)P_ * D_ * D_ * 4);
    float* Dm = (float*)alloc((size_t)P_ * D_ * D_ * 4);
    float* dnorm = (float*)alloc((size_t)N_ * 4);
    // contiguous zero region: degS,cntT,curT,bcnt,bcur
    int* degS = (int*)alloc((size_t)(3 * N_ + 2 * P_) * 4);
    int* cntT = degS + N_;
    int* curT = cntT + N_;
    int* bcnt = curT + N_;
    int* bcur = bcnt + P_;
    int* pol = (int*)alloc((size_t)N_ * 4);
    int* offT = (int*)alloc((size_t)(N_ + 1) * 4);
    int* eSrc = (int*)alloc((size_t)E_ * 4);
    int* boff = (int*)alloc((size_t)(P_ + 1) * 4);
    int* tileOff = (int*)alloc((size_t)(P_ + 1) * 4);
    int* blist = (int*)alloc((size_t)N_ * 4);

    hipMemsetAsync(degS, 0, (size_t)(3 * N_ + 2 * P_) * 4, stream);

    const int NG = (N_ + 255) / 256;   // 196
    const int EG = (E_ + 255) / 256;   // 3125
    const int SG = P_ * D_ * D_ / 256; // 576
    const int BTILES = N_ / TM + P_;   // 791 (>= max bucketed tiles)
    const int CTILES = (N_ + TM - 1) / TM;  // 782

    node_init<<<NG, 256, 0, stream>>>(ring, pol, bcnt);
    edge_count<<<EG, 256, 0, stream>>>(ei, degS, cntT);
    scan_kernel<<<1, 1024, 0, stream>>>(cntT, offT, bcnt, boff, tileOff);
    fill_edges<<<EG, 256, 0, stream>>>(ei, offT, curT, eSrc);
    bucket_dnorm<<<NG, 256, 0, stream>>>(pol, boff, bcur, blist, degS, dnorm);

    const float* xs = x0;
    for (int l = 0; l < L_; ++l) {
        const size_t lPDD = (size_t)l * P_ * D_ * D_;
        const size_t lDD = (size_t)l * D_ * D_;
        small_gemm1<<<SG, 256, 0, stream>>>(R + lPDD, dR + lPDD, W1 + lDD, T1);
        small_gemm2<<<SG, 256, 0, stream>>>(Wr + lDD, T1, Dm);
        // xt = X @ (S+dS)[pol]
        gemm_tile<0, false, true><<<BTILES, 256, 0, stream>>>(
            xs, S + lPDD, dS + lPDD, bufA, blist, boff, tileOff,
            nullptr, nullptr, nullptr, nullptr, nullptr, nullptr, nullptr);
        // agg0 = CSR-sum of xt
        aggregate<<<N_ / 4, 256, 0, stream>>>(bufA, offT, eSrc, bufB);
        // h = relu(LN(dn * (agg0 @ Dm[pol]) + b1))
        gemm_tile<1, false, true><<<BTILES, 256, 0, stream>>>(
            bufB, Dm, nullptr, bufA, blist, boff, tileOff,
            dnorm, b1 + (size_t)l * D_, lng + (size_t)l * D_, lnb + (size_t)l * D_,
            nullptr, nullptr, nullptr);
        // x_next = LN(rs*(h @ W2.T + b2) + x)  (+x0 on last layer -> d_out)
        float* xo = (l == L_ - 1) ? out : xbuf;
        gemm_tile<2, true, false><<<CTILES, 256, 0, stream>>>(
            bufA, W2 + lDD, nullptr, xo, nullptr, nullptr, nullptr,
            nullptr, b2 + (size_t)l * D_, ng + (size_t)l * D_, nb + (size_t)l * D_,
            rsc + l, xs, (l == L_ - 1) ? x0 : nullptr);
        xs = xbuf;
    }
}

// Round 2
// 919.973 us; speedup vs baseline: 1.4108x; 1.4108x over previous
//
#include <hip/hip_runtime.h>
#include <hip/hip_bf16.h>

// Problem constants
constexpr int N_ = 50000;
constexpr int D_ = 128;
constexpr int E_ = 800000;
constexpr int P_ = 9;
constexpr int L_ = 3;
constexpr float EPS_ = 1e-5f;

constexpr int TM = 64;   // rows per GEMM block
constexpr int BK = 32;   // K chunk
constexpr int NB = (N_ + 1023) / 1024;  // scan blocks = 49

// ---------------------------------------------------------------------------
// Setup kernels
// ---------------------------------------------------------------------------

// pol + per-polarity counts via LDS histogram (avoids 50k same-address atomics)
__global__ __launch_bounds__(256) void node_init(const int* __restrict__ ring,
                                                 int* __restrict__ pol,
                                                 int* __restrict__ bcnt) {
    __shared__ int h[P_];
    int tid = threadIdx.x;
    if (tid < P_) h[tid] = 0;
    __syncthreads();
    int n = blockIdx.x * 256 + tid;
    if (n < N_) {
        int p = ring[n] % P_;
        pol[n] = p;
        atomicAdd(&h[p], 1);
    }
    __syncthreads();
    if (tid < P_ && h[tid] > 0) atomicAdd(&bcnt[tid], h[tid]);
}

__global__ void edge_count(const int* __restrict__ ei, int* __restrict__ degS,
                           int* __restrict__ cntT) {
    int e = blockIdx.x * 256 + threadIdx.x;
    if (e >= E_) return;
    atomicAdd(&degS[ei[e]], 1);        // src (deg is over src in the reference)
    atomicAdd(&cntT[ei[E_ + e]], 1);   // tgt
}

// Multi-block exclusive scan of cnt -> off, 3 passes.
__global__ __launch_bounds__(1024) void scan1(const int* __restrict__ cnt,
                                              int* __restrict__ off,
                                              int* __restrict__ blkSum) {
    __shared__ int wsum[16];
    int tid = threadIdx.x, lane = tid & 63, wid = tid >> 6;
    int idx = blockIdx.x * 1024 + tid;
    int v = (idx < N_) ? cnt[idx] : 0;
    int inc = v;
#pragma unroll
    for (int o = 1; o < 64; o <<= 1) {
        int t = __shfl_up(inc, o, 64);
        if (lane >= o) inc += t;
    }
    if (lane == 63) wsum[wid] = inc;
    __syncthreads();
    if (tid < 16) {
        int s = wsum[tid];
#pragma unroll
        for (int o = 1; o < 16; o <<= 1) {
            int t = __shfl_up(s, o, 64);
            if (tid >= o) s += t;
        }
        wsum[tid] = s;  // inclusive over waves
    }
    __syncthreads();
    int wexcl = (wid == 0) ? 0 : wsum[wid - 1];
    if (idx < N_) off[idx] = wexcl + inc - v;  // exclusive within block
    if (tid == 1023) blkSum[blockIdx.x] = wsum[15];
}

__global__ void scan2(const int* __restrict__ blkSum, int* __restrict__ blkOff,
                      int* __restrict__ off, const int* __restrict__ bcnt,
                      int* __restrict__ boff, int* __restrict__ tileOff) {
    if (threadIdx.x != 0) return;
    int run = 0;
    for (int i = 0; i < NB; ++i) {
        blkOff[i] = run;
        run += blkSum[i];
    }
    off[N_] = run;
    boff[0] = 0;
    tileOff[0] = 0;
    for (int p = 0; p < P_; ++p) {
        boff[p + 1] = boff[p] + bcnt[p];
        tileOff[p + 1] = tileOff[p] + (bcnt[p] + TM - 1) / TM;
    }
}

__global__ __launch_bounds__(1024) void scan3(int* __restrict__ off,
                                              const int* __restrict__ blkOff) {
    int idx = blockIdx.x * 1024 + threadIdx.x;
    if (idx < N_) off[idx] += blkOff[blockIdx.x];
}

__global__ void fill_edges(const int* __restrict__ ei, const int* __restrict__ offT,
                           int* __restrict__ curT, int* __restrict__ eSrc) {
    int e = blockIdx.x * 256 + threadIdx.x;
    if (e >= E_) return;
    int t = ei[E_ + e];
    int pos = atomicAdd(&curT[t], 1);
    eSrc[offT[t] + pos] = ei[e];
}

// bucket list build: LDS histogram + one global atomic per (block, polarity)
__global__ __launch_bounds__(256) void bucket_dnorm(
    const int* __restrict__ pol, const int* __restrict__ boff,
    int* __restrict__ bcur, int* __restrict__ blist,
    const int* __restrict__ degS, float* __restrict__ dnorm) {
    __shared__ int h[P_];
    __shared__ int base[P_];
    int tid = threadIdx.x;
    if (tid < P_) h[tid] = 0;
    __syncthreads();
    int n = blockIdx.x * 256 + tid;
    int p = 0, loc = 0;
    bool act = (n < N_);
    if (act) {
        p = pol[n];
        loc = atomicAdd(&h[p], 1);  // position within this block for polarity p
        int dg = degS[n];
        dnorm[n] = 1.f / (float)(dg > 1 ? dg : 1);
    }
    __syncthreads();
    if (tid < P_ && h[tid] > 0) base[tid] = atomicAdd(&bcur[tid], h[tid]);
    __syncthreads();
    if (act) blist[boff[p] + base[p] + loc] = n;
}

// ---------------------------------------------------------------------------
// Small per-layer matrix precompute:
//   T1[p][i][k] = sum_j (R+dR)[p][i][j] * W1[k][j]
//   Dm[p][d][k] = sum_i Wr[i][d] * T1[p][i][k]
// so that  t_pre = agg0 @ Dm[pol]  ==  ((agg0 @ Wr.T) @ (R+dR)[pol]) @ W1.T
// ---------------------------------------------------------------------------

__global__ void small_gemm1(const float* __restrict__ Rm, const float* __restrict__ dRm,
                            const float* __restrict__ W1, float* __restrict__ T1) {
    int idx = blockIdx.x * 256 + threadIdx.x;  // P*D*D threads
    int p = idx / (D_ * D_);
    int rem = idx % (D_ * D_);
    int i = rem / D_, k = rem % D_;
    const float* a = Rm + ((size_t)p * D_ + i) * D_;
    const float* a2 = dRm + ((size_t)p * D_ + i) * D_;
    const float* w = W1 + (size_t)k * D_;
    float acc = 0.f;
#pragma unroll 8
    for (int j = 0; j < D_; ++j) acc += (a[j] + a2[j]) * w[j];
    T1[idx] = acc;
}

__global__ void small_gemm2(const float* __restrict__ Wr, const float* __restrict__ T1,
                            float* __restrict__ Dm) {
    int idx = blockIdx.x * 256 + threadIdx.x;  // P*D*D threads
    int p = idx / (D_ * D_);
    int rem = idx % (D_ * D_);
    int d = rem / D_, k = rem % D_;
    const float* t = T1 + (size_t)p * D_ * D_;
    float acc = 0.f;
#pragma unroll 8
    for (int i = 0; i < D_; ++i) acc += Wr[i * D_ + d] * t[i * D_ + k];
    Dm[idx] = acc;
}

// ---------------------------------------------------------------------------
// CSR aggregation: agg[n] = sum over incoming edges of xt[src]
// one wave per node, 2 floats per lane
// ---------------------------------------------------------------------------

__global__ __launch_bounds__(256) void aggregate(const float* __restrict__ xt,
                                                 const int* __restrict__ offT,
                                                 const int* __restrict__ eSrc,
                                                 float* __restrict__ agg) {
    int n = blockIdx.x * 4 + (threadIdx.x >> 6);
    if (n >= N_) return;
    int lane = threadIdx.x & 63;
    int beg = offT[n], end = offT[n + 1];
    float ax = 0.f, ay = 0.f;
    int i = beg;
    for (; i + 1 < end; i += 2) {
        int s0 = eSrc[i], s1 = eSrc[i + 1];
        float2 v0 = ((const float2*)(xt + (size_t)s0 * D_))[lane];
        float2 v1 = ((const float2*)(xt + (size_t)s1 * D_))[lane];
        ax += v0.x + v1.x;
        ay += v0.y + v1.y;
    }
    if (i < end) {
        int s0 = eSrc[i];
        float2 v0 = ((const float2*)(xt + (size_t)s0 * D_))[lane];
        ax += v0.x;
        ay += v0.y;
    }
    float2 o;
    o.x = ax;
    o.y = ay;
    ((float2*)(agg + (size_t)n * D_))[lane] = o;
}

// ---------------------------------------------------------------------------
// Main tiled GEMM: 64 rows x 128 cols per block, 256 threads, 8x4 microtile.
// EPI 0: plain store (xt = X @ (S+dS)[p])
// EPI 1: t = dn*acc + b1; h = relu(LN(t; g,bb))                  [bucketed]
// EPI 2: v = rs*(acc + b2) + xres; o = LN(v; g,bb) (+x0 if last) [contiguous, B=W2 transposed]
// ---------------------------------------------------------------------------

template <int EPI, bool TRANSB, bool BUCKETED>
__global__ __launch_bounds__(256) void gemm_tile(
    const float* __restrict__ A, const float* __restrict__ B0,
    const float* __restrict__ B0b, float* __restrict__ Out,
    const int* __restrict__ blist, const int* __restrict__ boff,
    const int* __restrict__ tileOff, const float* __restrict__ dnorm,
    const float* __restrict__ bias, const float* __restrict__ g,
    const float* __restrict__ bbeta, const float* __restrict__ rs_ptr,
    const float* __restrict__ xres, const float* __restrict__ x0add) {
    constexpr int AS_LD = 66;                        // pad: 2-way bank alias max (free)
    constexpr int SMEM_MAIN = BK * AS_LD + 4224;     // A chunk + B chunk (both layouts 4224)
    constexpr int SMEM_TS = TM * 130;                // LN staging tile
    constexpr int SMEM_SZ = (EPI == 0) ? SMEM_MAIN : (SMEM_MAIN > SMEM_TS ? SMEM_MAIN : SMEM_TS);
    __shared__ float smem[SMEM_SZ];
    __shared__ int rid[TM];
    __shared__ float mrow[TM], rrow[TM];

    float* sA = smem;             // [BK][AS_LD], sA[k][r]
    float* sB = smem + BK * AS_LD;

    int tid = threadIdx.x;
    int b = blockIdx.x;

    int pp = 0, nrows, rowbase;
    if constexpr (BUCKETED) {
        if (b >= tileOff[P_]) return;
        while (pp < P_ - 1 && b >= tileOff[pp + 1]) ++pp;
        int tileBase = b - tileOff[pp];
        int cntp = boff[pp + 1] - boff[pp];
        int start = tileBase * TM;
        nrows = min(TM, cntp - start);
        rowbase = boff[pp] + start;
    } else {
        int start = b * TM;
        nrows = min(TM, N_ - start);
        rowbase = start;
    }
    const float* B = B0 + (BUCKETED ? (size_t)pp * D_ * D_ : 0);
    const float* Bb = (B0b != nullptr) ? (B0b + (BUCKETED ? (size_t)pp * D_ * D_ : 0)) : nullptr;

    if (tid < TM) {
        int r = -1;
        if (tid < nrows) r = BUCKETED ? blist[rowbase + tid] : (rowbase + tid);
        rid[tid] = r;
    }
    __syncthreads();

    int m = tid & 31, rg = tid >> 5;

    // staging rows for this thread (A-load): rows rg + 8*i, col m of each chunk
    int arow[8];
#pragma unroll
    for (int i = 0; i < 8; ++i) arow[i] = rid[rg + 8 * i];

    float acc[8][4];
#pragma unroll
    for (int i = 0; i < 8; ++i)
#pragma unroll
        for (int j = 0; j < 4; ++j) acc[i][j] = 0.f;

    for (int kc = 0; kc < D_; kc += BK) {
        // A stage: sA[k][r] = A[row(r)][kc+k]
#pragma unroll
        for (int i = 0; i < 8; ++i) {
            int row = arow[i];
            sA[m * AS_LD + rg + 8 * i] = (row >= 0) ? A[(size_t)row * D_ + kc + m] : 0.f;
        }
        // B stage
        if constexpr (!TRANSB) {
#pragma unroll
            for (int i = 0; i < 16; ++i) {
                int e = tid + i * 256;
                int k = e >> 7, c = e & 127;
                size_t be = (size_t)(kc + k) * D_ + c;
                float v = B[be];
                if (Bb) v += Bb[be];
                sB[k * 132 + c] = v;
            }
        } else {
#pragma unroll
            for (int i = 0; i < 16; ++i) {
                int e = tid + i * 256;
                int c = e >> 5, k = e & 31;
                sB[c * 33 + k] = B[(size_t)c * D_ + kc + k];  // B[k][c] = W2[c][k]
            }
        }
        __syncthreads();
#pragma unroll 4
        for (int k = 0; k < BK; ++k) {
            float a[8];
            const float2* ap = (const float2*)&sA[k * AS_LD + rg * 8];
            float2 a0 = ap[0], a1 = ap[1], a2 = ap[2], a3 = ap[3];
            a[0] = a0.x; a[1] = a0.y; a[2] = a1.x; a[3] = a1.y;
            a[4] = a2.x; a[5] = a2.y; a[6] = a3.x; a[7] = a3.y;
            float bv[4];
            if constexpr (!TRANSB) {
                float4 b4 = *(const float4*)&sB[k * 132 + 4 * m];
                bv[0] = b4.x; bv[1] = b4.y; bv[2] = b4.z; bv[3] = b4.w;
            } else {
#pragma unroll
                for (int j = 0; j < 4; ++j) bv[j] = sB[(m + 32 * j) * 33 + k];
            }
#pragma unroll
            for (int i = 0; i < 8; ++i)
#pragma unroll
                for (int j = 0; j < 4; ++j) acc[i][j] += a[i] * bv[j];
        }
        __syncthreads();
    }

    if constexpr (EPI == 0) {
#pragma unroll
        for (int i = 0; i < 8; ++i) {
            int row = rid[rg * 8 + i];
            if (row < 0) continue;
            float4 v;
            v.x = acc[i][0]; v.y = acc[i][1]; v.z = acc[i][2]; v.w = acc[i][3];
            *(float4*)&Out[(size_t)row * D_ + 4 * m] = v;
        }
        return;
    }

    // EPI 1/2: stage pre-LN tile in LDS, row stats, normalize, store
    float* Ts = smem;  // [TM][130]
    float bias_j[4], g_j[4], bb_j[4];
#pragma unroll
    for (int j = 0; j < 4; ++j) {
        int c = TRANSB ? (m + 32 * j) : (4 * m + j);
        bias_j[j] = bias[c];
        g_j[j] = g[c];
        bb_j[j] = bbeta[c];
    }
    float rs = (EPI == 2) ? *rs_ptr : 0.f;

#pragma unroll
    for (int i = 0; i < 8; ++i) {
        int r = rg * 8 + i;
        int row = rid[r];
        float pre[4];
        if constexpr (EPI == 1) {
            float dn = (row >= 0) ? dnorm[row] : 1.f;
#pragma unroll
            for (int j = 0; j < 4; ++j) pre[j] = dn * acc[i][j] + bias_j[j];
            // contiguous cols: two float2 stores
            float2 p0, p1;
            p0.x = pre[0]; p0.y = pre[1]; p1.x = pre[2]; p1.y = pre[3];
            *(float2*)&Ts[r * 130 + 4 * m] = p0;
            *(float2*)&Ts[r * 130 + 4 * m + 2] = p1;
        } else {
#pragma unroll
            for (int j = 0; j < 4; ++j) {
                int c = m + 32 * j;  // EPI2 is TRANSB
                float xr = (row >= 0) ? xres[(size_t)row * D_ + c] : 0.f;
                pre[j] = rs * (acc[i][j] + bias_j[j]) + xr;
                Ts[r * 130 + c] = pre[j];
            }
        }
    }
    __syncthreads();
    if (tid < TM) {
        float s1 = 0.f;
#pragma unroll 8
        for (int c = 0; c < D_; ++c) s1 += Ts[tid * 130 + c];
        float mm = s1 * (1.f / D_);
        float s2 = 0.f;
#pragma unroll 8
        for (int c = 0; c < D_; ++c) {
            float dl = Ts[tid * 130 + c] - mm;
            s2 += dl * dl;
        }
        mrow[tid] = mm;
        rrow[tid] = rsqrtf(s2 * (1.f / D_) + EPS_);
    }
    __syncthreads();
#pragma unroll
    for (int i = 0; i < 8; ++i) {
        int r = rg * 8 + i;
        int row = rid[r];
        if (row < 0) continue;
        float mm = mrow[r], rr = rrow[r];
        if constexpr (EPI == 1) {
            float vv[4];
#pragma unroll
            for (int j = 0; j < 4; ++j) {
                float v = Ts[r * 130 + 4 * m + j];
                float nv = (v - mm) * rr * g_j[j] + bb_j[j];
                vv[j] = fmaxf(nv, 0.f);
            }
            float4 o;
            o.x = vv[0]; o.y = vv[1]; o.z = vv[2]; o.w = vv[3];
            *(float4*)&Out[(size_t)row * D_ + 4 * m] = o;
        } else {
#pragma unroll
            for (int j = 0; j < 4; ++j) {
                int c = m + 32 * j;
                float v = Ts[r * 130 + c];
                float nv = (v - mm) * rr * g_j[j] + bb_j[j];
                if (x0add) nv += x0add[(size_t)row * D_ + c];
                Out[(size_t)row * D_ + c] = nv;
            }
        }
    }
}

// ---------------------------------------------------------------------------
// Host launch
// ---------------------------------------------------------------------------

extern "C" void kernel_launch(void* const* d_in, const int* in_sizes, int n_in,
                              void* d_out, int out_size, void* d_ws, size_t ws_size,
                              hipStream_t stream) {
    const float* x0 = (const float*)d_in[0];
    const int* ei = (const int*)d_in[1];
    const int* ring = (const int*)d_in[2];
    const float* Wr = (const float*)d_in[3];
    const float* S = (const float*)d_in[4];
    const float* dS = (const float*)d_in[5];
    const float* R = (const float*)d_in[6];
    const float* dR = (const float*)d_in[7];
    const float* rsc = (const float*)d_in[8];
    const float* W1 = (const float*)d_in[9];
    const float* b1 = (const float*)d_in[10];
    const float* lng = (const float*)d_in[11];
    const float* lnb = (const float*)d_in[12];
    const float* W2 = (const float*)d_in[13];
    const float* b2 = (const float*)d_in[14];
    const float* ng = (const float*)d_in[15];
    const float* nb = (const float*)d_in[16];
    float* out = (float*)d_out;

    char* w = (char*)d_ws;
    auto alloc = [&](size_t bytes) {
        char* p = w;
        w += (bytes + 15) & ~(size_t)15;
        return p;
    };
    float* xbuf = (float*)alloc((size_t)N_ * D_ * 4);
    float* bufA = (float*)alloc((size_t)N_ * D_ * 4);  // xt, then h
    float* bufB = (float*)alloc((size_t)N_ * D_ * 4);  // agg0
    float* T1 = (float*)alloc((size_t)P_ * D_ * D_ * 4);
    float* Dm = (float*)alloc((size_t)P_ * D_ * D_ * 4);
    float* dnorm = (float*)alloc((size_t)N_ * 4);
    // contiguous zero region: degS,cntT,curT,bcnt,bcur
    int* degS = (int*)alloc((size_t)(3 * N_ + 2 * P_) * 4);
    int* cntT = degS + N_;
    int* curT = cntT + N_;
    int* bcnt = curT + N_;
    int* bcur = bcnt + P_;
    int* pol = (int*)alloc((size_t)N_ * 4);
    int* offT = (int*)alloc((size_t)(N_ + 1) * 4);
    int* eSrc = (int*)alloc((size_t)E_ * 4);
    int* boff = (int*)alloc((size_t)(P_ + 1) * 4);
    int* tileOff = (int*)alloc((size_t)(P_ + 1) * 4);
    int* blist = (int*)alloc((size_t)N_ * 4);
    int* blkSum = (int*)alloc((size_t)NB * 4);
    int* blkOff = (int*)alloc((size_t)NB * 4);

    hipMemsetAsync(degS, 0, (size_t)(3 * N_ + 2 * P_) * 4, stream);

    const int NG = (N_ + 255) / 256;   // 196
    const int EG = (E_ + 255) / 256;   // 3125
    const int SG = P_ * D_ * D_ / 256; // 576
    const int BTILES = N_ / TM + P_;   // 791 (>= max bucketed tiles)
    const int CTILES = (N_ + TM - 1) / TM;  // 782

    node_init<<<NG, 256, 0, stream>>>(ring, pol, bcnt);
    edge_count<<<EG, 256, 0, stream>>>(ei, degS, cntT);
    scan1<<<NB, 1024, 0, stream>>>(cntT, offT, blkSum);
    scan2<<<1, 64, 0, stream>>>(blkSum, blkOff, offT, bcnt, boff, tileOff);
    scan3<<<NB, 1024, 0, stream>>>(offT, blkOff);
    fill_edges<<<EG, 256, 0, stream>>>(ei, offT, curT, eSrc);
    bucket_dnorm<<<NG, 256, 0, stream>>>(pol, boff, bcur, blist, degS, dnorm);

    const float* xs = x0;
    for (int l = 0; l < L_; ++l) {
        const size_t lPDD = (size_t)l * P_ * D_ * D_;
        const size_t lDD = (size_t)l * D_ * D_;
        small_gemm1<<<SG, 256, 0, stream>>>(R + lPDD, dR + lPDD, W1 + lDD, T1);
        small_gemm2<<<SG, 256, 0, stream>>>(Wr + lDD, T1, Dm);
        // xt = X @ (S+dS)[pol]
        gemm_tile<0, false, true><<<BTILES, 256, 0, stream>>>(
            xs, S + lPDD, dS + lPDD, bufA, blist, boff, tileOff,
            nullptr, nullptr, nullptr, nullptr, nullptr, nullptr, nullptr);
        // agg0 = CSR-sum of xt
        aggregate<<<N_ / 4, 256, 0, stream>>>(bufA, offT, eSrc, bufB);
        // h = relu(LN(dn * (agg0 @ Dm[pol]) + b1))
        gemm_tile<1, false, true><<<BTILES, 256, 0, stream>>>(
            bufB, Dm, nullptr, bufA, blist, boff, tileOff,
            dnorm, b1 + (size_t)l * D_, lng + (size_t)l * D_, lnb + (size_t)l * D_,
            nullptr, nullptr, nullptr);
        // x_next = LN(rs*(h @ W2.T + b2) + x)  (+x0 on last layer -> d_out)
        float* xo = (l == L_ - 1) ? out : xbuf;
        gemm_tile<2, true, false><<<CTILES, 256, 0, stream>>>(
            bufA, W2 + lDD, nullptr, xo, nullptr, nullptr, nullptr,
            nullptr, b2 + (size_t)l * D_, ng + (size_t)l * D_, nb + (size_t)l * D_,
            rsc + l, xs, (l == L_ - 1) ? x0 : nullptr);
        xs = xbuf;
    }
}

// Round 3
// 650.568 us; speedup vs baseline: 1.9950x; 1.4141x over previous
//
#include <hip/hip_runtime.h>
#include <hip/hip_bf16.h>

// Problem constants
constexpr int N_ = 50000;
constexpr int D_ = 128;
constexpr int E_ = 800000;
constexpr int P_ = 9;
constexpr int L_ = 3;
constexpr float EPS_ = 1e-5f;

constexpr int TM = 64;   // rows per GEMM block
constexpr int NB = (N_ + 1023) / 1024;  // scan blocks = 49

typedef short bf16x8 __attribute__((ext_vector_type(8)));
typedef float f32x4 __attribute__((ext_vector_type(4)));

__device__ inline unsigned short f2bf(float f) {
    __hip_bfloat16 h = __float2bfloat16(f);
    return *reinterpret_cast<unsigned short*>(&h);
}
__device__ inline float bflo(unsigned u) { return __uint_as_float(u << 16); }
__device__ inline float bfhi(unsigned u) { return __uint_as_float(u & 0xffff0000u); }

// ---------------------------------------------------------------------------
// Setup kernels (unchanged from R2 — atomic-light versions)
// ---------------------------------------------------------------------------

__global__ __launch_bounds__(256) void node_init(const int* __restrict__ ring,
                                                 int* __restrict__ pol,
                                                 int* __restrict__ bcnt) {
    __shared__ int h[P_];
    int tid = threadIdx.x;
    if (tid < P_) h[tid] = 0;
    __syncthreads();
    int n = blockIdx.x * 256 + tid;
    if (n < N_) {
        int p = ring[n] % P_;
        pol[n] = p;
        atomicAdd(&h[p], 1);
    }
    __syncthreads();
    if (tid < P_ && h[tid] > 0) atomicAdd(&bcnt[tid], h[tid]);
}

__global__ void edge_count(const int* __restrict__ ei, int* __restrict__ degS,
                           int* __restrict__ cntT) {
    int e = blockIdx.x * 256 + threadIdx.x;
    if (e >= E_) return;
    atomicAdd(&degS[ei[e]], 1);
    atomicAdd(&cntT[ei[E_ + e]], 1);
}

__global__ __launch_bounds__(1024) void scan1(const int* __restrict__ cnt,
                                              int* __restrict__ off,
                                              int* __restrict__ blkSum) {
    __shared__ int wsum[16];
    int tid = threadIdx.x, lane = tid & 63, wid = tid >> 6;
    int idx = blockIdx.x * 1024 + tid;
    int v = (idx < N_) ? cnt[idx] : 0;
    int inc = v;
#pragma unroll
    for (int o = 1; o < 64; o <<= 1) {
        int t = __shfl_up(inc, o, 64);
        if (lane >= o) inc += t;
    }
    if (lane == 63) wsum[wid] = inc;
    __syncthreads();
    if (tid < 16) {
        int s = wsum[tid];
#pragma unroll
        for (int o = 1; o < 16; o <<= 1) {
            int t = __shfl_up(s, o, 64);
            if (tid >= o) s += t;
        }
        wsum[tid] = s;
    }
    __syncthreads();
    int wexcl = (wid == 0) ? 0 : wsum[wid - 1];
    if (idx < N_) off[idx] = wexcl + inc - v;
    if (tid == 1023) blkSum[blockIdx.x] = wsum[15];
}

__global__ void scan2(const int* __restrict__ blkSum, int* __restrict__ blkOff,
                      int* __restrict__ off, const int* __restrict__ bcnt,
                      int* __restrict__ boff, int* __restrict__ tileOff) {
    if (threadIdx.x != 0) return;
    int run = 0;
    for (int i = 0; i < NB; ++i) {
        blkOff[i] = run;
        run += blkSum[i];
    }
    off[N_] = run;
    boff[0] = 0;
    tileOff[0] = 0;
    for (int p = 0; p < P_; ++p) {
        boff[p + 1] = boff[p] + bcnt[p];
        tileOff[p + 1] = tileOff[p] + (bcnt[p] + TM - 1) / TM;
    }
}

__global__ __launch_bounds__(1024) void scan3(int* __restrict__ off,
                                              const int* __restrict__ blkOff) {
    int idx = blockIdx.x * 1024 + threadIdx.x;
    if (idx < N_) off[idx] += blkOff[blockIdx.x];
}

__global__ void fill_edges(const int* __restrict__ ei, const int* __restrict__ offT,
                           int* __restrict__ curT, int* __restrict__ eSrc) {
    int e = blockIdx.x * 256 + threadIdx.x;
    if (e >= E_) return;
    int t = ei[E_ + e];
    int pos = atomicAdd(&curT[t], 1);
    eSrc[offT[t] + pos] = ei[e];
}

__global__ __launch_bounds__(256) void bucket_dnorm(
    const int* __restrict__ pol, const int* __restrict__ boff,
    int* __restrict__ bcur, int* __restrict__ blist,
    const int* __restrict__ degS, float* __restrict__ dnorm) {
    __shared__ int h[P_];
    __shared__ int base[P_];
    int tid = threadIdx.x;
    if (tid < P_) h[tid] = 0;
    __syncthreads();
    int n = blockIdx.x * 256 + tid;
    int p = 0, loc = 0;
    bool act = (n < N_);
    if (act) {
        p = pol[n];
        loc = atomicAdd(&h[p], 1);
        int dg = degS[n];
        dnorm[n] = 1.f / (float)(dg > 1 ? dg : 1);
    }
    __syncthreads();
    if (tid < P_ && h[tid] > 0) base[tid] = atomicAdd(&bcur[tid], h[tid]);
    __syncthreads();
    if (act) blist[boff[p] + base[p] + loc] = n;
}

// ---------------------------------------------------------------------------
// Weight prep: fp32 -> bf16, transposed to [out_col][k] where needed
// ---------------------------------------------------------------------------

// x0 -> bf16, 4 elems/thread
__global__ __launch_bounds__(256) void conv4(const float* __restrict__ x,
                                             unsigned short* __restrict__ xb) {
    int i = blockIdx.x * 256 + threadIdx.x;
    if (i >= N_ * D_ / 4) return;
    float4 v = ((const float4*)x)[i];
    ushort4 o;
    o.x = f2bf(v.x); o.y = f2bf(v.y); o.z = f2bf(v.z); o.w = f2bf(v.w);
    ((ushort4*)xb)[i] = o;
}

// Sb[l][p][c][d] = bf16(S[l][p][d][c] + dS[l][p][d][c])   (transpose + cast)
__global__ __launch_bounds__(256) void prep_S(const float* __restrict__ S,
                                              const float* __restrict__ dS,
                                              unsigned short* __restrict__ Sb) {
    int idx = blockIdx.x * 256 + threadIdx.x;  // 3*P*D*D
    int base = idx / (D_ * D_);
    int rem = idx % (D_ * D_);
    int c = rem / D_, d = rem % D_;
    size_t in = (size_t)base * D_ * D_ + (size_t)d * D_ + c;
    Sb[idx] = f2bf(S[in] + dS[in]);
}

// W2 is [c][k] already — cast only
__global__ __launch_bounds__(256) void prep_W2(const float* __restrict__ W2,
                                               unsigned short* __restrict__ W2b) {
    int idx = blockIdx.x * 256 + threadIdx.x;  // 3*D*D
    W2b[idx] = f2bf(W2[idx]);
}

// T1[p][i][k] = sum_j (R+dR)[p][i][j] * W1[k][j]
__global__ void small_gemm1(const float* __restrict__ Rm, const float* __restrict__ dRm,
                            const float* __restrict__ W1, float* __restrict__ T1) {
    int idx = blockIdx.x * 256 + threadIdx.x;  // P*D*D
    int p = idx / (D_ * D_);
    int rem = idx % (D_ * D_);
    int i = rem / D_, k = rem % D_;
    const float* a = Rm + ((size_t)p * D_ + i) * D_;
    const float* a2 = dRm + ((size_t)p * D_ + i) * D_;
    const float* w = W1 + (size_t)k * D_;
    float acc = 0.f;
#pragma unroll 8
    for (int j = 0; j < D_; ++j) acc += (a[j] + a2[j]) * w[j];
    T1[idx] = acc;
}

// Dmb[p][k][d] = bf16( sum_i Wr[i][d] * T1[p][i][k] )   (transposed out, bf16)
__global__ void small_gemm2T(const float* __restrict__ Wr, const float* __restrict__ T1,
                             unsigned short* __restrict__ Dmb) {
    int idx = blockIdx.x * 256 + threadIdx.x;  // P*D*D
    int p = idx / (D_ * D_);
    int rem = idx % (D_ * D_);
    int k = rem / D_, d = rem % D_;
    const float* t = T1 + (size_t)p * D_ * D_;
    float acc = 0.f;
#pragma unroll 8
    for (int i = 0; i < D_; ++i) acc += Wr[i * D_ + d] * t[i * D_ + k];
    Dmb[idx] = f2bf(acc);
}

// ---------------------------------------------------------------------------
// CSR aggregation over bf16 rows: agg[n] = sum_{incoming e} xt[src(e)]
// one wave per node; lane holds one packed bf16 pair; fp32 accumulate
// ---------------------------------------------------------------------------

__global__ __launch_bounds__(256) void aggregate_bf(const unsigned short* __restrict__ xt,
                                                    const int* __restrict__ offT,
                                                    const int* __restrict__ eSrc,
                                                    unsigned short* __restrict__ agg) {
    int nd = blockIdx.x * 4 + (threadIdx.x >> 6);
    if (nd >= N_) return;
    int lane = threadIdx.x & 63;
    int beg = offT[nd], end = offT[nd + 1];
    float ax = 0.f, ay = 0.f;
    int i = beg;
    for (; i + 1 < end; i += 2) {
        unsigned u0 = ((const unsigned*)(xt + (size_t)eSrc[i] * D_))[lane];
        unsigned u1 = ((const unsigned*)(xt + (size_t)eSrc[i + 1] * D_))[lane];
        ax += bflo(u0) + bflo(u1);
        ay += bfhi(u0) + bfhi(u1);
    }
    if (i < end) {
        unsigned u0 = ((const unsigned*)(xt + (size_t)eSrc[i] * D_))[lane];
        ax += bflo(u0);
        ay += bfhi(u0);
    }
    unsigned o = (unsigned)f2bf(ax) | ((unsigned)f2bf(ay) << 16);
    ((unsigned*)(agg + (size_t)nd * D_))[lane] = o;
}

// ---------------------------------------------------------------------------
// MFMA GEMM: 64 rows x 128 cols per block, 4 waves x 16 rows, K=128 resident.
// A: bf16 [N][128] row-gathered. Bw: bf16 [c][k] (pre-transposed weights).
// mfma_f32_16x16x32_bf16: A-frag A[m=lane&15][k=q*8+j]; B-frag B[k=q*8+j][n=lane&15];
// C/D: col=lane&15, row=q*4+reg  [m89-verified]
// EPI 0: OutB = bf16(acc)                                  (xt)
// EPI 1: pre = dnRow*acc + b1; OutB = bf16(relu(LN(pre)))  (h)
// EPI 2: pre = rs*(acc+b2) + xres; o = LN(pre) (+x0add); OutF=o fp32, OutB=bf16(o)
// ---------------------------------------------------------------------------

template <int EPI, bool BUCKETED>
__global__ __launch_bounds__(256) void mfma_gemm(
    const unsigned short* __restrict__ A, const unsigned short* __restrict__ Bw,
    float* __restrict__ OutF, unsigned short* __restrict__ OutB,
    const int* __restrict__ blist, const int* __restrict__ boff,
    const int* __restrict__ tileOff, const float* __restrict__ dnorm,
    const float* __restrict__ bias, const float* __restrict__ g,
    const float* __restrict__ bb, const float* __restrict__ rs_ptr,
    const float* __restrict__ xres, const float* __restrict__ x0add) {
    // sA: 64 x 136 bf16 (17408 B), sB: 128 x 136 bf16 (34816 B)
    __shared__ unsigned short smem[8704 + 17408];
    __shared__ int rid[TM];
    __shared__ float dnRow[TM];
    unsigned short* sA = smem;
    unsigned short* sB = smem + 8704;
    float* Ts = (float*)(smem + 8704);  // overlays sB: 64*132 fp32 = 33792 B

    int tid = threadIdx.x;
    int b = blockIdx.x;

    int pp = 0, nrows, rowbase;
    if constexpr (BUCKETED) {
        if (b >= tileOff[P_]) return;
        while (pp < P_ - 1 && b >= tileOff[pp + 1]) ++pp;
        int tb = b - tileOff[pp];
        int cnt = boff[pp + 1] - boff[pp];
        nrows = min(TM, cnt - tb * TM);
        rowbase = boff[pp] + tb * TM;
    } else {
        nrows = min(TM, N_ - b * TM);
        rowbase = b * TM;
    }
    const unsigned short* B = Bw + (BUCKETED ? (size_t)pp * D_ * D_ : 0);

    if (tid < TM) {
        int r = (tid < nrows) ? (BUCKETED ? blist[rowbase + tid] : rowbase + tid) : -1;
        rid[tid] = r;
        if constexpr (EPI == 1) dnRow[tid] = (r >= 0) ? dnorm[r] : 1.f;
    }
    __syncthreads();

    // stage B (contiguous 32 KB): 2048 x 16B chunks
#pragma unroll
    for (int i = 0; i < 8; ++i) {
        int c = tid + i * 256;
        int r = c >> 4, off = c & 15;
        uint4 v = *(const uint4*)(B + r * 128 + off * 8);
        *(uint4*)(sB + r * 136 + off * 8) = v;
    }
    // stage A (gathered rows): 1024 x 16B chunks
#pragma unroll
    for (int i = 0; i < 4; ++i) {
        int c = tid + i * 256;
        int r = c >> 4, off = c & 15;
        int row = rid[r];
        uint4 v = make_uint4(0, 0, 0, 0);
        if (row >= 0) v = *(const uint4*)(A + (size_t)row * D_ + off * 8);
        *(uint4*)(sA + r * 136 + off * 8) = v;
    }
    __syncthreads();

    int lane = tid & 63, wave = tid >> 6;
    int n = lane & 15, q = lane >> 4;
    int wr = wave * 16;

    f32x4 acc[8];
#pragma unroll
    for (int t = 0; t < 8; ++t) acc[t] = (f32x4){0.f, 0.f, 0.f, 0.f};

#pragma unroll
    for (int k0 = 0; k0 < 4; ++k0) {
        bf16x8 af = *(const bf16x8*)(sA + (wr + n) * 136 + k0 * 32 + q * 8);
#pragma unroll
        for (int t = 0; t < 8; ++t) {
            bf16x8 bf = *(const bf16x8*)(sB + (t * 16 + n) * 136 + k0 * 32 + q * 8);
            acc[t] = __builtin_amdgcn_mfma_f32_16x16x32_bf16(af, bf, acc[t], 0, 0, 0);
        }
    }
    __syncthreads();  // LDS about to be reused

    unsigned short* Tb = sA;  // bf16 out staging, stride 136

    if constexpr (EPI == 0) {
#pragma unroll
        for (int t = 0; t < 8; ++t)
#pragma unroll
            for (int r = 0; r < 4; ++r)
                Tb[(wr + q * 4 + r) * 136 + t * 16 + n] = f2bf(acc[t][r]);
        __syncthreads();
#pragma unroll
        for (int i = 0; i < 4; ++i) {
            int c = tid + i * 256;
            int rr2 = c >> 4, off = c & 15;
            int row = rid[rr2];
            if (row >= 0)
                *(uint4*)(OutB + (size_t)row * D_ + off * 8) =
                    *(const uint4*)(Tb + rr2 * 136 + off * 8);
        }
        return;
    }

    if constexpr (EPI == 1) {
        float rs1[4] = {0, 0, 0, 0}, rs2[4] = {0, 0, 0, 0};
#pragma unroll
        for (int t = 0; t < 8; ++t) {
            int col = t * 16 + n;
            float bia = bias[col];
#pragma unroll
            for (int r = 0; r < 4; ++r) {
                float v = dnRow[wr + q * 4 + r] * acc[t][r] + bia;
                acc[t][r] = v;
                rs1[r] += v;
                rs2[r] += v * v;
            }
        }
#pragma unroll
        for (int mk = 1; mk < 16; mk <<= 1)
#pragma unroll
            for (int r = 0; r < 4; ++r) {
                rs1[r] += __shfl_xor(rs1[r], mk, 64);
                rs2[r] += __shfl_xor(rs2[r], mk, 64);
            }
        float mr[4], rv[4];
#pragma unroll
        for (int r = 0; r < 4; ++r) {
            float mm = rs1[r] * (1.f / 128.f);
            mr[r] = mm;
            rv[r] = rsqrtf(rs2[r] * (1.f / 128.f) - mm * mm + EPS_);
        }
#pragma unroll
        for (int t = 0; t < 8; ++t) {
            int col = t * 16 + n;
            float gg = g[col], bbv = bb[col];
#pragma unroll
            for (int r = 0; r < 4; ++r) {
                float nv = (acc[t][r] - mr[r]) * rv[r] * gg + bbv;
                Tb[(wr + q * 4 + r) * 136 + col] = f2bf(fmaxf(nv, 0.f));
            }
        }
        __syncthreads();
#pragma unroll
        for (int i = 0; i < 4; ++i) {
            int c = tid + i * 256;
            int rr2 = c >> 4, off = c & 15;
            int row = rid[rr2];
            if (row >= 0)
                *(uint4*)(OutB + (size_t)row * D_ + off * 8) =
                    *(const uint4*)(Tb + rr2 * 136 + off * 8);
        }
        return;
    }

    if constexpr (EPI == 2) {
        // prefill Ts with xres (coalesced float4)
#pragma unroll
        for (int i = 0; i < 8; ++i) {
            int c = tid + i * 256;
            int rr2 = c >> 5, off = c & 31;
            int row = rid[rr2];
            float4 v = make_float4(0, 0, 0, 0);
            if (row >= 0) v = *(const float4*)(xres + (size_t)row * D_ + off * 4);
            *(float4*)(Ts + rr2 * 132 + off * 4) = v;
        }
        __syncthreads();
        float rs = rs_ptr[0];
        float rs1[4] = {0, 0, 0, 0}, rs2[4] = {0, 0, 0, 0};
#pragma unroll
        for (int t = 0; t < 8; ++t) {
            int col = t * 16 + n;
            float bia = bias[col];
#pragma unroll
            for (int r = 0; r < 4; ++r) {
                int row = wr + q * 4 + r;
                float v = rs * (acc[t][r] + bia) + Ts[row * 132 + col];
                acc[t][r] = v;
                rs1[r] += v;
                rs2[r] += v * v;
            }
        }
#pragma unroll
        for (int mk = 1; mk < 16; mk <<= 1)
#pragma unroll
            for (int r = 0; r < 4; ++r) {
                rs1[r] += __shfl_xor(rs1[r], mk, 64);
                rs2[r] += __shfl_xor(rs2[r], mk, 64);
            }
        float mr[4], rv[4];
#pragma unroll
        for (int r = 0; r < 4; ++r) {
            float mm = rs1[r] * (1.f / 128.f);
            mr[r] = mm;
            rv[r] = rsqrtf(rs2[r] * (1.f / 128.f) - mm * mm + EPS_);
        }
        bool hasB = (OutB != nullptr);
#pragma unroll
        for (int t = 0; t < 8; ++t) {
            int col = t * 16 + n;
            float gg = g[col], bbv = bb[col];
#pragma unroll
            for (int r = 0; r < 4; ++r) {
                int row = wr + q * 4 + r;
                float nv = (acc[t][r] - mr[r]) * rv[r] * gg + bbv;
                if (x0add) {
                    int grow = rid[row];
                    if (grow >= 0) nv += x0add[(size_t)grow * D_ + col];
                }
                Ts[row * 132 + col] = nv;
                if (hasB) Tb[row * 136 + col] = f2bf(nv);
            }
        }
        __syncthreads();
#pragma unroll
        for (int i = 0; i < 8; ++i) {
            int c = tid + i * 256;
            int rr2 = c >> 5, off = c & 31;
            int row = rid[rr2];
            if (row >= 0)
                *(float4*)(OutF + (size_t)row * D_ + off * 4) =
                    *(const float4*)(Ts + rr2 * 132 + off * 4);
        }
        if (hasB) {
#pragma unroll
            for (int i = 0; i < 4; ++i) {
                int c = tid + i * 256;
                int rr2 = c >> 4, off = c & 15;
                int row = rid[rr2];
                if (row >= 0)
                    *(uint4*)(OutB + (size_t)row * D_ + off * 8) =
                        *(const uint4*)(Tb + rr2 * 136 + off * 8);
            }
        }
    }
}

// ---------------------------------------------------------------------------
// Host launch
// ---------------------------------------------------------------------------

extern "C" void kernel_launch(void* const* d_in, const int* in_sizes, int n_in,
                              void* d_out, int out_size, void* d_ws, size_t ws_size,
                              hipStream_t stream) {
    const float* x0 = (const float*)d_in[0];
    const int* ei = (const int*)d_in[1];
    const int* ring = (const int*)d_in[2];
    const float* Wr = (const float*)d_in[3];
    const float* S = (const float*)d_in[4];
    const float* dS = (const float*)d_in[5];
    const float* R = (const float*)d_in[6];
    const float* dR = (const float*)d_in[7];
    const float* rsc = (const float*)d_in[8];
    const float* W1 = (const float*)d_in[9];
    const float* b1 = (const float*)d_in[10];
    const float* lng = (const float*)d_in[11];
    const float* lnb = (const float*)d_in[12];
    const float* W2 = (const float*)d_in[13];
    const float* b2 = (const float*)d_in[14];
    const float* ng = (const float*)d_in[15];
    const float* nb = (const float*)d_in[16];
    float* out = (float*)d_out;

    char* w = (char*)d_ws;
    auto alloc = [&](size_t bytes) {
        char* p = w;
        w += (bytes + 15) & ~(size_t)15;
        return p;
    };
    unsigned short* xb = (unsigned short*)alloc((size_t)N_ * D_ * 2);     // bf16 x
    unsigned short* bufAb = (unsigned short*)alloc((size_t)N_ * D_ * 2);  // xt / h
    unsigned short* bufBb = (unsigned short*)alloc((size_t)N_ * D_ * 2);  // agg
    float* xbuf = (float*)alloc((size_t)N_ * D_ * 4);                     // fp32 x
    unsigned short* Sb = (unsigned short*)alloc((size_t)L_ * P_ * D_ * D_ * 2);
    unsigned short* Dmb = (unsigned short*)alloc((size_t)L_ * P_ * D_ * D_ * 2);
    unsigned short* W2b = (unsigned short*)alloc((size_t)L_ * D_ * D_ * 2);
    float* T1 = (float*)alloc((size_t)P_ * D_ * D_ * 4);
    float* dnorm = (float*)alloc((size_t)N_ * 4);
    int* degS = (int*)alloc((size_t)(3 * N_ + 2 * P_) * 4);  // zeroed region
    int* cntT = degS + N_;
    int* curT = cntT + N_;
    int* bcnt = curT + N_;
    int* bcur = bcnt + P_;
    int* pol = (int*)alloc((size_t)N_ * 4);
    int* offT = (int*)alloc((size_t)(N_ + 1) * 4);
    int* eSrc = (int*)alloc((size_t)E_ * 4);
    int* boff = (int*)alloc((size_t)(P_ + 1) * 4);
    int* tileOff = (int*)alloc((size_t)(P_ + 1) * 4);
    int* blist = (int*)alloc((size_t)N_ * 4);
    int* blkSum = (int*)alloc((size_t)NB * 4);
    int* blkOff = (int*)alloc((size_t)NB * 4);

    hipMemsetAsync(degS, 0, (size_t)(3 * N_ + 2 * P_) * 4, stream);

    const int NG = (N_ + 255) / 256;
    const int EG = (E_ + 255) / 256;
    const int SG = P_ * D_ * D_ / 256;          // 576
    const int BTILES = N_ / TM + P_;            // 790 (>= total bucketed tiles)
    const int CTILES = (N_ + TM - 1) / TM;      // 782

    node_init<<<NG, 256, 0, stream>>>(ring, pol, bcnt);
    edge_count<<<EG, 256, 0, stream>>>(ei, degS, cntT);
    scan1<<<NB, 1024, 0, stream>>>(cntT, offT, blkSum);
    scan2<<<1, 64, 0, stream>>>(blkSum, blkOff, offT, bcnt, boff, tileOff);
    scan3<<<NB, 1024, 0, stream>>>(offT, blkOff);
    fill_edges<<<EG, 256, 0, stream>>>(ei, offT, curT, eSrc);
    bucket_dnorm<<<NG, 256, 0, stream>>>(pol, boff, bcur, blist, degS, dnorm);

    conv4<<<(N_ * D_ / 4 + 255) / 256, 256, 0, stream>>>(x0, xb);
    prep_S<<<L_ * SG, 256, 0, stream>>>(S, dS, Sb);
    prep_W2<<<L_ * D_ * D_ / 256, 256, 0, stream>>>(W2, W2b);
    for (int l = 0; l < L_; ++l) {
        const size_t lPDD = (size_t)l * P_ * D_ * D_;
        const size_t lDD = (size_t)l * D_ * D_;
        small_gemm1<<<SG, 256, 0, stream>>>(R + lPDD, dR + lPDD, W1 + lDD, T1);
        small_gemm2T<<<SG, 256, 0, stream>>>(Wr + lDD, T1, Dmb + lPDD);
    }

    for (int l = 0; l < L_; ++l) {
        const size_t lPDD = (size_t)l * P_ * D_ * D_;
        const size_t lDD = (size_t)l * D_ * D_;
        const size_t lD = (size_t)l * D_;
        // xt = x @ (S+dS)[pol]   -> bf16
        mfma_gemm<0, true><<<BTILES, 256, 0, stream>>>(
            xb, Sb + lPDD, nullptr, bufAb, blist, boff, tileOff,
            nullptr, nullptr, nullptr, nullptr, nullptr, nullptr, nullptr);
        // agg = CSR-sum xt  -> bf16
        aggregate_bf<<<N_ / 4, 256, 0, stream>>>(bufAb, offT, eSrc, bufBb);
        // h = relu(LN(dn * (agg @ Dm[pol]) + b1)) -> bf16
        mfma_gemm<1, true><<<BTILES, 256, 0, stream>>>(
            bufBb, Dmb + lPDD, nullptr, bufAb, blist, boff, tileOff,
            dnorm, b1 + lD, lng + lD, lnb + lD, nullptr, nullptr, nullptr);
        // x' = LN(rs*(h @ W2.T + b2) + x) (+x0 last) -> fp32 (+bf16 for next layer)
        float* xo = (l == L_ - 1) ? out : xbuf;
        const float* xr = (l == 0) ? x0 : xbuf;
        unsigned short* xbn = (l == L_ - 1) ? nullptr : xb;
        mfma_gemm<2, false><<<CTILES, 256, 0, stream>>>(
            bufAb, W2b + lDD, xo, xbn, nullptr, nullptr, nullptr,
            nullptr, b2 + lD, ng + lD, nb + lD, rsc + l, xr,
            (l == L_ - 1) ? x0 : nullptr);
    }
}

// Round 4
// 556.443 us; speedup vs baseline: 2.3325x; 1.1692x over previous
//
#include <hip/hip_runtime.h>
#include <hip/hip_bf16.h>

// Problem constants
constexpr int N_ = 50000;
constexpr int D_ = 128;
constexpr int E_ = 800000;
constexpr int P_ = 9;
constexpr int L_ = 3;
constexpr float EPS_ = 1e-5f;

constexpr int TM = 64;    // rows per GEMM block
constexpr int CHUNK = 4096;                    // edges per hist/scatter block
constexpr int NBK = (E_ + CHUNK - 1) / CHUNK;  // 196 edge chunks
constexpr int NBUK = 196;                      // node buckets (50000>>8 = 195 max)
constexpr int HHALF = 256 * NBK;               // 50176 (per-half hist size)
constexpr int HTOT = 2 * HHALF;                // 100352 = 98 * 1024 exactly
constexpr int NSB = HTOT / 1024;               // 98 scan blocks

typedef short bf16x8 __attribute__((ext_vector_type(8)));
typedef float f32x4 __attribute__((ext_vector_type(4)));

__device__ inline unsigned short f2bf(float f) {
    __hip_bfloat16 h = __float2bfloat16(f);
    return *reinterpret_cast<unsigned short*>(&h);
}
__device__ inline float bflo(unsigned u) { return __uint_as_float(u << 16); }
__device__ inline float bfhi(unsigned u) { return __uint_as_float(u & 0xffff0000u); }

// ---------------------------------------------------------------------------
// Node polarity init (LDS histogram; 9 global atomics per block)
// ---------------------------------------------------------------------------

__global__ __launch_bounds__(256) void node_init(const int* __restrict__ ring,
                                                 int* __restrict__ pol,
                                                 int* __restrict__ bcnt) {
    __shared__ int h[P_];
    int tid = threadIdx.x;
    if (tid < P_) h[tid] = 0;
    __syncthreads();
    int n = blockIdx.x * 256 + tid;
    if (n < N_) {
        int p = ring[n] % P_;
        pol[n] = p;
        atomicAdd(&h[p], 1);
    }
    __syncthreads();
    if (tid < P_ && h[tid] > 0) atomicAdd(&bcnt[tid], h[tid]);
}

// ---------------------------------------------------------------------------
// CSR build via bucket sort — replaces 2.4M memory-side atomics (32B HBM
// write-through each, measured 66 µs for edge_count alone) with LDS atomics.
// ---------------------------------------------------------------------------

// per-chunk 256-bin histograms of tgt>>8 and src>>8, bin-major output
__global__ __launch_bounds__(256) void khist(const int* __restrict__ ei,
                                             int* __restrict__ histG) {
    __shared__ int hT[256], hS[256];
    int blk = blockIdx.x, tid = threadIdx.x;
    hT[tid] = 0;
    hS[tid] = 0;
    __syncthreads();
    int base = blk * CHUNK;
#pragma unroll
    for (int i = 0; i < CHUNK / 256; ++i) {
        int e = base + tid + i * 256;
        if (e < E_) {
            atomicAdd(&hS[ei[e] >> 8], 1);
            atomicAdd(&hT[ei[E_ + e] >> 8], 1);
        }
    }
    __syncthreads();
    histG[tid * NBK + blk] = hT[tid];
    histG[HHALF + tid * NBK + blk] = hS[tid];
}

// exclusive scan of histG[HTOT] (in place), 3 dispatches
__global__ __launch_bounds__(1024) void scanH1(int* __restrict__ a,
                                               int* __restrict__ blkSum) {
    __shared__ int wsum[16];
    int tid = threadIdx.x, lane = tid & 63, wid = tid >> 6;
    int idx = blockIdx.x * 1024 + tid;  // HTOT = NSB*1024 exactly, no bounds check
    int v = a[idx];
    int inc = v;
#pragma unroll
    for (int o = 1; o < 64; o <<= 1) {
        int t = __shfl_up(inc, o, 64);
        if (lane >= o) inc += t;
    }
    if (lane == 63) wsum[wid] = inc;
    __syncthreads();
    if (tid < 16) {
        int s = wsum[tid];
#pragma unroll
        for (int o = 1; o < 16; o <<= 1) {
            int t = __shfl_up(s, o, 64);
            if (tid >= o) s += t;
        }
        wsum[tid] = s;
    }
    __syncthreads();
    int wexcl = (wid == 0) ? 0 : wsum[wid - 1];
    a[idx] = wexcl + inc - v;
    if (tid == 1023) blkSum[blockIdx.x] = wsum[15];
}

__global__ void scanH2(const int* __restrict__ blkSum, int* __restrict__ blkOff,
                       int* __restrict__ offT, const int* __restrict__ bcnt,
                       int* __restrict__ boff, int* __restrict__ tileOff) {
    if (threadIdx.x != 0) return;
    int run = 0;
    for (int i = 0; i < NSB; ++i) {
        blkOff[i] = run;
        run += blkSum[i];
    }
    offT[N_] = E_;
    boff[0] = 0;
    tileOff[0] = 0;
    for (int p = 0; p < P_; ++p) {
        boff[p + 1] = boff[p] + bcnt[p];
        tileOff[p + 1] = tileOff[p] + (bcnt[p] + TM - 1) / TM;
    }
}

__global__ __launch_bounds__(1024) void scanH3(int* __restrict__ a,
                                               const int* __restrict__ blkOff) {
    int idx = blockIdx.x * 1024 + threadIdx.x;
    a[idx] += blkOff[blockIdx.x];
}

// scatter into tgt-buckets (packed tgt<<16|src) and src-buckets (low byte only)
__global__ __launch_bounds__(256) void scatterTS(const int* __restrict__ ei,
                                                 const int* __restrict__ histG,
                                                 unsigned* __restrict__ bufT,
                                                 unsigned char* __restrict__ bufS8) {
    __shared__ int ldsT[256], ldsS[256];
    int blk = blockIdx.x, tid = threadIdx.x;
    ldsT[tid] = histG[tid * NBK + blk];
    ldsS[tid] = histG[HHALF + tid * NBK + blk] - E_;
    __syncthreads();
    int base = blk * CHUNK;
#pragma unroll
    for (int i = 0; i < CHUNK / 256; ++i) {
        int e = base + tid + i * 256;
        if (e < E_) {
            int s = ei[e], t = ei[E_ + e];
            int pT = atomicAdd(&ldsT[t >> 8], 1);
            bufT[pT] = ((unsigned)t << 16) | (unsigned)s;
            int pS = atomicAdd(&ldsS[s >> 8], 1);
            bufS8[pS] = (unsigned char)(s & 255);
        }
    }
}

// per-bucket counting sort by tgt&255 -> offT + fully sorted eSrc (u16)
__global__ __launch_bounds__(256) void finalizeT(const unsigned* __restrict__ bufT,
                                                 const int* __restrict__ histG,
                                                 int* __restrict__ offT,
                                                 unsigned short* __restrict__ eSrc) {
    __shared__ int hist[256];
    __shared__ int sOff[256];
    int b = blockIdx.x, tid = threadIdx.x;
    int start = histG[b * NBK];
    int end = histG[(b + 1) * NBK];  // bins >195 are empty, so this is bucket end
    hist[tid] = 0;
    __syncthreads();
    for (int i = start + tid; i < end; i += 256)
        atomicAdd(&hist[(bufT[i] >> 16) & 255], 1);
    __syncthreads();
    if (tid < 64) {  // wave 0: exclusive scan of 256 bins, 4 bins/lane
        int b0 = 4 * tid;
        int s0 = hist[b0], s1 = hist[b0 + 1], s2 = hist[b0 + 2], s3 = hist[b0 + 3];
        int lsum = s0 + s1 + s2 + s3;
        int inc = lsum;
#pragma unroll
        for (int o = 1; o < 64; o <<= 1) {
            int t = __shfl_up(inc, o, 64);
            if (tid >= o) inc += t;
        }
        int excl = inc - lsum;
        sOff[b0] = excl;
        sOff[b0 + 1] = excl + s0;
        sOff[b0 + 2] = excl + s0 + s1;
        sOff[b0 + 3] = excl + s0 + s1 + s2;
    }
    __syncthreads();
    int node = (b << 8) + tid;
    if (node < N_) offT[node] = start + sOff[tid];
    __syncthreads();  // offT reads of sOff must precede rank atomics
    for (int i = start + tid; i < end; i += 256) {
        unsigned pk = bufT[i];
        int pos = start + atomicAdd(&sOff[(pk >> 16) & 255], 1);
        eSrc[pos] = (unsigned short)(pk & 0xFFFF);
    }
}

// per-bucket src histogram -> dnorm directly
__global__ __launch_bounds__(256) void finalizeS(const unsigned char* __restrict__ bufS8,
                                                 const int* __restrict__ histG,
                                                 float* __restrict__ dnorm) {
    __shared__ int hist[256];
    int b = blockIdx.x, tid = threadIdx.x;
    int start = histG[HHALF + b * NBK] - E_;
    int end = histG[HHALF + (b + 1) * NBK] - E_;
    hist[tid] = 0;
    __syncthreads();
    for (int i = start + tid; i < end; i += 256) atomicAdd(&hist[bufS8[i]], 1);
    __syncthreads();
    int node = (b << 8) + tid;
    if (node < N_) {
        int dg = hist[tid];
        dnorm[node] = 1.f / (float)(dg > 1 ? dg : 1);
    }
}

// polarity bucket lists (LDS histogram + one global atomic per block-polarity)
__global__ __launch_bounds__(256) void bucket_fill(const int* __restrict__ pol,
                                                   const int* __restrict__ boff,
                                                   int* __restrict__ bcur,
                                                   int* __restrict__ blist) {
    __shared__ int h[P_];
    __shared__ int base[P_];
    int tid = threadIdx.x;
    if (tid < P_) h[tid] = 0;
    __syncthreads();
    int n = blockIdx.x * 256 + tid;
    int p = 0, loc = 0;
    bool act = (n < N_);
    if (act) {
        p = pol[n];
        loc = atomicAdd(&h[p], 1);
    }
    __syncthreads();
    if (tid < P_ && h[tid] > 0) base[tid] = atomicAdd(&bcur[tid], h[tid]);
    __syncthreads();
    if (act) blist[boff[p] + base[p] + loc] = n;
}

// ---------------------------------------------------------------------------
// Weight prep: fp32 -> bf16, transposed to [out_col][k] where needed
// ---------------------------------------------------------------------------

__global__ __launch_bounds__(256) void conv4(const float* __restrict__ x,
                                             unsigned short* __restrict__ xb) {
    int i = blockIdx.x * 256 + threadIdx.x;
    if (i >= N_ * D_ / 4) return;
    float4 v = ((const float4*)x)[i];
    ushort4 o;
    o.x = f2bf(v.x); o.y = f2bf(v.y); o.z = f2bf(v.z); o.w = f2bf(v.w);
    ((ushort4*)xb)[i] = o;
}

// Sb[l][p][c][d] = bf16(S[l][p][d][c] + dS[l][p][d][c])
__global__ __launch_bounds__(256) void prep_S(const float* __restrict__ S,
                                              const float* __restrict__ dS,
                                              unsigned short* __restrict__ Sb) {
    int idx = blockIdx.x * 256 + threadIdx.x;  // L*P*D*D
    int base = idx / (D_ * D_);
    int rem = idx % (D_ * D_);
    int c = rem / D_, d = rem % D_;
    size_t in = (size_t)base * D_ * D_ + (size_t)d * D_ + c;
    Sb[idx] = f2bf(S[in] + dS[in]);
}

__global__ __launch_bounds__(256) void prep_W2(const float* __restrict__ W2,
                                               unsigned short* __restrict__ W2b) {
    int idx = blockIdx.x * 256 + threadIdx.x;  // L*D*D
    W2b[idx] = f2bf(W2[idx]);
}

// T1[l][p][i][k] = sum_j (R+dR)[l][p][i][j] * W1[l][k][j]   (all layers batched)
__global__ void small_gemm1(const float* __restrict__ Rm, const float* __restrict__ dRm,
                            const float* __restrict__ W1, float* __restrict__ T1) {
    int idx = blockIdx.x * 256 + threadIdx.x;  // L*P*D*D
    int l = idx / (P_ * D_ * D_);
    int rem = idx % (D_ * D_);
    int i = rem / D_, k = rem % D_;
    int pi = idx / (D_ * D_);  // l*P + p
    const float* a = Rm + ((size_t)pi * D_ + i) * D_;
    const float* a2 = dRm + ((size_t)pi * D_ + i) * D_;
    const float* w = W1 + ((size_t)l * D_ + k) * D_;
    float acc = 0.f;
#pragma unroll 8
    for (int j = 0; j < D_; ++j) acc += (a[j] + a2[j]) * w[j];
    T1[idx] = acc;
}

// Dmb[l][p][k][d] = bf16( sum_i Wr[l][i][d] * T1[l][p][i][k] )
__global__ void small_gemm2T(const float* __restrict__ Wr, const float* __restrict__ T1,
                             unsigned short* __restrict__ Dmb) {
    int idx = blockIdx.x * 256 + threadIdx.x;  // L*P*D*D
    int l = idx / (P_ * D_ * D_);
    int rem = idx % (D_ * D_);
    int k = rem / D_, d = rem % D_;
    int pi = idx / (D_ * D_);
    const float* t = T1 + (size_t)pi * D_ * D_;
    const float* wr = Wr + (size_t)l * D_ * D_;
    float acc = 0.f;
#pragma unroll 8
    for (int i = 0; i < D_; ++i) acc += wr[i * D_ + d] * t[i * D_ + k];
    Dmb[idx] = f2bf(acc);
}

// ---------------------------------------------------------------------------
// CSR aggregation over bf16 rows; u16 edge sources
// ---------------------------------------------------------------------------

__global__ __launch_bounds__(256) void aggregate_bf(const unsigned short* __restrict__ xt,
                                                    const int* __restrict__ offT,
                                                    const unsigned short* __restrict__ eSrc,
                                                    unsigned short* __restrict__ agg) {
    int nd = blockIdx.x * 4 + (threadIdx.x >> 6);
    if (nd >= N_) return;
    int lane = threadIdx.x & 63;
    int beg = offT[nd], end = offT[nd + 1];
    float ax = 0.f, ay = 0.f;
    int i = beg;
    for (; i + 1 < end; i += 2) {
        unsigned u0 = ((const unsigned*)(xt + (size_t)eSrc[i] * D_))[lane];
        unsigned u1 = ((const unsigned*)(xt + (size_t)eSrc[i + 1] * D_))[lane];
        ax += bflo(u0) + bflo(u1);
        ay += bfhi(u0) + bfhi(u1);
    }
    if (i < end) {
        unsigned u0 = ((const unsigned*)(xt + (size_t)eSrc[i] * D_))[lane];
        ax += bflo(u0);
        ay += bfhi(u0);
    }
    unsigned o = (unsigned)f2bf(ax) | ((unsigned)f2bf(ay) << 16);
    ((unsigned*)(agg + (size_t)nd * D_))[lane] = o;
}

// ---------------------------------------------------------------------------
// MFMA GEMM: 64 rows x 128 cols per block, 4 waves x 16 rows, K=128 resident.
// mfma_f32_16x16x32_bf16; C/D: col=lane&15, row=(lane>>4)*4+reg [m89-verified]
// EPI 0: OutB = bf16(acc)
// EPI 1: pre = dnRow*acc + b1; OutB = bf16(relu(LN(pre)))
// EPI 2: pre = rs*(acc+b2) + xres; o = LN(pre) (+x0add); OutF fp32 (+OutB bf16)
// ---------------------------------------------------------------------------

template <int EPI, bool BUCKETED>
__global__ __launch_bounds__(256) void mfma_gemm(
    const unsigned short* __restrict__ A, const unsigned short* __restrict__ Bw,
    float* __restrict__ OutF, unsigned short* __restrict__ OutB,
    const int* __restrict__ blist, const int* __restrict__ boff,
    const int* __restrict__ tileOff, const float* __restrict__ dnorm,
    const float* __restrict__ bias, const float* __restrict__ g,
    const float* __restrict__ bb, const float* __restrict__ rs_ptr,
    const float* __restrict__ xres, const float* __restrict__ x0add) {
    __shared__ unsigned short smem[8704 + 17408];  // sA 64x136, sB 128x136
    __shared__ int rid[TM];
    __shared__ float dnRow[TM];
    unsigned short* sA = smem;
    unsigned short* sB = smem + 8704;
    float* Ts = (float*)(smem + 8704);  // overlays sB: 64x132 fp32

    int tid = threadIdx.x;
    int b = blockIdx.x;

    int pp = 0, nrows, rowbase;
    if constexpr (BUCKETED) {
        if (b >= tileOff[P_]) return;
        while (pp < P_ - 1 && b >= tileOff[pp + 1]) ++pp;
        int tb = b - tileOff[pp];
        int cnt = boff[pp + 1] - boff[pp];
        nrows = min(TM, cnt - tb * TM);
        rowbase = boff[pp] + tb * TM;
    } else {
        nrows = min(TM, N_ - b * TM);
        rowbase = b * TM;
    }
    const unsigned short* B = Bw + (BUCKETED ? (size_t)pp * D_ * D_ : 0);

    if (tid < TM) {
        int r = (tid < nrows) ? (BUCKETED ? blist[rowbase + tid] : rowbase + tid) : -1;
        rid[tid] = r;
        if constexpr (EPI == 1) dnRow[tid] = (r >= 0) ? dnorm[r] : 1.f;
    }
    __syncthreads();

#pragma unroll
    for (int i = 0; i < 8; ++i) {
        int c = tid + i * 256;
        int r = c >> 4, off = c & 15;
        uint4 v = *(const uint4*)(B + r * 128 + off * 8);
        *(uint4*)(sB + r * 136 + off * 8) = v;
    }
#pragma unroll
    for (int i = 0; i < 4; ++i) {
        int c = tid + i * 256;
        int r = c >> 4, off = c & 15;
        int row = rid[r];
        uint4 v = make_uint4(0, 0, 0, 0);
        if (row >= 0) v = *(const uint4*)(A + (size_t)row * D_ + off * 8);
        *(uint4*)(sA + r * 136 + off * 8) = v;
    }
    __syncthreads();

    int lane = tid & 63, wave = tid >> 6;
    int n = lane & 15, q = lane >> 4;
    int wr = wave * 16;

    f32x4 acc[8];
#pragma unroll
    for (int t = 0; t < 8; ++t) acc[t] = (f32x4){0.f, 0.f, 0.f, 0.f};

#pragma unroll
    for (int k0 = 0; k0 < 4; ++k0) {
        bf16x8 af = *(const bf16x8*)(sA + (wr + n) * 136 + k0 * 32 + q * 8);
#pragma unroll
        for (int t = 0; t < 8; ++t) {
            bf16x8 bf = *(const bf16x8*)(sB + (t * 16 + n) * 136 + k0 * 32 + q * 8);
            acc[t] = __builtin_amdgcn_mfma_f32_16x16x32_bf16(af, bf, acc[t], 0, 0, 0);
        }
    }
    __syncthreads();  // LDS about to be reused

    unsigned short* Tb = sA;  // bf16 out staging, stride 136

    if constexpr (EPI == 0) {
#pragma unroll
        for (int t = 0; t < 8; ++t)
#pragma unroll
            for (int r = 0; r < 4; ++r)
                Tb[(wr + q * 4 + r) * 136 + t * 16 + n] = f2bf(acc[t][r]);
        __syncthreads();
#pragma unroll
        for (int i = 0; i < 4; ++i) {
            int c = tid + i * 256;
            int rr2 = c >> 4, off = c & 15;
            int row = rid[rr2];
            if (row >= 0)
                *(uint4*)(OutB + (size_t)row * D_ + off * 8) =
                    *(const uint4*)(Tb + rr2 * 136 + off * 8);
        }
        return;
    }

    if constexpr (EPI == 1) {
        float rs1[4] = {0, 0, 0, 0}, rs2[4] = {0, 0, 0, 0};
#pragma unroll
        for (int t = 0; t < 8; ++t) {
            int col = t * 16 + n;
            float bia = bias[col];
#pragma unroll
            for (int r = 0; r < 4; ++r) {
                float v = dnRow[wr + q * 4 + r] * acc[t][r] + bia;
                acc[t][r] = v;
                rs1[r] += v;
                rs2[r] += v * v;
            }
        }
#pragma unroll
        for (int mk = 1; mk < 16; mk <<= 1)
#pragma unroll
            for (int r = 0; r < 4; ++r) {
                rs1[r] += __shfl_xor(rs1[r], mk, 64);
                rs2[r] += __shfl_xor(rs2[r], mk, 64);
            }
        float mr[4], rv[4];
#pragma unroll
        for (int r = 0; r < 4; ++r) {
            float mm = rs1[r] * (1.f / 128.f);
            mr[r] = mm;
            rv[r] = rsqrtf(rs2[r] * (1.f / 128.f) - mm * mm + EPS_);
        }
#pragma unroll
        for (int t = 0; t < 8; ++t) {
            int col = t * 16 + n;
            float gg = g[col], bbv = bb[col];
#pragma unroll
            for (int r = 0; r < 4; ++r) {
                float nv = (acc[t][r] - mr[r]) * rv[r] * gg + bbv;
                Tb[(wr + q * 4 + r) * 136 + col] = f2bf(fmaxf(nv, 0.f));
            }
        }
        __syncthreads();
#pragma unroll
        for (int i = 0; i < 4; ++i) {
            int c = tid + i * 256;
            int rr2 = c >> 4, off = c & 15;
            int row = rid[rr2];
            if (row >= 0)
                *(uint4*)(OutB + (size_t)row * D_ + off * 8) =
                    *(const uint4*)(Tb + rr2 * 136 + off * 8);
        }
        return;
    }

    if constexpr (EPI == 2) {
#pragma unroll
        for (int i = 0; i < 8; ++i) {
            int c = tid + i * 256;
            int rr2 = c >> 5, off = c & 31;
            int row = rid[rr2];
            float4 v = make_float4(0, 0, 0, 0);
            if (row >= 0) v = *(const float4*)(xres + (size_t)row * D_ + off * 4);
            *(float4*)(Ts + rr2 * 132 + off * 4) = v;
        }
        __syncthreads();
        float rs = rs_ptr[0];
        float rs1[4] = {0, 0, 0, 0}, rs2[4] = {0, 0, 0, 0};
#pragma unroll
        for (int t = 0; t < 8; ++t) {
            int col = t * 16 + n;
            float bia = bias[col];
#pragma unroll
            for (int r = 0; r < 4; ++r) {
                int row = wr + q * 4 + r;
                float v = rs * (acc[t][r] + bia) + Ts[row * 132 + col];
                acc[t][r] = v;
                rs1[r] += v;
                rs2[r] += v * v;
            }
        }
#pragma unroll
        for (int mk = 1; mk < 16; mk <<= 1)
#pragma unroll
            for (int r = 0; r < 4; ++r) {
                rs1[r] += __shfl_xor(rs1[r], mk, 64);
                rs2[r] += __shfl_xor(rs2[r], mk, 64);
            }
        float mr[4], rv[4];
#pragma unroll
        for (int r = 0; r < 4; ++r) {
            float mm = rs1[r] * (1.f / 128.f);
            mr[r] = mm;
            rv[r] = rsqrtf(rs2[r] * (1.f / 128.f) - mm * mm + EPS_);
        }
        bool hasB = (OutB != nullptr);
#pragma unroll
        for (int t = 0; t < 8; ++t) {
            int col = t * 16 + n;
            float gg = g[col], bbv = bb[col];
#pragma unroll
            for (int r = 0; r < 4; ++r) {
                int row = wr + q * 4 + r;
                float nv = (acc[t][r] - mr[r]) * rv[r] * gg + bbv;
                if (x0add) {
                    int grow = rid[row];
                    if (grow >= 0) nv += x0add[(size_t)grow * D_ + col];
                }
                Ts[row * 132 + col] = nv;
                if (hasB) Tb[row * 136 + col] = f2bf(nv);
            }
        }
        __syncthreads();
#pragma unroll
        for (int i = 0; i < 8; ++i) {
            int c = tid + i * 256;
            int rr2 = c >> 5, off = c & 31;
            int row = rid[rr2];
            if (row >= 0)
                *(float4*)(OutF + (size_t)row * D_ + off * 4) =
                    *(const float4*)(Ts + rr2 * 132 + off * 4);
        }
        if (hasB) {
#pragma unroll
            for (int i = 0; i < 4; ++i) {
                int c = tid + i * 256;
                int rr2 = c >> 4, off = c & 15;
                int row = rid[rr2];
                if (row >= 0)
                    *(uint4*)(OutB + (size_t)row * D_ + off * 8) =
                        *(const uint4*)(Tb + rr2 * 136 + off * 8);
            }
        }
    }
}

// ---------------------------------------------------------------------------
// Host launch
// ---------------------------------------------------------------------------

extern "C" void kernel_launch(void* const* d_in, const int* in_sizes, int n_in,
                              void* d_out, int out_size, void* d_ws, size_t ws_size,
                              hipStream_t stream) {
    const float* x0 = (const float*)d_in[0];
    const int* ei = (const int*)d_in[1];
    const int* ring = (const int*)d_in[2];
    const float* Wr = (const float*)d_in[3];
    const float* S = (const float*)d_in[4];
    const float* dS = (const float*)d_in[5];
    const float* R = (const float*)d_in[6];
    const float* dR = (const float*)d_in[7];
    const float* rsc = (const float*)d_in[8];
    const float* W1 = (const float*)d_in[9];
    const float* b1 = (const float*)d_in[10];
    const float* lng = (const float*)d_in[11];
    const float* lnb = (const float*)d_in[12];
    const float* W2 = (const float*)d_in[13];
    const float* b2 = (const float*)d_in[14];
    const float* ng = (const float*)d_in[15];
    const float* nb = (const float*)d_in[16];
    float* out = (float*)d_out;

    char* w = (char*)d_ws;
    auto alloc = [&](size_t bytes) {
        char* p = w;
        w += (bytes + 15) & ~(size_t)15;
        return p;
    };
    unsigned short* xb = (unsigned short*)alloc((size_t)N_ * D_ * 2);     // bf16 x
    unsigned short* bufAb = (unsigned short*)alloc((size_t)N_ * D_ * 2);  // xt / h
    unsigned short* bufBb = (unsigned short*)alloc((size_t)N_ * D_ * 2);  // agg
    float* xbuf = (float*)alloc((size_t)N_ * D_ * 4);                     // fp32 x
    unsigned short* Sb = (unsigned short*)alloc((size_t)L_ * P_ * D_ * D_ * 2);
    unsigned short* Dmb = (unsigned short*)alloc((size_t)L_ * P_ * D_ * D_ * 2);
    unsigned short* W2b = (unsigned short*)alloc((size_t)L_ * D_ * D_ * 2);
    float* T1 = (float*)alloc((size_t)L_ * P_ * D_ * D_ * 4);
    float* dnorm = (float*)alloc((size_t)N_ * 4);
    int* histG = (int*)alloc((size_t)HTOT * 4);
    unsigned* bufT = (unsigned*)alloc((size_t)E_ * 4);
    unsigned char* bufS8 = (unsigned char*)alloc((size_t)E_);
    unsigned short* eSrc = (unsigned short*)alloc((size_t)E_ * 2);
    int* offT = (int*)alloc((size_t)(N_ + 1) * 4);
    int* pol = (int*)alloc((size_t)N_ * 4);
    int* boff = (int*)alloc((size_t)(P_ + 1) * 4);
    int* tileOff = (int*)alloc((size_t)(P_ + 1) * 4);
    int* blist = (int*)alloc((size_t)N_ * 4);
    int* blkSum = (int*)alloc((size_t)NSB * 4);
    int* blkOff = (int*)alloc((size_t)NSB * 4);
    int* bcnt = (int*)alloc((size_t)2 * P_ * 4);  // zeroed region: bcnt + bcur
    int* bcur = bcnt + P_;

    hipMemsetAsync(bcnt, 0, (size_t)2 * P_ * 4, stream);

    const int NG = (N_ + 255) / 256;
    const int SG = L_ * P_ * D_ * D_ / 256;     // 1728 (batched over layers)
    const int BTILES = N_ / TM + P_;            // bucketed tile upper bound
    const int CTILES = (N_ + TM - 1) / TM;

    node_init<<<NG, 256, 0, stream>>>(ring, pol, bcnt);
    khist<<<NBK, 256, 0, stream>>>(ei, histG);
    scanH1<<<NSB, 1024, 0, stream>>>(histG, blkSum);
    scanH2<<<1, 64, 0, stream>>>(blkSum, blkOff, offT, bcnt, boff, tileOff);
    scanH3<<<NSB, 1024, 0, stream>>>(histG, blkOff);
    scatterTS<<<NBK, 256, 0, stream>>>(ei, histG, bufT, bufS8);
    finalizeT<<<NBUK, 256, 0, stream>>>(bufT, histG, offT, eSrc);
    finalizeS<<<NBUK, 256, 0, stream>>>(bufS8, histG, dnorm);
    bucket_fill<<<NG, 256, 0, stream>>>(pol, boff, bcur, blist);

    conv4<<<(N_ * D_ / 4 + 255) / 256, 256, 0, stream>>>(x0, xb);
    prep_S<<<SG, 256, 0, stream>>>(S, dS, Sb);
    prep_W2<<<L_ * D_ * D_ / 256, 256, 0, stream>>>(W2, W2b);
    small_gemm1<<<SG, 256, 0, stream>>>(R, dR, W1, T1);
    small_gemm2T<<<SG, 256, 0, stream>>>(Wr, T1, Dmb);

    for (int l = 0; l < L_; ++l) {
        const size_t lPDD = (size_t)l * P_ * D_ * D_;
        const size_t lDD = (size_t)l * D_ * D_;
        const size_t lD = (size_t)l * D_;
        // xt = x @ (S+dS)[pol]   -> bf16
        mfma_gemm<0, true><<<BTILES, 256, 0, stream>>>(
            xb, Sb + lPDD, nullptr, bufAb, blist, boff, tileOff,
            nullptr, nullptr, nullptr, nullptr, nullptr, nullptr, nullptr);
        // agg = CSR-sum xt  -> bf16
        aggregate_bf<<<N_ / 4, 256, 0, stream>>>(bufAb, offT, eSrc, bufBb);
        // h = relu(LN(dn * (agg @ Dm[pol]) + b1)) -> bf16
        mfma_gemm<1, true><<<BTILES, 256, 0, stream>>>(
            bufBb, Dmb + lPDD, nullptr, bufAb, blist, boff, tileOff,
            dnorm, b1 + lD, lng + lD, lnb + lD, nullptr, nullptr, nullptr);
        // x' = LN(rs*(h @ W2.T + b2) + x) (+x0 last) -> fp32 (+bf16 for next layer)
        float* xo = (l == L_ - 1) ? out : xbuf;
        const float* xr = (l == 0) ? x0 : xbuf;
        unsigned short* xbn = (l == L_ - 1) ? nullptr : xb;
        mfma_gemm<2, false><<<CTILES, 256, 0, stream>>>(
            bufAb, W2b + lDD, xo, xbn, nullptr, nullptr, nullptr,
            nullptr, b2 + lD, ng + lD, nb + lD, rsc + l, xr,
            (l == L_ - 1) ? x0 : nullptr);
    }
}

// Round 5
// 492.286 us; speedup vs baseline: 2.6364x; 1.1303x over previous
//
#include <hip/hip_runtime.h>
#include <hip/hip_bf16.h>

// Problem constants
constexpr int N_ = 50000;
constexpr int D_ = 128;
constexpr int E_ = 800000;
constexpr int P_ = 9;
constexpr int L_ = 3;
constexpr float EPS_ = 1e-5f;

constexpr int TM = 64;    // rows per GEMM block
constexpr int CHUNK = 4096;                    // edges per hist/scatter block
constexpr int NBK = (E_ + CHUNK - 1) / CHUNK;  // 196 edge chunks
constexpr int NBUK = 196;                      // node buckets (50000>>8 = 195 max)
constexpr int HHALF = 256 * NBK;               // 50176 (per-half hist size)
constexpr int HTOT = 2 * HHALF;                // 100352 = 98 * 1024 exactly
constexpr int NSB = HTOT / 1024;               // 98 scan blocks

typedef short bf16x8 __attribute__((ext_vector_type(8)));
typedef float f32x4 __attribute__((ext_vector_type(4)));

__device__ inline unsigned short f2bf(float f) {
    __hip_bfloat16 h = __float2bfloat16(f);
    return *reinterpret_cast<unsigned short*>(&h);
}
__device__ inline float bflo(unsigned u) { return __uint_as_float(u << 16); }
__device__ inline float bfhi(unsigned u) { return __uint_as_float(u & 0xffff0000u); }

// ---------------------------------------------------------------------------
// Node polarity init (LDS histogram; 9 global atomics per block)
// ---------------------------------------------------------------------------

__global__ __launch_bounds__(256) void node_init(const int* __restrict__ ring,
                                                 int* __restrict__ pol,
                                                 int* __restrict__ bcnt) {
    __shared__ int h[P_];
    int tid = threadIdx.x;
    if (tid < P_) h[tid] = 0;
    __syncthreads();
    int n = blockIdx.x * 256 + tid;
    if (n < N_) {
        int p = ring[n] % P_;
        pol[n] = p;
        atomicAdd(&h[p], 1);
    }
    __syncthreads();
    if (tid < P_ && h[tid] > 0) atomicAdd(&bcnt[tid], h[tid]);
}

// ---------------------------------------------------------------------------
// CSR build via bucket sort (no node-granular global atomics)
// ---------------------------------------------------------------------------

__global__ __launch_bounds__(256) void khist(const int* __restrict__ ei,
                                             int* __restrict__ histG) {
    __shared__ int hT[256], hS[256];
    int blk = blockIdx.x, tid = threadIdx.x;
    hT[tid] = 0;
    hS[tid] = 0;
    __syncthreads();
    int base = blk * CHUNK;
#pragma unroll
    for (int i = 0; i < CHUNK / 256; ++i) {
        int e = base + tid + i * 256;
        if (e < E_) {
            atomicAdd(&hS[ei[e] >> 8], 1);
            atomicAdd(&hT[ei[E_ + e] >> 8], 1);
        }
    }
    __syncthreads();
    histG[tid * NBK + blk] = hT[tid];
    histG[HHALF + tid * NBK + blk] = hS[tid];
}

__global__ __launch_bounds__(1024) void scanH1(int* __restrict__ a,
                                               int* __restrict__ blkSum) {
    __shared__ int wsum[16];
    int tid = threadIdx.x, lane = tid & 63, wid = tid >> 6;
    int idx = blockIdx.x * 1024 + tid;
    int v = a[idx];
    int inc = v;
#pragma unroll
    for (int o = 1; o < 64; o <<= 1) {
        int t = __shfl_up(inc, o, 64);
        if (lane >= o) inc += t;
    }
    if (lane == 63) wsum[wid] = inc;
    __syncthreads();
    if (tid < 16) {
        int s = wsum[tid];
#pragma unroll
        for (int o = 1; o < 16; o <<= 1) {
            int t = __shfl_up(s, o, 64);
            if (tid >= o) s += t;
        }
        wsum[tid] = s;
    }
    __syncthreads();
    int wexcl = (wid == 0) ? 0 : wsum[wid - 1];
    a[idx] = wexcl + inc - v;
    if (tid == 1023) blkSum[blockIdx.x] = wsum[15];
}

__global__ void scanH2(const int* __restrict__ blkSum, int* __restrict__ blkOff,
                       int* __restrict__ offT, const int* __restrict__ bcnt,
                       int* __restrict__ boff, int* __restrict__ tileOff) {
    if (threadIdx.x != 0) return;
    int run = 0;
    for (int i = 0; i < NSB; ++i) {
        blkOff[i] = run;
        run += blkSum[i];
    }
    offT[N_] = E_;
    boff[0] = 0;
    tileOff[0] = 0;
    for (int p = 0; p < P_; ++p) {
        boff[p + 1] = boff[p] + bcnt[p];
        tileOff[p + 1] = tileOff[p] + (bcnt[p] + TM - 1) / TM;
    }
}

__global__ __launch_bounds__(1024) void scanH3(int* __restrict__ a,
                                               const int* __restrict__ blkOff) {
    int idx = blockIdx.x * 1024 + threadIdx.x;
    a[idx] += blkOff[blockIdx.x];
}

__global__ __launch_bounds__(256) void scatterTS(const int* __restrict__ ei,
                                                 const int* __restrict__ histG,
                                                 unsigned* __restrict__ bufT,
                                                 unsigned char* __restrict__ bufS8) {
    __shared__ int ldsT[256], ldsS[256];
    int blk = blockIdx.x, tid = threadIdx.x;
    ldsT[tid] = histG[tid * NBK + blk];
    ldsS[tid] = histG[HHALF + tid * NBK + blk] - E_;
    __syncthreads();
    int base = blk * CHUNK;
#pragma unroll
    for (int i = 0; i < CHUNK / 256; ++i) {
        int e = base + tid + i * 256;
        if (e < E_) {
            int s = ei[e], t = ei[E_ + e];
            int pT = atomicAdd(&ldsT[t >> 8], 1);
            bufT[pT] = ((unsigned)t << 16) | (unsigned)s;
            int pS = atomicAdd(&ldsS[s >> 8], 1);
            bufS8[pS] = (unsigned char)(s & 255);
        }
    }
}

__global__ __launch_bounds__(256) void finalizeT(const unsigned* __restrict__ bufT,
                                                 const int* __restrict__ histG,
                                                 int* __restrict__ offT,
                                                 unsigned short* __restrict__ eSrc) {
    __shared__ int hist[256];
    __shared__ int sOff[256];
    int b = blockIdx.x, tid = threadIdx.x;
    int start = histG[b * NBK];
    int end = histG[(b + 1) * NBK];
    hist[tid] = 0;
    __syncthreads();
    for (int i = start + tid; i < end; i += 256)
        atomicAdd(&hist[(bufT[i] >> 16) & 255], 1);
    __syncthreads();
    if (tid < 64) {
        int b0 = 4 * tid;
        int s0 = hist[b0], s1 = hist[b0 + 1], s2 = hist[b0 + 2], s3 = hist[b0 + 3];
        int lsum = s0 + s1 + s2 + s3;
        int inc = lsum;
#pragma unroll
        for (int o = 1; o < 64; o <<= 1) {
            int t = __shfl_up(inc, o, 64);
            if (tid >= o) inc += t;
        }
        int excl = inc - lsum;
        sOff[b0] = excl;
        sOff[b0 + 1] = excl + s0;
        sOff[b0 + 2] = excl + s0 + s1;
        sOff[b0 + 3] = excl + s0 + s1 + s2;
    }
    __syncthreads();
    int node = (b << 8) + tid;
    if (node < N_) offT[node] = start + sOff[tid];
    __syncthreads();
    for (int i = start + tid; i < end; i += 256) {
        unsigned pk = bufT[i];
        int pos = start + atomicAdd(&sOff[(pk >> 16) & 255], 1);
        eSrc[pos] = (unsigned short)(pk & 0xFFFF);
    }
}

__global__ __launch_bounds__(256) void finalizeS(const unsigned char* __restrict__ bufS8,
                                                 const int* __restrict__ histG,
                                                 float* __restrict__ dnorm) {
    __shared__ int hist[256];
    int b = blockIdx.x, tid = threadIdx.x;
    int start = histG[HHALF + b * NBK] - E_;
    int end = histG[HHALF + (b + 1) * NBK] - E_;
    hist[tid] = 0;
    __syncthreads();
    for (int i = start + tid; i < end; i += 256) atomicAdd(&hist[bufS8[i]], 1);
    __syncthreads();
    int node = (b << 8) + tid;
    if (node < N_) {
        int dg = hist[tid];
        dnorm[node] = 1.f / (float)(dg > 1 ? dg : 1);
    }
}

__global__ __launch_bounds__(256) void bucket_fill(const int* __restrict__ pol,
                                                   const int* __restrict__ boff,
                                                   int* __restrict__ bcur,
                                                   int* __restrict__ blist) {
    __shared__ int h[P_];
    __shared__ int base[P_];
    int tid = threadIdx.x;
    if (tid < P_) h[tid] = 0;
    __syncthreads();
    int n = blockIdx.x * 256 + tid;
    int p = 0, loc = 0;
    bool act = (n < N_);
    if (act) {
        p = pol[n];
        loc = atomicAdd(&h[p], 1);
    }
    __syncthreads();
    if (tid < P_ && h[tid] > 0) base[tid] = atomicAdd(&bcur[tid], h[tid]);
    __syncthreads();
    if (act) blist[boff[p] + base[p] + loc] = n;
}

// ---------------------------------------------------------------------------
// Weight prep
// ---------------------------------------------------------------------------

__global__ __launch_bounds__(256) void conv4(const float* __restrict__ x,
                                             unsigned short* __restrict__ xb) {
    int i = blockIdx.x * 256 + threadIdx.x;
    if (i >= N_ * D_ / 4) return;
    float4 v = ((const float4*)x)[i];
    ushort4 o;
    o.x = f2bf(v.x); o.y = f2bf(v.y); o.z = f2bf(v.z); o.w = f2bf(v.w);
    ((ushort4*)xb)[i] = o;
}

// zero the dummy gather row xt[N_] (used for tail-step padding in aggregate)
__global__ void zero_row(unsigned short* __restrict__ bufAb) {
    ((unsigned*)(bufAb + (size_t)N_ * D_))[threadIdx.x] = 0;
}

__global__ __launch_bounds__(256) void prep_S(const float* __restrict__ S,
                                              const float* __restrict__ dS,
                                              unsigned short* __restrict__ Sb) {
    int idx = blockIdx.x * 256 + threadIdx.x;  // L*P*D*D
    int base = idx / (D_ * D_);
    int rem = idx % (D_ * D_);
    int c = rem / D_, d = rem % D_;
    size_t in = (size_t)base * D_ * D_ + (size_t)d * D_ + c;
    Sb[idx] = f2bf(S[in] + dS[in]);
}

__global__ __launch_bounds__(256) void prep_W2(const float* __restrict__ W2,
                                               unsigned short* __restrict__ W2b) {
    int idx = blockIdx.x * 256 + threadIdx.x;  // L*D*D
    W2b[idx] = f2bf(W2[idx]);
}

__global__ void small_gemm1(const float* __restrict__ Rm, const float* __restrict__ dRm,
                            const float* __restrict__ W1, float* __restrict__ T1) {
    int idx = blockIdx.x * 256 + threadIdx.x;  // L*P*D*D
    int l = idx / (P_ * D_ * D_);
    int rem = idx % (D_ * D_);
    int i = rem / D_, k = rem % D_;
    int pi = idx / (D_ * D_);
    const float* a = Rm + ((size_t)pi * D_ + i) * D_;
    const float* a2 = dRm + ((size_t)pi * D_ + i) * D_;
    const float* w = W1 + ((size_t)l * D_ + k) * D_;
    float acc = 0.f;
#pragma unroll 8
    for (int j = 0; j < D_; ++j) acc += (a[j] + a2[j]) * w[j];
    T1[idx] = acc;
}

__global__ void small_gemm2T(const float* __restrict__ Wr, const float* __restrict__ T1,
                             unsigned short* __restrict__ Dmb) {
    int idx = blockIdx.x * 256 + threadIdx.x;  // L*P*D*D
    int l = idx / (P_ * D_ * D_);
    int rem = idx % (D_ * D_);
    int k = rem / D_, d = rem % D_;
    int pi = idx / (D_ * D_);
    const float* t = T1 + (size_t)pi * D_ * D_;
    const float* wr = Wr + (size_t)l * D_ * D_;
    float acc = 0.f;
#pragma unroll 8
    for (int i = 0; i < D_; ++i) acc += wr[i * D_ + d] * t[i * D_ + k];
    Dmb[idx] = f2bf(acc);
}

// ---------------------------------------------------------------------------
// CSR aggregation, MLP-optimized:
//  - lane-parallel index preload (1 vmem per 64 edges) + ds_bpermute broadcast
//  - 16 lanes per row, dwordx4 gathers (4 edges per step), 2 steps in flight
//  - invalid tail steps redirect to zero row xt[N_] (no divergent loads)
// ---------------------------------------------------------------------------

__device__ inline void accum_row(float* acc, uint4 r) {
    acc[0] += bflo(r.x); acc[1] += bfhi(r.x);
    acc[2] += bflo(r.y); acc[3] += bfhi(r.y);
    acc[4] += bflo(r.z); acc[5] += bfhi(r.z);
    acc[6] += bflo(r.w); acc[7] += bfhi(r.w);
}

__global__ __launch_bounds__(256) void aggregate_bf(const unsigned short* __restrict__ xt,
                                                    const int* __restrict__ offT,
                                                    const unsigned short* __restrict__ eSrc,
                                                    unsigned short* __restrict__ agg) {
    int nd = blockIdx.x * 4 + (threadIdx.x >> 6);
    if (nd >= N_) return;
    int l = threadIdx.x & 63;
    int g = l >> 4, c16 = l & 15;
    int beg = offT[nd], end = offT[nd + 1];

    float acc[8];
#pragma unroll
    for (int k = 0; k < 8; ++k) acc[k] = 0.f;

    for (int base = beg; base < end; base += 64) {
        int cnt = min(64, end - base);
        int idxv = 0;
        if (l < cnt) idxv = (int)eSrc[base + l];
        int steps = (cnt + 3) >> 2;
        int j = 0;
        for (; j + 1 < steps; j += 2) {
            int e0 = 4 * j + g, e1 = e0 + 4;
            int i0 = __shfl(idxv, e0, 64);
            int i1 = __shfl(idxv, e1, 64);
            int r0 = (e0 < cnt) ? i0 : N_;
            int r1 = (e1 < cnt) ? i1 : N_;
            uint4 v0 = ((const uint4*)(xt + (size_t)r0 * D_))[c16];
            uint4 v1 = ((const uint4*)(xt + (size_t)r1 * D_))[c16];
            accum_row(acc, v0);
            accum_row(acc, v1);
        }
        if (j < steps) {
            int e0 = 4 * j + g;
            int i0 = __shfl(idxv, e0, 64);
            int r0 = (e0 < cnt) ? i0 : N_;
            uint4 v0 = ((const uint4*)(xt + (size_t)r0 * D_))[c16];
            accum_row(acc, v0);
        }
    }
    // combine 4 edge-groups
#pragma unroll
    for (int k = 0; k < 8; ++k) {
        acc[k] += __shfl_xor(acc[k], 16, 64);
        acc[k] += __shfl_xor(acc[k], 32, 64);
    }
    if (g == 0) {
        uint4 o;
        o.x = (unsigned)f2bf(acc[0]) | ((unsigned)f2bf(acc[1]) << 16);
        o.y = (unsigned)f2bf(acc[2]) | ((unsigned)f2bf(acc[3]) << 16);
        o.z = (unsigned)f2bf(acc[4]) | ((unsigned)f2bf(acc[5]) << 16);
        o.w = (unsigned)f2bf(acc[6]) | ((unsigned)f2bf(acc[7]) << 16);
        ((uint4*)(agg + (size_t)nd * D_))[c16] = o;
    }
}

// ---------------------------------------------------------------------------
// MFMA GEMM: 64 rows x 128 cols per block, 4 waves x 16 rows, K=128 resident.
// mfma_f32_16x16x32_bf16; C/D: col=lane&15, row=(lane>>4)*4+reg [m89-verified]
// ---------------------------------------------------------------------------

template <int EPI, bool BUCKETED>
__global__ __launch_bounds__(256) void mfma_gemm(
    const unsigned short* __restrict__ A, const unsigned short* __restrict__ Bw,
    float* __restrict__ OutF, unsigned short* __restrict__ OutB,
    const int* __restrict__ blist, const int* __restrict__ boff,
    const int* __restrict__ tileOff, const float* __restrict__ dnorm,
    const float* __restrict__ bias, const float* __restrict__ g,
    const float* __restrict__ bb, const float* __restrict__ rs_ptr,
    const float* __restrict__ xres, const float* __restrict__ x0add) {
    __shared__ unsigned short smem[8704 + 17408];  // sA 64x136, sB 128x136
    __shared__ int rid[TM];
    __shared__ float dnRow[TM];
    unsigned short* sA = smem;
    unsigned short* sB = smem + 8704;
    float* Ts = (float*)(smem + 8704);  // overlays sB: 64x132 fp32

    int tid = threadIdx.x;
    int b = blockIdx.x;

    int pp = 0, nrows, rowbase;
    if constexpr (BUCKETED) {
        if (b >= tileOff[P_]) return;
        while (pp < P_ - 1 && b >= tileOff[pp + 1]) ++pp;
        int tb = b - tileOff[pp];
        int cnt = boff[pp + 1] - boff[pp];
        nrows = min(TM, cnt - tb * TM);
        rowbase = boff[pp] + tb * TM;
    } else {
        nrows = min(TM, N_ - b * TM);
        rowbase = b * TM;
    }
    const unsigned short* B = Bw + (BUCKETED ? (size_t)pp * D_ * D_ : 0);

    if (tid < TM) {
        int r = (tid < nrows) ? (BUCKETED ? blist[rowbase + tid] : rowbase + tid) : -1;
        rid[tid] = r;
        if constexpr (EPI == 1) dnRow[tid] = (r >= 0) ? dnorm[r] : 1.f;
    }
    __syncthreads();

#pragma unroll
    for (int i = 0; i < 8; ++i) {
        int c = tid + i * 256;
        int r = c >> 4, off = c & 15;
        uint4 v = *(const uint4*)(B + r * 128 + off * 8);
        *(uint4*)(sB + r * 136 + off * 8) = v;
    }
#pragma unroll
    for (int i = 0; i < 4; ++i) {
        int c = tid + i * 256;
        int r = c >> 4, off = c & 15;
        int row = rid[r];
        uint4 v = make_uint4(0, 0, 0, 0);
        if (row >= 0) v = *(const uint4*)(A + (size_t)row * D_ + off * 8);
        *(uint4*)(sA + r * 136 + off * 8) = v;
    }
    __syncthreads();

    int lane = tid & 63, wave = tid >> 6;
    int n = lane & 15, q = lane >> 4;
    int wr = wave * 16;

    f32x4 acc[8];
#pragma unroll
    for (int t = 0; t < 8; ++t) acc[t] = (f32x4){0.f, 0.f, 0.f, 0.f};

#pragma unroll
    for (int k0 = 0; k0 < 4; ++k0) {
        bf16x8 af = *(const bf16x8*)(sA + (wr + n) * 136 + k0 * 32 + q * 8);
#pragma unroll
        for (int t = 0; t < 8; ++t) {
            bf16x8 bf = *(const bf16x8*)(sB + (t * 16 + n) * 136 + k0 * 32 + q * 8);
            acc[t] = __builtin_amdgcn_mfma_f32_16x16x32_bf16(af, bf, acc[t], 0, 0, 0);
        }
    }
    __syncthreads();  // LDS about to be reused

    unsigned short* Tb = sA;  // bf16 out staging, stride 136

    if constexpr (EPI == 0) {
#pragma unroll
        for (int t = 0; t < 8; ++t)
#pragma unroll
            for (int r = 0; r < 4; ++r)
                Tb[(wr + q * 4 + r) * 136 + t * 16 + n] = f2bf(acc[t][r]);
        __syncthreads();
#pragma unroll
        for (int i = 0; i < 4; ++i) {
            int c = tid + i * 256;
            int rr2 = c >> 4, off = c & 15;
            int row = rid[rr2];
            if (row >= 0)
                *(uint4*)(OutB + (size_t)row * D_ + off * 8) =
                    *(const uint4*)(Tb + rr2 * 136 + off * 8);
        }
        return;
    }

    if constexpr (EPI == 1) {
        float rs1[4] = {0, 0, 0, 0}, rs2[4] = {0, 0, 0, 0};
#pragma unroll
        for (int t = 0; t < 8; ++t) {
            int col = t * 16 + n;
            float bia = bias[col];
#pragma unroll
            for (int r = 0; r < 4; ++r) {
                float v = dnRow[wr + q * 4 + r] * acc[t][r] + bia;
                acc[t][r] = v;
                rs1[r] += v;
                rs2[r] += v * v;
            }
        }
#pragma unroll
        for (int mk = 1; mk < 16; mk <<= 1)
#pragma unroll
            for (int r = 0; r < 4; ++r) {
                rs1[r] += __shfl_xor(rs1[r], mk, 64);
                rs2[r] += __shfl_xor(rs2[r], mk, 64);
            }
        float mr[4], rv[4];
#pragma unroll
        for (int r = 0; r < 4; ++r) {
            float mm = rs1[r] * (1.f / 128.f);
            mr[r] = mm;
            rv[r] = rsqrtf(rs2[r] * (1.f / 128.f) - mm * mm + EPS_);
        }
#pragma unroll
        for (int t = 0; t < 8; ++t) {
            int col = t * 16 + n;
            float gg = g[col], bbv = bb[col];
#pragma unroll
            for (int r = 0; r < 4; ++r) {
                float nv = (acc[t][r] - mr[r]) * rv[r] * gg + bbv;
                Tb[(wr + q * 4 + r) * 136 + col] = f2bf(fmaxf(nv, 0.f));
            }
        }
        __syncthreads();
#pragma unroll
        for (int i = 0; i < 4; ++i) {
            int c = tid + i * 256;
            int rr2 = c >> 4, off = c & 15;
            int row = rid[rr2];
            if (row >= 0)
                *(uint4*)(OutB + (size_t)row * D_ + off * 8) =
                    *(const uint4*)(Tb + rr2 * 136 + off * 8);
        }
        return;
    }

    if constexpr (EPI == 2) {
#pragma unroll
        for (int i = 0; i < 8; ++i) {
            int c = tid + i * 256;
            int rr2 = c >> 5, off = c & 31;
            int row = rid[rr2];
            float4 v = make_float4(0, 0, 0, 0);
            if (row >= 0) v = *(const float4*)(xres + (size_t)row * D_ + off * 4);
            *(float4*)(Ts + rr2 * 132 + off * 4) = v;
        }
        __syncthreads();
        float rs = rs_ptr[0];
        float rs1[4] = {0, 0, 0, 0}, rs2[4] = {0, 0, 0, 0};
#pragma unroll
        for (int t = 0; t < 8; ++t) {
            int col = t * 16 + n;
            float bia = bias[col];
#pragma unroll
            for (int r = 0; r < 4; ++r) {
                int row = wr + q * 4 + r;
                float v = rs * (acc[t][r] + bia) + Ts[row * 132 + col];
                acc[t][r] = v;
                rs1[r] += v;
                rs2[r] += v * v;
            }
        }
#pragma unroll
        for (int mk = 1; mk < 16; mk <<= 1)
#pragma unroll
            for (int r = 0; r < 4; ++r) {
                rs1[r] += __shfl_xor(rs1[r], mk, 64);
                rs2[r] += __shfl_xor(rs2[r], mk, 64);
            }
        float mr[4], rv[4];
#pragma unroll
        for (int r = 0; r < 4; ++r) {
            float mm = rs1[r] * (1.f / 128.f);
            mr[r] = mm;
            rv[r] = rsqrtf(rs2[r] * (1.f / 128.f) - mm * mm + EPS_);
        }
        bool hasB = (OutB != nullptr);
#pragma unroll
        for (int t = 0; t < 8; ++t) {
            int col = t * 16 + n;
            float gg = g[col], bbv = bb[col];
#pragma unroll
            for (int r = 0; r < 4; ++r) {
                int row = wr + q * 4 + r;
                float nv = (acc[t][r] - mr[r]) * rv[r] * gg + bbv;
                if (x0add) {
                    int grow = rid[row];
                    if (grow >= 0) nv += x0add[(size_t)grow * D_ + col];
                }
                Ts[row * 132 + col] = nv;
                if (hasB) Tb[row * 136 + col] = f2bf(nv);
            }
        }
        __syncthreads();
#pragma unroll
        for (int i = 0; i < 8; ++i) {
            int c = tid + i * 256;
            int rr2 = c >> 5, off = c & 31;
            int row = rid[rr2];
            if (row >= 0)
                *(float4*)(OutF + (size_t)row * D_ + off * 4) =
                    *(const float4*)(Ts + rr2 * 132 + off * 4);
        }
        if (hasB) {
#pragma unroll
            for (int i = 0; i < 4; ++i) {
                int c = tid + i * 256;
                int rr2 = c >> 4, off = c & 15;
                int row = rid[rr2];
                if (row >= 0)
                    *(uint4*)(OutB + (size_t)row * D_ + off * 8) =
                        *(const uint4*)(Tb + rr2 * 136 + off * 8);
            }
        }
    }
}

// ---------------------------------------------------------------------------
// Host launch
// ---------------------------------------------------------------------------

extern "C" void kernel_launch(void* const* d_in, const int* in_sizes, int n_in,
                              void* d_out, int out_size, void* d_ws, size_t ws_size,
                              hipStream_t stream) {
    const float* x0 = (const float*)d_in[0];
    const int* ei = (const int*)d_in[1];
    const int* ring = (const int*)d_in[2];
    const float* Wr = (const float*)d_in[3];
    const float* S = (const float*)d_in[4];
    const float* dS = (const float*)d_in[5];
    const float* R = (const float*)d_in[6];
    const float* dR = (const float*)d_in[7];
    const float* rsc = (const float*)d_in[8];
    const float* W1 = (const float*)d_in[9];
    const float* b1 = (const float*)d_in[10];
    const float* lng = (const float*)d_in[11];
    const float* lnb = (const float*)d_in[12];
    const float* W2 = (const float*)d_in[13];
    const float* b2 = (const float*)d_in[14];
    const float* ng = (const float*)d_in[15];
    const float* nb = (const float*)d_in[16];
    float* out = (float*)d_out;

    char* w = (char*)d_ws;
    auto alloc = [&](size_t bytes) {
        char* p = w;
        w += (bytes + 15) & ~(size_t)15;
        return p;
    };
    unsigned short* xb = (unsigned short*)alloc((size_t)N_ * D_ * 2);          // bf16 x
    unsigned short* bufAb = (unsigned short*)alloc((size_t)(N_ + 1) * D_ * 2); // xt / h (+zero row)
    unsigned short* bufBb = (unsigned short*)alloc((size_t)N_ * D_ * 2);       // agg
    float* xbuf = (float*)alloc((size_t)N_ * D_ * 4);                          // fp32 x
    unsigned short* Sb = (unsigned short*)alloc((size_t)L_ * P_ * D_ * D_ * 2);
    unsigned short* Dmb = (unsigned short*)alloc((size_t)L_ * P_ * D_ * D_ * 2);
    unsigned short* W2b = (unsigned short*)alloc((size_t)L_ * D_ * D_ * 2);
    float* T1 = (float*)alloc((size_t)L_ * P_ * D_ * D_ * 4);
    float* dnorm = (float*)alloc((size_t)N_ * 4);
    int* histG = (int*)alloc((size_t)HTOT * 4);
    unsigned* bufT = (unsigned*)alloc((size_t)E_ * 4);
    unsigned char* bufS8 = (unsigned char*)alloc((size_t)E_);
    unsigned short* eSrc = (unsigned short*)alloc((size_t)E_ * 2);
    int* offT = (int*)alloc((size_t)(N_ + 1) * 4);
    int* pol = (int*)alloc((size_t)N_ * 4);
    int* boff = (int*)alloc((size_t)(P_ + 1) * 4);
    int* tileOff = (int*)alloc((size_t)(P_ + 1) * 4);
    int* blist = (int*)alloc((size_t)N_ * 4);
    int* blkSum = (int*)alloc((size_t)NSB * 4);
    int* blkOff = (int*)alloc((size_t)NSB * 4);
    int* bcnt = (int*)alloc((size_t)2 * P_ * 4);  // zeroed region: bcnt + bcur
    int* bcur = bcnt + P_;

    hipMemsetAsync(bcnt, 0, (size_t)2 * P_ * 4, stream);

    const int NG = (N_ + 255) / 256;
    const int SG = L_ * P_ * D_ * D_ / 256;
    const int BTILES = N_ / TM + P_;
    const int CTILES = (N_ + TM - 1) / TM;

    node_init<<<NG, 256, 0, stream>>>(ring, pol, bcnt);
    khist<<<NBK, 256, 0, stream>>>(ei, histG);
    scanH1<<<NSB, 1024, 0, stream>>>(histG, blkSum);
    scanH2<<<1, 64, 0, stream>>>(blkSum, blkOff, offT, bcnt, boff, tileOff);
    scanH3<<<NSB, 1024, 0, stream>>>(histG, blkOff);
    scatterTS<<<NBK, 256, 0, stream>>>(ei, histG, bufT, bufS8);
    finalizeT<<<NBUK, 256, 0, stream>>>(bufT, histG, offT, eSrc);
    finalizeS<<<NBUK, 256, 0, stream>>>(bufS8, histG, dnorm);
    bucket_fill<<<NG, 256, 0, stream>>>(pol, boff, bcur, blist);

    conv4<<<(N_ * D_ / 4 + 255) / 256, 256, 0, stream>>>(x0, xb);
    zero_row<<<1, 64, 0, stream>>>(bufAb);
    prep_S<<<SG, 256, 0, stream>>>(S, dS, Sb);
    prep_W2<<<L_ * D_ * D_ / 256, 256, 0, stream>>>(W2, W2b);
    small_gemm1<<<SG, 256, 0, stream>>>(R, dR, W1, T1);
    small_gemm2T<<<SG, 256, 0, stream>>>(Wr, T1, Dmb);

    for (int l = 0; l < L_; ++l) {
        const size_t lPDD = (size_t)l * P_ * D_ * D_;
        const size_t lDD = (size_t)l * D_ * D_;
        const size_t lD = (size_t)l * D_;
        // xt = x @ (S+dS)[pol]   -> bf16
        mfma_gemm<0, true><<<BTILES, 256, 0, stream>>>(
            xb, Sb + lPDD, nullptr, bufAb, blist, boff, tileOff,
            nullptr, nullptr, nullptr, nullptr, nullptr, nullptr, nullptr);
        // agg = CSR-sum xt  -> bf16
        aggregate_bf<<<N_ / 4, 256, 0, stream>>>(bufAb, offT, eSrc, bufBb);
        // h = relu(LN(dn * (agg @ Dm[pol]) + b1)) -> bf16
        mfma_gemm<1, true><<<BTILES, 256, 0, stream>>>(
            bufBb, Dmb + lPDD, nullptr, bufAb, blist, boff, tileOff,
            dnorm, b1 + lD, lng + lD, lnb + lD, nullptr, nullptr, nullptr);
        // x' = LN(rs*(h @ W2.T + b2) + x) (+x0 last) -> fp32 (+bf16 for next layer)
        float* xo = (l == L_ - 1) ? out : xbuf;
        const float* xr = (l == 0) ? x0 : xbuf;
        unsigned short* xbn = (l == L_ - 1) ? nullptr : xb;
        mfma_gemm<2, false><<<CTILES, 256, 0, stream>>>(
            bufAb, W2b + lDD, xo, xbn, nullptr, nullptr, nullptr,
            nullptr, b2 + lD, ng + lD, nb + lD, rsc + l, xr,
            (l == L_ - 1) ? x0 : nullptr);
    }
}

// Round 6
// 469.722 us; speedup vs baseline: 2.7631x; 1.0480x over previous
//
#include <hip/hip_runtime.h>
#include <hip/hip_bf16.h>

// Problem constants
constexpr int N_ = 50000;
constexpr int D_ = 128;
constexpr int E_ = 800000;
constexpr int P_ = 9;
constexpr int L_ = 3;
constexpr float EPS_ = 1e-5f;

constexpr int TM = 64;    // rows per GEMM block
constexpr int CHUNK = 4096;                    // edges per hist/scatter block
constexpr int NBK = (E_ + CHUNK - 1) / CHUNK;  // 196 edge chunks
constexpr int NBUK = 196;                      // node buckets (50000>>8 = 195 max)
constexpr int HHALF = 256 * NBK;               // 50176 (per-half hist size)
constexpr int HTOT = 2 * HHALF;                // 100352 = 98 * 1024 exactly
constexpr int NSB = HTOT / 1024;               // 98 scan blocks
constexpr int MAT = L_ * P_;                   // 27 small matrices per operand set

typedef short bf16x8 __attribute__((ext_vector_type(8)));
typedef float f32x4 __attribute__((ext_vector_type(4)));

__device__ inline unsigned short f2bf(float f) {
    __hip_bfloat16 h = __float2bfloat16(f);
    return *reinterpret_cast<unsigned short*>(&h);
}
__device__ inline float bflo(unsigned u) { return __uint_as_float(u << 16); }
__device__ inline float bfhi(unsigned u) { return __uint_as_float(u & 0xffff0000u); }
__device__ inline float bf2f(unsigned short h) {
    return __uint_as_float((unsigned)h << 16);
}

// ---------------------------------------------------------------------------
// Node polarity init (LDS histogram; 9 global atomics per block)
// ---------------------------------------------------------------------------

__global__ __launch_bounds__(256) void node_init(const int* __restrict__ ring,
                                                 int* __restrict__ pol,
                                                 int* __restrict__ bcnt) {
    __shared__ int h[P_];
    int tid = threadIdx.x;
    if (tid < P_) h[tid] = 0;
    __syncthreads();
    int n = blockIdx.x * 256 + tid;
    if (n < N_) {
        int p = ring[n] % P_;
        pol[n] = p;
        atomicAdd(&h[p], 1);
    }
    __syncthreads();
    if (tid < P_ && h[tid] > 0) atomicAdd(&bcnt[tid], h[tid]);
}

// ---------------------------------------------------------------------------
// CSR build via bucket sort (no node-granular global atomics)
// ---------------------------------------------------------------------------

__global__ __launch_bounds__(256) void khist(const int* __restrict__ ei,
                                             int* __restrict__ histG) {
    __shared__ int hT[256], hS[256];
    int blk = blockIdx.x, tid = threadIdx.x;
    hT[tid] = 0;
    hS[tid] = 0;
    __syncthreads();
    int base = blk * CHUNK;
#pragma unroll
    for (int i = 0; i < CHUNK / 256; ++i) {
        int e = base + tid + i * 256;
        if (e < E_) {
            atomicAdd(&hS[ei[e] >> 8], 1);
            atomicAdd(&hT[ei[E_ + e] >> 8], 1);
        }
    }
    __syncthreads();
    histG[tid * NBK + blk] = hT[tid];
    histG[HHALF + tid * NBK + blk] = hS[tid];
}

__global__ __launch_bounds__(1024) void scanH1(int* __restrict__ a,
                                               int* __restrict__ blkSum) {
    __shared__ int wsum[16];
    int tid = threadIdx.x, lane = tid & 63, wid = tid >> 6;
    int idx = blockIdx.x * 1024 + tid;
    int v = a[idx];
    int inc = v;
#pragma unroll
    for (int o = 1; o < 64; o <<= 1) {
        int t = __shfl_up(inc, o, 64);
        if (lane >= o) inc += t;
    }
    if (lane == 63) wsum[wid] = inc;
    __syncthreads();
    if (tid < 16) {
        int s = wsum[tid];
#pragma unroll
        for (int o = 1; o < 16; o <<= 1) {
            int t = __shfl_up(s, o, 64);
            if (tid >= o) s += t;
        }
        wsum[tid] = s;
    }
    __syncthreads();
    int wexcl = (wid == 0) ? 0 : wsum[wid - 1];
    a[idx] = wexcl + inc - v;
    if (tid == 1023) blkSum[blockIdx.x] = wsum[15];
}

__global__ void scanH2(const int* __restrict__ blkSum, int* __restrict__ blkOff,
                       int* __restrict__ offT, const int* __restrict__ bcnt,
                       int* __restrict__ boff, int* __restrict__ tileOff) {
    if (threadIdx.x != 0) return;
    int run = 0;
    for (int i = 0; i < NSB; ++i) {
        blkOff[i] = run;
        run += blkSum[i];
    }
    offT[N_] = E_;
    boff[0] = 0;
    tileOff[0] = 0;
    for (int p = 0; p < P_; ++p) {
        boff[p + 1] = boff[p] + bcnt[p];
        tileOff[p + 1] = tileOff[p] + (bcnt[p] + TM - 1) / TM;
    }
}

__global__ __launch_bounds__(1024) void scanH3(int* __restrict__ a,
                                               const int* __restrict__ blkOff) {
    int idx = blockIdx.x * 1024 + threadIdx.x;
    a[idx] += blkOff[blockIdx.x];
}

__global__ __launch_bounds__(256) void scatterTS(const int* __restrict__ ei,
                                                 const int* __restrict__ histG,
                                                 unsigned* __restrict__ bufT,
                                                 unsigned char* __restrict__ bufS8) {
    __shared__ int ldsT[256], ldsS[256];
    int blk = blockIdx.x, tid = threadIdx.x;
    ldsT[tid] = histG[tid * NBK + blk];
    ldsS[tid] = histG[HHALF + tid * NBK + blk] - E_;
    __syncthreads();
    int base = blk * CHUNK;
#pragma unroll
    for (int i = 0; i < CHUNK / 256; ++i) {
        int e = base + tid + i * 256;
        if (e < E_) {
            int s = ei[e], t = ei[E_ + e];
            int pT = atomicAdd(&ldsT[t >> 8], 1);
            bufT[pT] = ((unsigned)t << 16) | (unsigned)s;
            int pS = atomicAdd(&ldsS[s >> 8], 1);
            bufS8[pS] = (unsigned char)(s & 255);
        }
    }
}

__global__ __launch_bounds__(256) void finalizeT(const unsigned* __restrict__ bufT,
                                                 const int* __restrict__ histG,
                                                 int* __restrict__ offT,
                                                 unsigned short* __restrict__ eSrc) {
    __shared__ int hist[256];
    __shared__ int sOff[256];
    int b = blockIdx.x, tid = threadIdx.x;
    int start = histG[b * NBK];
    int end = histG[(b + 1) * NBK];
    hist[tid] = 0;
    __syncthreads();
    for (int i = start + tid; i < end; i += 256)
        atomicAdd(&hist[(bufT[i] >> 16) & 255], 1);
    __syncthreads();
    if (tid < 64) {
        int b0 = 4 * tid;
        int s0 = hist[b0], s1 = hist[b0 + 1], s2 = hist[b0 + 2], s3 = hist[b0 + 3];
        int lsum = s0 + s1 + s2 + s3;
        int inc = lsum;
#pragma unroll
        for (int o = 1; o < 64; o <<= 1) {
            int t = __shfl_up(inc, o, 64);
            if (tid >= o) inc += t;
        }
        int excl = inc - lsum;
        sOff[b0] = excl;
        sOff[b0 + 1] = excl + s0;
        sOff[b0 + 2] = excl + s0 + s1;
        sOff[b0 + 3] = excl + s0 + s1 + s2;
    }
    __syncthreads();
    int node = (b << 8) + tid;
    if (node < N_) offT[node] = start + sOff[tid];
    __syncthreads();
    for (int i = start + tid; i < end; i += 256) {
        unsigned pk = bufT[i];
        int pos = start + atomicAdd(&sOff[(pk >> 16) & 255], 1);
        eSrc[pos] = (unsigned short)(pk & 0xFFFF);
    }
}

__global__ __launch_bounds__(256) void finalizeS(const unsigned char* __restrict__ bufS8,
                                                 const int* __restrict__ histG,
                                                 float* __restrict__ dnorm) {
    __shared__ int hist[256];
    int b = blockIdx.x, tid = threadIdx.x;
    int start = histG[HHALF + b * NBK] - E_;
    int end = histG[HHALF + (b + 1) * NBK] - E_;
    hist[tid] = 0;
    __syncthreads();
    for (int i = start + tid; i < end; i += 256) atomicAdd(&hist[bufS8[i]], 1);
    __syncthreads();
    int node = (b << 8) + tid;
    if (node < N_) {
        int dg = hist[tid];
        dnorm[node] = 1.f / (float)(dg > 1 ? dg : 1);
    }
}

__global__ __launch_bounds__(256) void bucket_fill(const int* __restrict__ pol,
                                                   const int* __restrict__ boff,
                                                   int* __restrict__ bcur,
                                                   int* __restrict__ blist) {
    __shared__ int h[P_];
    __shared__ int base[P_];
    int tid = threadIdx.x;
    if (tid < P_) h[tid] = 0;
    __syncthreads();
    int n = blockIdx.x * 256 + tid;
    int p = 0, loc = 0;
    bool act = (n < N_);
    if (act) {
        p = pol[n];
        loc = atomicAdd(&h[p], 1);
    }
    __syncthreads();
    if (tid < P_ && h[tid] > 0) base[tid] = atomicAdd(&bcur[tid], h[tid]);
    __syncthreads();
    if (act) blist[boff[p] + base[p] + loc] = n;
}

// ---------------------------------------------------------------------------
// Weight prep
// ---------------------------------------------------------------------------

__global__ __launch_bounds__(256) void conv4(const float* __restrict__ x,
                                             unsigned short* __restrict__ xb) {
    int i = blockIdx.x * 256 + threadIdx.x;
    if (i >= N_ * D_ / 4) return;
    float4 v = ((const float4*)x)[i];
    ushort4 o;
    o.x = f2bf(v.x); o.y = f2bf(v.y); o.z = f2bf(v.z); o.w = f2bf(v.w);
    ((ushort4*)xb)[i] = o;
}

// zero the dummy gather row xt[N_] (used for tail-step padding in aggregate)
__global__ void zero_row(unsigned short* __restrict__ bufAb) {
    ((unsigned*)(bufAb + (size_t)N_ * D_))[threadIdx.x] = 0;
}

__global__ __launch_bounds__(256) void prep_S(const float* __restrict__ S,
                                              const float* __restrict__ dS,
                                              unsigned short* __restrict__ Sb) {
    int idx = blockIdx.x * 256 + threadIdx.x;  // L*P*D*D
    int base = idx / (D_ * D_);
    int rem = idx % (D_ * D_);
    int c = rem / D_, d = rem % D_;
    size_t in = (size_t)base * D_ * D_ + (size_t)d * D_ + c;
    Sb[idx] = f2bf(S[in] + dS[in]);
}

__global__ __launch_bounds__(256) void prep_W2(const float* __restrict__ W2,
                                               unsigned short* __restrict__ W2b) {
    int idx = blockIdx.x * 256 + threadIdx.x;  // L*D*D
    W2b[idx] = f2bf(W2[idx]);
}

// Split fp32 -> bf16 hi/lo pairs for the small-GEMM operands:
//   Ar[mat][i][j]   = (R+dR)               (27 * 16384)
//   W1s[l][k][j]    = W1                   ( 3 * 16384)
//   Wrt[l][d][i]    = Wr[l][i][d]          ( 3 * 16384, transposed)
__global__ __launch_bounds__(256) void prep_split(
    const float* __restrict__ R, const float* __restrict__ dR,
    const float* __restrict__ W1, const float* __restrict__ Wr,
    unsigned short* __restrict__ Arh, unsigned short* __restrict__ Arl,
    unsigned short* __restrict__ W1h, unsigned short* __restrict__ W1l,
    unsigned short* __restrict__ Wrth, unsigned short* __restrict__ Wrtl) {
    constexpr int SZ1 = MAT * 16384;
    constexpr int SZ2 = SZ1 + 3 * 16384;
    int idx = blockIdx.x * 256 + threadIdx.x;  // SZ2 + 3*16384 total
    float v;
    unsigned short* oh;
    unsigned short* ol;
    int j;
    if (idx < SZ1) {
        v = R[idx] + dR[idx];
        oh = Arh; ol = Arl; j = idx;
    } else if (idx < SZ2) {
        j = idx - SZ1;
        v = W1[j];
        oh = W1h; ol = W1l;
    } else {
        j = idx - SZ2;
        int l = j >> 14, rem = j & 16383;
        int d = rem >> 7, i = rem & 127;
        v = Wr[(l << 14) + i * 128 + d];
        oh = Wrth; ol = Wrtl;
    }
    unsigned short h = f2bf(v);
    oh[j] = h;
    ol[j] = f2bf(v - bf2f(h));
}

// ---------------------------------------------------------------------------
// Batched small MFMA GEMM (fp32-equivalent via 2-term bf16 split, 3 MFMAs):
//   out[mat][row][col] = sum_k A[...][row][k] * B[...][col][k]
// grid = 2*MAT blocks (64 rows each); A/B read direct from L2 (no LDS stage);
// output goes through LDS for coalesced stores.
//   APM: A indexed per-mat (else per-l). BPM: same for B.
//   OUT_SPLIT: write hi/lo bf16 pair (for T1t), else single bf16 (for Dmb).
// ---------------------------------------------------------------------------

template <bool APM, bool BPM, bool OUT_SPLIT>
__global__ __launch_bounds__(256) void small_mfma(
    const unsigned short* __restrict__ Ah, const unsigned short* __restrict__ Al,
    const unsigned short* __restrict__ Bh, const unsigned short* __restrict__ Bl,
    unsigned short* __restrict__ Oh, unsigned short* __restrict__ Ol) {
    __shared__ unsigned short stg[(OUT_SPLIT ? 2 : 1) * 64 * 136];
    int tid = threadIdx.x, b = blockIdx.x;
    int mat = b >> 1, rb = b & 1;
    int l = mat / P_;
    size_t aoff = (size_t)(APM ? mat : l) * 16384 + (size_t)rb * 8192;
    size_t boff = (size_t)(BPM ? mat : l) * 16384;
    const unsigned short* ahp = Ah + aoff;
    const unsigned short* alp = Al + aoff;
    const unsigned short* bhp = Bh + boff;
    const unsigned short* blp = Bl + boff;

    int lane = tid & 63, wave = tid >> 6;
    int n = lane & 15, q = lane >> 4;
    int wr = wave * 16;

    f32x4 acc[8];
#pragma unroll
    for (int t = 0; t < 8; ++t) acc[t] = (f32x4){0.f, 0.f, 0.f, 0.f};

    int arow = (wr + n) * 128;
#pragma unroll
    for (int kc = 0; kc < 4; ++kc) {
        int ko = kc * 32 + q * 8;
        bf16x8 avh = *(const bf16x8*)(ahp + arow + ko);
        bf16x8 avl = *(const bf16x8*)(alp + arow + ko);
#pragma unroll
        for (int t = 0; t < 8; ++t) {
            int brow = (t * 16 + n) * 128;
            bf16x8 bvh = *(const bf16x8*)(bhp + brow + ko);
            bf16x8 bvl = *(const bf16x8*)(blp + brow + ko);
            acc[t] = __builtin_amdgcn_mfma_f32_16x16x32_bf16(avh, bvh, acc[t], 0, 0, 0);
            acc[t] = __builtin_amdgcn_mfma_f32_16x16x32_bf16(avh, bvl, acc[t], 0, 0, 0);
            acc[t] = __builtin_amdgcn_mfma_f32_16x16x32_bf16(avl, bvh, acc[t], 0, 0, 0);
        }
    }

    // C/D layout: col=t*16+n, row=q*4+r (within wave's 16 rows)
#pragma unroll
    for (int t = 0; t < 8; ++t)
#pragma unroll
        for (int r = 0; r < 4; ++r) {
            int row = wr + q * 4 + r;
            float v = acc[t][r];
            unsigned short h = f2bf(v);
            stg[row * 136 + t * 16 + n] = h;
            if constexpr (OUT_SPLIT)
                stg[64 * 136 + row * 136 + t * 16 + n] = f2bf(v - bf2f(h));
        }
    __syncthreads();
    size_t obase = (size_t)mat * 16384 + (size_t)rb * 8192;
#pragma unroll
    for (int i = 0; i < 4; ++i) {
        int c = tid + i * 256;
        int r = c >> 4, off = c & 15;
        *(uint4*)(Oh + obase + r * 128 + off * 8) =
            *(const uint4*)(stg + r * 136 + off * 8);
        if constexpr (OUT_SPLIT)
            *(uint4*)(Ol + obase + r * 128 + off * 8) =
                *(const uint4*)(stg + 64 * 136 + r * 136 + off * 8);
    }
}

// ---------------------------------------------------------------------------
// CSR aggregation, MLP-optimized (R5 version)
// ---------------------------------------------------------------------------

__device__ inline void accum_row(float* acc, uint4 r) {
    acc[0] += bflo(r.x); acc[1] += bfhi(r.x);
    acc[2] += bflo(r.y); acc[3] += bfhi(r.y);
    acc[4] += bflo(r.z); acc[5] += bfhi(r.z);
    acc[6] += bflo(r.w); acc[7] += bfhi(r.w);
}

__global__ __launch_bounds__(256) void aggregate_bf(const unsigned short* __restrict__ xt,
                                                    const int* __restrict__ offT,
                                                    const unsigned short* __restrict__ eSrc,
                                                    unsigned short* __restrict__ agg) {
    int nd = blockIdx.x * 4 + (threadIdx.x >> 6);
    if (nd >= N_) return;
    int l = threadIdx.x & 63;
    int g = l >> 4, c16 = l & 15;
    int beg = offT[nd], end = offT[nd + 1];

    float acc[8];
#pragma unroll
    for (int k = 0; k < 8; ++k) acc[k] = 0.f;

    for (int base = beg; base < end; base += 64) {
        int cnt = min(64, end - base);
        int idxv = 0;
        if (l < cnt) idxv = (int)eSrc[base + l];
        int steps = (cnt + 3) >> 2;
        int j = 0;
        for (; j + 1 < steps; j += 2) {
            int e0 = 4 * j + g, e1 = e0 + 4;
            int i0 = __shfl(idxv, e0, 64);
            int i1 = __shfl(idxv, e1, 64);
            int r0 = (e0 < cnt) ? i0 : N_;
            int r1 = (e1 < cnt) ? i1 : N_;
            uint4 v0 = ((const uint4*)(xt + (size_t)r0 * D_))[c16];
            uint4 v1 = ((const uint4*)(xt + (size_t)r1 * D_))[c16];
            accum_row(acc, v0);
            accum_row(acc, v1);
        }
        if (j < steps) {
            int e0 = 4 * j + g;
            int i0 = __shfl(idxv, e0, 64);
            int r0 = (e0 < cnt) ? i0 : N_;
            uint4 v0 = ((const uint4*)(xt + (size_t)r0 * D_))[c16];
            accum_row(acc, v0);
        }
    }
#pragma unroll
    for (int k = 0; k < 8; ++k) {
        acc[k] += __shfl_xor(acc[k], 16, 64);
        acc[k] += __shfl_xor(acc[k], 32, 64);
    }
    if (g == 0) {
        uint4 o;
        o.x = (unsigned)f2bf(acc[0]) | ((unsigned)f2bf(acc[1]) << 16);
        o.y = (unsigned)f2bf(acc[2]) | ((unsigned)f2bf(acc[3]) << 16);
        o.z = (unsigned)f2bf(acc[4]) | ((unsigned)f2bf(acc[5]) << 16);
        o.w = (unsigned)f2bf(acc[6]) | ((unsigned)f2bf(acc[7]) << 16);
        ((uint4*)(agg + (size_t)nd * D_))[c16] = o;
    }
}

// ---------------------------------------------------------------------------
// MFMA GEMM: 64 rows x 128 cols per block, 4 waves x 16 rows, K=128 resident.
// mfma_f32_16x16x32_bf16; C/D: col=lane&15, row=(lane>>4)*4+reg [m89-verified]
// ---------------------------------------------------------------------------

template <int EPI, bool BUCKETED>
__global__ __launch_bounds__(256) void mfma_gemm(
    const unsigned short* __restrict__ A, const unsigned short* __restrict__ Bw,
    float* __restrict__ OutF, unsigned short* __restrict__ OutB,
    const int* __restrict__ blist, const int* __restrict__ boff,
    const int* __restrict__ tileOff, const float* __restrict__ dnorm,
    const float* __restrict__ bias, const float* __restrict__ g,
    const float* __restrict__ bb, const float* __restrict__ rs_ptr,
    const float* __restrict__ xres, const float* __restrict__ x0add) {
    __shared__ unsigned short smem[8704 + 17408];  // sA 64x136, sB 128x136
    __shared__ int rid[TM];
    __shared__ float dnRow[TM];
    unsigned short* sA = smem;
    unsigned short* sB = smem + 8704;
    float* Ts = (float*)(smem + 8704);  // overlays sB: 64x132 fp32

    int tid = threadIdx.x;
    int b = blockIdx.x;

    int pp = 0, nrows, rowbase;
    if constexpr (BUCKETED) {
        if (b >= tileOff[P_]) return;
        while (pp < P_ - 1 && b >= tileOff[pp + 1]) ++pp;
        int tb = b - tileOff[pp];
        int cnt = boff[pp + 1] - boff[pp];
        nrows = min(TM, cnt - tb * TM);
        rowbase = boff[pp] + tb * TM;
    } else {
        nrows = min(TM, N_ - b * TM);
        rowbase = b * TM;
    }
    const unsigned short* B = Bw + (BUCKETED ? (size_t)pp * D_ * D_ : 0);

    if (tid < TM) {
        int r = (tid < nrows) ? (BUCKETED ? blist[rowbase + tid] : rowbase + tid) : -1;
        rid[tid] = r;
        if constexpr (EPI == 1) dnRow[tid] = (r >= 0) ? dnorm[r] : 1.f;
    }
    __syncthreads();

#pragma unroll
    for (int i = 0; i < 8; ++i) {
        int c = tid + i * 256;
        int r = c >> 4, off = c & 15;
        uint4 v = *(const uint4*)(B + r * 128 + off * 8);
        *(uint4*)(sB + r * 136 + off * 8) = v;
    }
#pragma unroll
    for (int i = 0; i < 4; ++i) {
        int c = tid + i * 256;
        int r = c >> 4, off = c & 15;
        int row = rid[r];
        uint4 v = make_uint4(0, 0, 0, 0);
        if (row >= 0) v = *(const uint4*)(A + (size_t)row * D_ + off * 8);
        *(uint4*)(sA + r * 136 + off * 8) = v;
    }
    __syncthreads();

    int lane = tid & 63, wave = tid >> 6;
    int n = lane & 15, q = lane >> 4;
    int wr = wave * 16;

    f32x4 acc[8];
#pragma unroll
    for (int t = 0; t < 8; ++t) acc[t] = (f32x4){0.f, 0.f, 0.f, 0.f};

#pragma unroll
    for (int k0 = 0; k0 < 4; ++k0) {
        bf16x8 af = *(const bf16x8*)(sA + (wr + n) * 136 + k0 * 32 + q * 8);
#pragma unroll
        for (int t = 0; t < 8; ++t) {
            bf16x8 bf = *(const bf16x8*)(sB + (t * 16 + n) * 136 + k0 * 32 + q * 8);
            acc[t] = __builtin_amdgcn_mfma_f32_16x16x32_bf16(af, bf, acc[t], 0, 0, 0);
        }
    }
    __syncthreads();  // LDS about to be reused

    unsigned short* Tb = sA;  // bf16 out staging, stride 136

    if constexpr (EPI == 0) {
#pragma unroll
        for (int t = 0; t < 8; ++t)
#pragma unroll
            for (int r = 0; r < 4; ++r)
                Tb[(wr + q * 4 + r) * 136 + t * 16 + n] = f2bf(acc[t][r]);
        __syncthreads();
#pragma unroll
        for (int i = 0; i < 4; ++i) {
            int c = tid + i * 256;
            int rr2 = c >> 4, off = c & 15;
            int row = rid[rr2];
            if (row >= 0)
                *(uint4*)(OutB + (size_t)row * D_ + off * 8) =
                    *(const uint4*)(Tb + rr2 * 136 + off * 8);
        }
        return;
    }

    if constexpr (EPI == 1) {
        float rs1[4] = {0, 0, 0, 0}, rs2[4] = {0, 0, 0, 0};
#pragma unroll
        for (int t = 0; t < 8; ++t) {
            int col = t * 16 + n;
            float bia = bias[col];
#pragma unroll
            for (int r = 0; r < 4; ++r) {
                float v = dnRow[wr + q * 4 + r] * acc[t][r] + bia;
                acc[t][r] = v;
                rs1[r] += v;
                rs2[r] += v * v;
            }
        }
#pragma unroll
        for (int mk = 1; mk < 16; mk <<= 1)
#pragma unroll
            for (int r = 0; r < 4; ++r) {
                rs1[r] += __shfl_xor(rs1[r], mk, 64);
                rs2[r] += __shfl_xor(rs2[r], mk, 64);
            }
        float mr[4], rv[4];
#pragma unroll
        for (int r = 0; r < 4; ++r) {
            float mm = rs1[r] * (1.f / 128.f);
            mr[r] = mm;
            rv[r] = rsqrtf(rs2[r] * (1.f / 128.f) - mm * mm + EPS_);
        }
#pragma unroll
        for (int t = 0; t < 8; ++t) {
            int col = t * 16 + n;
            float gg = g[col], bbv = bb[col];
#pragma unroll
            for (int r = 0; r < 4; ++r) {
                float nv = (acc[t][r] - mr[r]) * rv[r] * gg + bbv;
                Tb[(wr + q * 4 + r) * 136 + col] = f2bf(fmaxf(nv, 0.f));
            }
        }
        __syncthreads();
#pragma unroll
        for (int i = 0; i < 4; ++i) {
            int c = tid + i * 256;
            int rr2 = c >> 4, off = c & 15;
            int row = rid[rr2];
            if (row >= 0)
                *(uint4*)(OutB + (size_t)row * D_ + off * 8) =
                    *(const uint4*)(Tb + rr2 * 136 + off * 8);
        }
        return;
    }

    if constexpr (EPI == 2) {
#pragma unroll
        for (int i = 0; i < 8; ++i) {
            int c = tid + i * 256;
            int rr2 = c >> 5, off = c & 31;
            int row = rid[rr2];
            float4 v = make_float4(0, 0, 0, 0);
            if (row >= 0) v = *(const float4*)(xres + (size_t)row * D_ + off * 4);
            *(float4*)(Ts + rr2 * 132 + off * 4) = v;
        }
        __syncthreads();
        float rs = rs_ptr[0];
        float rs1[4] = {0, 0, 0, 0}, rs2[4] = {0, 0, 0, 0};
#pragma unroll
        for (int t = 0; t < 8; ++t) {
            int col = t * 16 + n;
            float bia = bias[col];
#pragma unroll
            for (int r = 0; r < 4; ++r) {
                int row = wr + q * 4 + r;
                float v = rs * (acc[t][r] + bia) + Ts[row * 132 + col];
                acc[t][r] = v;
                rs1[r] += v;
                rs2[r] += v * v;
            }
        }
#pragma unroll
        for (int mk = 1; mk < 16; mk <<= 1)
#pragma unroll
            for (int r = 0; r < 4; ++r) {
                rs1[r] += __shfl_xor(rs1[r], mk, 64);
                rs2[r] += __shfl_xor(rs2[r], mk, 64);
            }
        float mr[4], rv[4];
#pragma unroll
        for (int r = 0; r < 4; ++r) {
            float mm = rs1[r] * (1.f / 128.f);
            mr[r] = mm;
            rv[r] = rsqrtf(rs2[r] * (1.f / 128.f) - mm * mm + EPS_);
        }
        bool hasB = (OutB != nullptr);
#pragma unroll
        for (int t = 0; t < 8; ++t) {
            int col = t * 16 + n;
            float gg = g[col], bbv = bb[col];
#pragma unroll
            for (int r = 0; r < 4; ++r) {
                int row = wr + q * 4 + r;
                float nv = (acc[t][r] - mr[r]) * rv[r] * gg + bbv;
                if (x0add) {
                    int grow = rid[row];
                    if (grow >= 0) nv += x0add[(size_t)grow * D_ + col];
                }
                Ts[row * 132 + col] = nv;
                if (hasB) Tb[row * 136 + col] = f2bf(nv);
            }
        }
        __syncthreads();
#pragma unroll
        for (int i = 0; i < 8; ++i) {
            int c = tid + i * 256;
            int rr2 = c >> 5, off = c & 31;
            int row = rid[rr2];
            if (row >= 0)
                *(float4*)(OutF + (size_t)row * D_ + off * 4) =
                    *(const float4*)(Ts + rr2 * 132 + off * 4);
        }
        if (hasB) {
#pragma unroll
            for (int i = 0; i < 4; ++i) {
                int c = tid + i * 256;
                int rr2 = c >> 4, off = c & 15;
                int row = rid[rr2];
                if (row >= 0)
                    *(uint4*)(OutB + (size_t)row * D_ + off * 8) =
                        *(const uint4*)(Tb + rr2 * 136 + off * 8);
            }
        }
    }
}

// ---------------------------------------------------------------------------
// Host launch
// ---------------------------------------------------------------------------

extern "C" void kernel_launch(void* const* d_in, const int* in_sizes, int n_in,
                              void* d_out, int out_size, void* d_ws, size_t ws_size,
                              hipStream_t stream) {
    const float* x0 = (const float*)d_in[0];
    const int* ei = (const int*)d_in[1];
    const int* ring = (const int*)d_in[2];
    const float* Wr = (const float*)d_in[3];
    const float* S = (const float*)d_in[4];
    const float* dS = (const float*)d_in[5];
    const float* R = (const float*)d_in[6];
    const float* dR = (const float*)d_in[7];
    const float* rsc = (const float*)d_in[8];
    const float* W1 = (const float*)d_in[9];
    const float* b1 = (const float*)d_in[10];
    const float* lng = (const float*)d_in[11];
    const float* lnb = (const float*)d_in[12];
    const float* W2 = (const float*)d_in[13];
    const float* b2 = (const float*)d_in[14];
    const float* ng = (const float*)d_in[15];
    const float* nb = (const float*)d_in[16];
    float* out = (float*)d_out;

    char* w = (char*)d_ws;
    auto alloc = [&](size_t bytes) {
        char* p = w;
        w += (bytes + 15) & ~(size_t)15;
        return p;
    };
    unsigned short* xb = (unsigned short*)alloc((size_t)N_ * D_ * 2);          // bf16 x
    unsigned short* bufAb = (unsigned short*)alloc((size_t)(N_ + 1) * D_ * 2); // xt / h (+zero row)
    unsigned short* bufBb = (unsigned short*)alloc((size_t)N_ * D_ * 2);       // agg
    float* xbuf = (float*)alloc((size_t)N_ * D_ * 4);                          // fp32 x
    unsigned short* Sb = (unsigned short*)alloc((size_t)L_ * P_ * D_ * D_ * 2);
    unsigned short* Dmb = (unsigned short*)alloc((size_t)L_ * P_ * D_ * D_ * 2);
    unsigned short* W2b = (unsigned short*)alloc((size_t)L_ * D_ * D_ * 2);
    // split-precision operand arrays for the batched small GEMMs
    unsigned short* Arh = (unsigned short*)alloc((size_t)MAT * 16384 * 2);
    unsigned short* Arl = (unsigned short*)alloc((size_t)MAT * 16384 * 2);
    unsigned short* W1h = (unsigned short*)alloc((size_t)3 * 16384 * 2);
    unsigned short* W1l = (unsigned short*)alloc((size_t)3 * 16384 * 2);
    unsigned short* Wrth = (unsigned short*)alloc((size_t)3 * 16384 * 2);
    unsigned short* Wrtl = (unsigned short*)alloc((size_t)3 * 16384 * 2);
    unsigned short* T1th = (unsigned short*)alloc((size_t)MAT * 16384 * 2);
    unsigned short* T1tl = (unsigned short*)alloc((size_t)MAT * 16384 * 2);
    float* dnorm = (float*)alloc((size_t)N_ * 4);
    int* histG = (int*)alloc((size_t)HTOT * 4);
    unsigned* bufT = (unsigned*)alloc((size_t)E_ * 4);
    unsigned char* bufS8 = (unsigned char*)alloc((size_t)E_);
    unsigned short* eSrc = (unsigned short*)alloc((size_t)E_ * 2);
    int* offT = (int*)alloc((size_t)(N_ + 1) * 4);
    int* pol = (int*)alloc((size_t)N_ * 4);
    int* boff = (int*)alloc((size_t)(P_ + 1) * 4);
    int* tileOff = (int*)alloc((size_t)(P_ + 1) * 4);
    int* blist = (int*)alloc((size_t)N_ * 4);
    int* blkSum = (int*)alloc((size_t)NSB * 4);
    int* blkOff = (int*)alloc((size_t)NSB * 4);
    int* bcnt = (int*)alloc((size_t)2 * P_ * 4);  // zeroed region: bcnt + bcur
    int* bcur = bcnt + P_;

    hipMemsetAsync(bcnt, 0, (size_t)2 * P_ * 4, stream);

    const int NG = (N_ + 255) / 256;
    const int SG = L_ * P_ * D_ * D_ / 256;
    const int BTILES = N_ / TM + P_;
    const int CTILES = (N_ + TM - 1) / TM;
    const int SPG = (MAT + 6) * 16384 / 256;  // prep_split grid = 2112

    node_init<<<NG, 256, 0, stream>>>(ring, pol, bcnt);
    khist<<<NBK, 256, 0, stream>>>(ei, histG);
    scanH1<<<NSB, 1024, 0, stream>>>(histG, blkSum);
    scanH2<<<1, 64, 0, stream>>>(blkSum, blkOff, offT, bcnt, boff, tileOff);
    scanH3<<<NSB, 1024, 0, stream>>>(histG, blkOff);
    scatterTS<<<NBK, 256, 0, stream>>>(ei, histG, bufT, bufS8);
    finalizeT<<<NBUK, 256, 0, stream>>>(bufT, histG, offT, eSrc);
    finalizeS<<<NBUK, 256, 0, stream>>>(bufS8, histG, dnorm);
    bucket_fill<<<NG, 256, 0, stream>>>(pol, boff, bcur, blist);

    conv4<<<(N_ * D_ / 4 + 255) / 256, 256, 0, stream>>>(x0, xb);
    zero_row<<<1, 64, 0, stream>>>(bufAb);
    prep_S<<<SG, 256, 0, stream>>>(S, dS, Sb);
    prep_W2<<<L_ * D_ * D_ / 256, 256, 0, stream>>>(W2, W2b);
    prep_split<<<SPG, 256, 0, stream>>>(R, dR, W1, Wr, Arh, Arl, W1h, W1l, Wrth, Wrtl);
    // T1t[mat][k][i] = sum_j W1[l][k][j] * Ar[mat][i][j]   (A per-l, B per-mat)
    small_mfma<false, true, true><<<2 * MAT, 256, 0, stream>>>(
        W1h, W1l, Arh, Arl, T1th, T1tl);
    // Dmb[mat][k][d] = sum_i T1t[mat][k][i] * Wrt[l][d][i] (A per-mat, B per-l)
    small_mfma<true, false, false><<<2 * MAT, 256, 0, stream>>>(
        T1th, T1tl, Wrth, Wrtl, Dmb, nullptr);

    for (int l = 0; l < L_; ++l) {
        const size_t lPDD = (size_t)l * P_ * D_ * D_;
        const size_t lDD = (size_t)l * D_ * D_;
        const size_t lD = (size_t)l * D_;
        // xt = x @ (S+dS)[pol]   -> bf16
        mfma_gemm<0, true><<<BTILES, 256, 0, stream>>>(
            xb, Sb + lPDD, nullptr, bufAb, blist, boff, tileOff,
            nullptr, nullptr, nullptr, nullptr, nullptr, nullptr, nullptr);
        // agg = CSR-sum xt  -> bf16
        aggregate_bf<<<N_ / 4, 256, 0, stream>>>(bufAb, offT, eSrc, bufBb);
        // h = relu(LN(dn * (agg @ Dm[pol]) + b1)) -> bf16
        mfma_gemm<1, true><<<BTILES, 256, 0, stream>>>(
            bufBb, Dmb + lPDD, nullptr, bufAb, blist, boff, tileOff,
            dnorm, b1 + lD, lng + lD, lnb + lD, nullptr, nullptr, nullptr);
        // x' = LN(rs*(h @ W2.T + b2) + x) (+x0 last) -> fp32 (+bf16 for next layer)
        float* xo = (l == L_ - 1) ? out : xbuf;
        const float* xr = (l == 0) ? x0 : xbuf;
        unsigned short* xbn = (l == L_ - 1) ? nullptr : xb;
        mfma_gemm<2, false><<<CTILES, 256, 0, stream>>>(
            bufAb, W2b + lDD, xo, xbn, nullptr, nullptr, nullptr,
            nullptr, b2 + lD, ng + lD, nb + lD, rsc + l, xr,
            (l == L_ - 1) ? x0 : nullptr);
    }
}

// Round 7
// 381.475 us; speedup vs baseline: 3.4023x; 1.2313x over previous
//
#include <hip/hip_runtime.h>
#include <hip/hip_bf16.h>

// Problem constants
constexpr int N_ = 50000;
constexpr int D_ = 128;
constexpr int E_ = 800000;
constexpr int P_ = 9;
constexpr int L_ = 3;
constexpr float EPS_ = 1e-5f;

constexpr int TM = 64;    // rows per GEMM block
constexpr int CHUNK = 4096;                    // edges per hist/scatter block
constexpr int NBK = (E_ + CHUNK - 1) / CHUNK;  // 196 edge chunks
constexpr int NBUK = 196;                      // node buckets (50000>>8 = 195 max)
constexpr int HHALF = 256 * NBK;               // 50176 (per-half hist size)
constexpr int HTOT = 2 * HHALF;                // 100352 = 98 * 1024 exactly
constexpr int NSB = HTOT / 1024;               // 98 scan blocks
constexpr int MAT = L_ * P_;                   // 27 small matrices

typedef short bf16x8 __attribute__((ext_vector_type(8)));
typedef float f32x4 __attribute__((ext_vector_type(4)));

__device__ inline unsigned short f2bf(float f) {
    __hip_bfloat16 h = __float2bfloat16(f);
    return *reinterpret_cast<unsigned short*>(&h);
}
__device__ inline float bflo(unsigned u) { return __uint_as_float(u << 16); }
__device__ inline float bfhi(unsigned u) { return __uint_as_float(u & 0xffff0000u); }
__device__ inline float bf2f(unsigned short h) {
    return __uint_as_float((unsigned)h << 16);
}

// ---------------------------------------------------------------------------
// setup_nk: node polarity init (block = node range) + edge histograms
// (block = edge chunk). NG == NBK == 196 so one grid serves both roles.
// ---------------------------------------------------------------------------

__global__ __launch_bounds__(256) void setup_nk(const int* __restrict__ ring,
                                                int* __restrict__ pol,
                                                int* __restrict__ bcnt,
                                                const int* __restrict__ ei,
                                                int* __restrict__ histG) {
    __shared__ int h[P_];
    __shared__ int hT[256], hS[256];
    int blk = blockIdx.x, tid = threadIdx.x;
    if (tid < P_) h[tid] = 0;
    hT[tid] = 0;
    hS[tid] = 0;
    __syncthreads();
    // node role
    int n = blk * 256 + tid;
    if (n < N_) {
        int p = ring[n] % P_;
        pol[n] = p;
        atomicAdd(&h[p], 1);
    }
    // edge role
    int base = blk * CHUNK;
#pragma unroll
    for (int i = 0; i < CHUNK / 256; ++i) {
        int e = base + tid + i * 256;
        if (e < E_) {
            atomicAdd(&hS[ei[e] >> 8], 1);
            atomicAdd(&hT[ei[E_ + e] >> 8], 1);
        }
    }
    __syncthreads();
    if (tid < P_ && h[tid] > 0) atomicAdd(&bcnt[tid], h[tid]);
    histG[tid * NBK + blk] = hT[tid];
    histG[HHALF + tid * NBK + blk] = hS[tid];
}

// ---------------------------------------------------------------------------
// 3-phase exclusive scan of histG[HTOT]
// ---------------------------------------------------------------------------

__global__ __launch_bounds__(1024) void scanH1(int* __restrict__ a,
                                               int* __restrict__ blkSum) {
    __shared__ int wsum[16];
    int tid = threadIdx.x, lane = tid & 63, wid = tid >> 6;
    int idx = blockIdx.x * 1024 + tid;
    int v = a[idx];
    int inc = v;
#pragma unroll
    for (int o = 1; o < 64; o <<= 1) {
        int t = __shfl_up(inc, o, 64);
        if (lane >= o) inc += t;
    }
    if (lane == 63) wsum[wid] = inc;
    __syncthreads();
    if (tid < 16) {
        int s = wsum[tid];
#pragma unroll
        for (int o = 1; o < 16; o <<= 1) {
            int t = __shfl_up(s, o, 64);
            if (tid >= o) s += t;
        }
        wsum[tid] = s;
    }
    __syncthreads();
    int wexcl = (wid == 0) ? 0 : wsum[wid - 1];
    a[idx] = wexcl + inc - v;
    if (tid == 1023) blkSum[blockIdx.x] = wsum[15];
}

__global__ void scanH2(const int* __restrict__ blkSum, int* __restrict__ blkOff,
                       int* __restrict__ offT, const int* __restrict__ bcnt,
                       int* __restrict__ boff, int* __restrict__ tileOff) {
    if (threadIdx.x != 0) return;
    int run = 0;
    for (int i = 0; i < NSB; ++i) {
        blkOff[i] = run;
        run += blkSum[i];
    }
    offT[N_] = E_;
    boff[0] = 0;
    tileOff[0] = 0;
    for (int p = 0; p < P_; ++p) {
        boff[p + 1] = boff[p] + bcnt[p];
        tileOff[p + 1] = tileOff[p] + (bcnt[p] + TM - 1) / TM;
    }
}

__global__ __launch_bounds__(1024) void scanH3(int* __restrict__ a,
                                               const int* __restrict__ blkOff) {
    int idx = blockIdx.x * 1024 + threadIdx.x;
    a[idx] += blkOff[blockIdx.x];
}

// ---------------------------------------------------------------------------
// scatter into tgt-buckets (packed) and src-buckets (low byte)
// ---------------------------------------------------------------------------

__global__ __launch_bounds__(256) void scatterTS(const int* __restrict__ ei,
                                                 const int* __restrict__ histG,
                                                 unsigned* __restrict__ bufT,
                                                 unsigned char* __restrict__ bufS8) {
    __shared__ int ldsT[256], ldsS[256];
    int blk = blockIdx.x, tid = threadIdx.x;
    ldsT[tid] = histG[tid * NBK + blk];
    ldsS[tid] = histG[HHALF + tid * NBK + blk] - E_;
    __syncthreads();
    int base = blk * CHUNK;
#pragma unroll
    for (int i = 0; i < CHUNK / 256; ++i) {
        int e = base + tid + i * 256;
        if (e < E_) {
            int s = ei[e], t = ei[E_ + e];
            int pT = atomicAdd(&ldsT[t >> 8], 1);
            bufT[pT] = ((unsigned)t << 16) | (unsigned)s;
            int pS = atomicAdd(&ldsS[s >> 8], 1);
            bufS8[pS] = (unsigned char)(s & 255);
        }
    }
}

// ---------------------------------------------------------------------------
// finalize3: merged finalizeT (b<196) / finalizeS (196<=b<392) /
// bucket_fill (392<=b<588)
// ---------------------------------------------------------------------------

__global__ __launch_bounds__(256) void finalize3(
    const unsigned* __restrict__ bufT, const unsigned char* __restrict__ bufS8,
    const int* __restrict__ histG, int* __restrict__ offT,
    unsigned short* __restrict__ eSrc, float* __restrict__ dnorm,
    const int* __restrict__ pol, const int* __restrict__ boff,
    int* __restrict__ bcur, int* __restrict__ blist) {
    __shared__ int s0[256];
    __shared__ int s1[256];
    int bb = blockIdx.x, tid = threadIdx.x;

    if (bb < NBUK) {
        // finalizeT: counting sort by tgt&255 -> offT + sorted eSrc
        int b = bb;
        int start = histG[b * NBK];
        int end = histG[(b + 1) * NBK];
        s0[tid] = 0;
        __syncthreads();
        for (int i = start + tid; i < end; i += 256)
            atomicAdd(&s0[(bufT[i] >> 16) & 255], 1);
        __syncthreads();
        if (tid < 64) {
            int b0 = 4 * tid;
            int v0 = s0[b0], v1 = s0[b0 + 1], v2 = s0[b0 + 2], v3 = s0[b0 + 3];
            int lsum = v0 + v1 + v2 + v3;
            int inc = lsum;
#pragma unroll
            for (int o = 1; o < 64; o <<= 1) {
                int t = __shfl_up(inc, o, 64);
                if (tid >= o) inc += t;
            }
            int excl = inc - lsum;
            s1[b0] = excl;
            s1[b0 + 1] = excl + v0;
            s1[b0 + 2] = excl + v0 + v1;
            s1[b0 + 3] = excl + v0 + v1 + v2;
        }
        __syncthreads();
        int node = (b << 8) + tid;
        if (node < N_) offT[node] = start + s1[tid];
        __syncthreads();
        for (int i = start + tid; i < end; i += 256) {
            unsigned pk = bufT[i];
            int pos = start + atomicAdd(&s1[(pk >> 16) & 255], 1);
            eSrc[pos] = (unsigned short)(pk & 0xFFFF);
        }
    } else if (bb < 2 * NBUK) {
        // finalizeS: src histogram -> dnorm
        int b = bb - NBUK;
        int start = histG[HHALF + b * NBK] - E_;
        int end = histG[HHALF + (b + 1) * NBK] - E_;
        s0[tid] = 0;
        __syncthreads();
        for (int i = start + tid; i < end; i += 256) atomicAdd(&s0[bufS8[i]], 1);
        __syncthreads();
        int node = (b << 8) + tid;
        if (node < N_) {
            int dg = s0[tid];
            dnorm[node] = 1.f / (float)(dg > 1 ? dg : 1);
        }
    } else {
        // bucket_fill
        int b = bb - 2 * NBUK;
        if (tid < P_) s0[tid] = 0;
        __syncthreads();
        int n = b * 256 + tid;
        int p = 0, loc = 0;
        bool act = (n < N_);
        if (act) {
            p = pol[n];
            loc = atomicAdd(&s0[p], 1);
        }
        __syncthreads();
        if (tid < P_ && s0[tid] > 0) s1[tid] = atomicAdd(&bcur[tid], s0[tid]);
        __syncthreads();
        if (act) blist[boff[p] + s1[p] + loc] = n;
    }
}

// ---------------------------------------------------------------------------
// prep_all: conv4 | zero_row | prep_S | prep_W2 | prep_split merged
// ---------------------------------------------------------------------------

constexpr int GCONV = N_ * D_ / 4 / 256;       // 6250
constexpr int GS = L_ * P_ * D_ * D_ / 256;    // 1728
constexpr int GW2 = L_ * D_ * D_ / 256;        // 192
constexpr int GSPL = (MAT + 6) * 16384 / 256;  // 2112
constexpr int GPREP = GCONV + 1 + GS + GW2 + GSPL;

__global__ __launch_bounds__(256) void prep_all(
    const float* __restrict__ x, unsigned short* __restrict__ xb,
    unsigned short* __restrict__ bufAb,
    const float* __restrict__ S, const float* __restrict__ dS,
    unsigned short* __restrict__ Sb,
    const float* __restrict__ W2, unsigned short* __restrict__ W2b,
    const float* __restrict__ R, const float* __restrict__ dR,
    const float* __restrict__ W1, const float* __restrict__ Wr,
    unsigned short* __restrict__ Arh, unsigned short* __restrict__ Arl,
    unsigned short* __restrict__ W1h, unsigned short* __restrict__ W1l,
    unsigned short* __restrict__ Wrth, unsigned short* __restrict__ Wrtl) {
    int b = blockIdx.x, tid = threadIdx.x;
    if (b < GCONV) {
        int i = b * 256 + tid;  // exact range
        float4 v = ((const float4*)x)[i];
        ushort4 o;
        o.x = f2bf(v.x); o.y = f2bf(v.y); o.z = f2bf(v.z); o.w = f2bf(v.w);
        ((ushort4*)xb)[i] = o;
    } else if (b < GCONV + 1) {
        if (tid < 64) ((unsigned*)(bufAb + (size_t)N_ * D_))[tid] = 0;
    } else if (b < GCONV + 1 + GS) {
        int idx = (b - GCONV - 1) * 256 + tid;
        int base = idx / (D_ * D_);
        int rem = idx % (D_ * D_);
        int c = rem / D_, d = rem % D_;
        size_t in = (size_t)base * D_ * D_ + (size_t)d * D_ + c;
        Sb[idx] = f2bf(S[in] + dS[in]);
    } else if (b < GCONV + 1 + GS + GW2) {
        int idx = (b - GCONV - 1 - GS) * 256 + tid;
        W2b[idx] = f2bf(W2[idx]);
    } else {
        constexpr int SZ1 = MAT * 16384;
        constexpr int SZ2 = SZ1 + 3 * 16384;
        int idx = (b - GCONV - 1 - GS - GW2) * 256 + tid;
        float v;
        unsigned short* oh;
        unsigned short* ol;
        int j;
        if (idx < SZ1) {
            v = R[idx] + dR[idx];
            oh = Arh; ol = Arl; j = idx;
        } else if (idx < SZ2) {
            j = idx - SZ1;
            v = W1[j];
            oh = W1h; ol = W1l;
        } else {
            j = idx - SZ2;
            int l = j >> 14, rem = j & 16383;
            int d = rem >> 7, i = rem & 127;
            v = Wr[(l << 14) + i * 128 + d];
            oh = Wrth; ol = Wrtl;
        }
        unsigned short h = f2bf(v);
        oh[j] = h;
        ol[j] = f2bf(v - bf2f(h));
    }
}

// ---------------------------------------------------------------------------
// Batched small MFMA GEMM (fp32-equivalent via 2-term bf16 split)
// ---------------------------------------------------------------------------

template <bool APM, bool BPM, bool OUT_SPLIT>
__global__ __launch_bounds__(256) void small_mfma(
    const unsigned short* __restrict__ Ah, const unsigned short* __restrict__ Al,
    const unsigned short* __restrict__ Bh, const unsigned short* __restrict__ Bl,
    unsigned short* __restrict__ Oh, unsigned short* __restrict__ Ol) {
    __shared__ unsigned short stg[(OUT_SPLIT ? 2 : 1) * 64 * 136];
    int tid = threadIdx.x, b = blockIdx.x;
    int mat = b >> 1, rb = b & 1;
    int l = mat / P_;
    size_t aoff = (size_t)(APM ? mat : l) * 16384 + (size_t)rb * 8192;
    size_t boff = (size_t)(BPM ? mat : l) * 16384;
    const unsigned short* ahp = Ah + aoff;
    const unsigned short* alp = Al + aoff;
    const unsigned short* bhp = Bh + boff;
    const unsigned short* blp = Bl + boff;

    int lane = tid & 63, wave = tid >> 6;
    int n = lane & 15, q = lane >> 4;
    int wr = wave * 16;

    f32x4 acc[8];
#pragma unroll
    for (int t = 0; t < 8; ++t) acc[t] = (f32x4){0.f, 0.f, 0.f, 0.f};

    int arow = (wr + n) * 128;
#pragma unroll
    for (int kc = 0; kc < 4; ++kc) {
        int ko = kc * 32 + q * 8;
        bf16x8 avh = *(const bf16x8*)(ahp + arow + ko);
        bf16x8 avl = *(const bf16x8*)(alp + arow + ko);
#pragma unroll
        for (int t = 0; t < 8; ++t) {
            int brow = (t * 16 + n) * 128;
            bf16x8 bvh = *(const bf16x8*)(bhp + brow + ko);
            bf16x8 bvl = *(const bf16x8*)(blp + brow + ko);
            acc[t] = __builtin_amdgcn_mfma_f32_16x16x32_bf16(avh, bvh, acc[t], 0, 0, 0);
            acc[t] = __builtin_amdgcn_mfma_f32_16x16x32_bf16(avh, bvl, acc[t], 0, 0, 0);
            acc[t] = __builtin_amdgcn_mfma_f32_16x16x32_bf16(avl, bvh, acc[t], 0, 0, 0);
        }
    }
#pragma unroll
    for (int t = 0; t < 8; ++t)
#pragma unroll
        for (int r = 0; r < 4; ++r) {
            int row = wr + q * 4 + r;
            float v = acc[t][r];
            unsigned short h = f2bf(v);
            stg[row * 136 + t * 16 + n] = h;
            if constexpr (OUT_SPLIT)
                stg[64 * 136 + row * 136 + t * 16 + n] = f2bf(v - bf2f(h));
        }
    __syncthreads();
    size_t obase = (size_t)mat * 16384 + (size_t)rb * 8192;
#pragma unroll
    for (int i = 0; i < 4; ++i) {
        int c = tid + i * 256;
        int r = c >> 4, off = c & 15;
        *(uint4*)(Oh + obase + r * 128 + off * 8) =
            *(const uint4*)(stg + r * 136 + off * 8);
        if constexpr (OUT_SPLIT)
            *(uint4*)(Ol + obase + r * 128 + off * 8) =
                *(const uint4*)(stg + 64 * 136 + r * 136 + off * 8);
    }
}

// ---------------------------------------------------------------------------
// CSR aggregation: 4 dwordx4 gathers in flight, lane-preloaded indices
// ---------------------------------------------------------------------------

__device__ inline void accum_row(float* acc, uint4 r) {
    acc[0] += bflo(r.x); acc[1] += bfhi(r.x);
    acc[2] += bflo(r.y); acc[3] += bfhi(r.y);
    acc[4] += bflo(r.z); acc[5] += bfhi(r.z);
    acc[6] += bflo(r.w); acc[7] += bfhi(r.w);
}

__global__ __launch_bounds__(256) void aggregate_bf(const unsigned short* __restrict__ xt,
                                                    const int* __restrict__ offT,
                                                    const unsigned short* __restrict__ eSrc,
                                                    unsigned short* __restrict__ agg) {
    int nd = blockIdx.x * 4 + (threadIdx.x >> 6);
    if (nd >= N_) return;
    int l = threadIdx.x & 63;
    int g = l >> 4, c16 = l & 15;
    int beg = offT[nd], end = offT[nd + 1];

    float acc[8];
#pragma unroll
    for (int k = 0; k < 8; ++k) acc[k] = 0.f;

    for (int base = beg; base < end; base += 64) {
        int cnt = min(64, end - base);
        int idxv = (l < cnt) ? (int)eSrc[base + l] : 0;
        int steps = (cnt + 3) >> 2;
        int j = 0;
        for (; j + 3 < steps; j += 4) {
            int e0 = 4 * j + g, e1 = e0 + 4, e2 = e0 + 8, e3 = e0 + 12;
            int i0 = __shfl(idxv, e0, 64);
            int i1 = __shfl(idxv, e1, 64);
            int i2 = __shfl(idxv, e2, 64);
            int i3 = __shfl(idxv, e3, 64);
            int r0 = (e0 < cnt) ? i0 : N_;
            int r1 = (e1 < cnt) ? i1 : N_;
            int r2 = (e2 < cnt) ? i2 : N_;
            int r3 = (e3 < cnt) ? i3 : N_;
            uint4 v0 = ((const uint4*)(xt + (size_t)r0 * D_))[c16];
            uint4 v1 = ((const uint4*)(xt + (size_t)r1 * D_))[c16];
            uint4 v2 = ((const uint4*)(xt + (size_t)r2 * D_))[c16];
            uint4 v3 = ((const uint4*)(xt + (size_t)r3 * D_))[c16];
            accum_row(acc, v0);
            accum_row(acc, v1);
            accum_row(acc, v2);
            accum_row(acc, v3);
        }
        for (; j < steps; ++j) {
            int e0 = 4 * j + g;
            int i0 = __shfl(idxv, e0, 64);
            int r0 = (e0 < cnt) ? i0 : N_;
            uint4 v0 = ((const uint4*)(xt + (size_t)r0 * D_))[c16];
            accum_row(acc, v0);
        }
    }
#pragma unroll
    for (int k = 0; k < 8; ++k) {
        acc[k] += __shfl_xor(acc[k], 16, 64);
        acc[k] += __shfl_xor(acc[k], 32, 64);
    }
    if (g == 0) {
        uint4 o;
        o.x = (unsigned)f2bf(acc[0]) | ((unsigned)f2bf(acc[1]) << 16);
        o.y = (unsigned)f2bf(acc[2]) | ((unsigned)f2bf(acc[3]) << 16);
        o.z = (unsigned)f2bf(acc[4]) | ((unsigned)f2bf(acc[5]) << 16);
        o.w = (unsigned)f2bf(acc[6]) | ((unsigned)f2bf(acc[7]) << 16);
        ((uint4*)(agg + (size_t)nd * D_))[c16] = o;
    }
}

// ---------------------------------------------------------------------------
// gemm_xt0: xt = xb @ Sb[0][pol], bucketed (EPI0-only trimmed mfma_gemm)
// ---------------------------------------------------------------------------

__global__ __launch_bounds__(256) void gemm_xt0(
    const unsigned short* __restrict__ A, const unsigned short* __restrict__ Bw,
    unsigned short* __restrict__ OutB, const int* __restrict__ blist,
    const int* __restrict__ boff, const int* __restrict__ tileOff) {
    __shared__ unsigned short sA[64 * 136];
    __shared__ unsigned short sB[128 * 136];
    __shared__ int rid[TM];
    int tid = threadIdx.x, b = blockIdx.x;
    if (b >= tileOff[P_]) return;
    int pp = 0;
    while (pp < P_ - 1 && b >= tileOff[pp + 1]) ++pp;
    int tb = b - tileOff[pp];
    int cnt = boff[pp + 1] - boff[pp];
    int nrows = min(TM, cnt - tb * TM);
    int rowbase = boff[pp] + tb * TM;
    const unsigned short* B = Bw + (size_t)pp * D_ * D_;

    if (tid < TM)
        rid[tid] = (tid < nrows) ? blist[rowbase + tid] : -1;
    __syncthreads();

#pragma unroll
    for (int i = 0; i < 8; ++i) {
        int c = tid + i * 256;
        int r = c >> 4, off = c & 15;
        *(uint4*)(sB + r * 136 + off * 8) = *(const uint4*)(B + r * 128 + off * 8);
    }
#pragma unroll
    for (int i = 0; i < 4; ++i) {
        int c = tid + i * 256;
        int r = c >> 4, off = c & 15;
        int row = rid[r];
        uint4 v = make_uint4(0, 0, 0, 0);
        if (row >= 0) v = *(const uint4*)(A + (size_t)row * D_ + off * 8);
        *(uint4*)(sA + r * 136 + off * 8) = v;
    }
    __syncthreads();

    int lane = tid & 63, wave = tid >> 6;
    int n = lane & 15, q = lane >> 4, wr = wave * 16;

    f32x4 acc[8];
#pragma unroll
    for (int t = 0; t < 8; ++t) acc[t] = (f32x4){0.f, 0.f, 0.f, 0.f};
#pragma unroll
    for (int kc = 0; kc < 4; ++kc) {
        bf16x8 af = *(const bf16x8*)(sA + (wr + n) * 136 + kc * 32 + q * 8);
#pragma unroll
        for (int t = 0; t < 8; ++t) {
            bf16x8 bf = *(const bf16x8*)(sB + (t * 16 + n) * 136 + kc * 32 + q * 8);
            acc[t] = __builtin_amdgcn_mfma_f32_16x16x32_bf16(af, bf, acc[t], 0, 0, 0);
        }
    }
    __syncthreads();
#pragma unroll
    for (int t = 0; t < 8; ++t)
#pragma unroll
        for (int r = 0; r < 4; ++r)
            sA[(wr + q * 4 + r) * 136 + t * 16 + n] = f2bf(acc[t][r]);
    __syncthreads();
#pragma unroll
    for (int i = 0; i < 4; ++i) {
        int c = tid + i * 256;
        int r = c >> 4, off = c & 15;
        int row = rid[r];
        if (row >= 0)
            *(uint4*)(OutB + (size_t)row * D_ + off * 8) =
                *(const uint4*)(sA + r * 136 + off * 8);
    }
}

// ---------------------------------------------------------------------------
// fused_layer: GEMM1(agg@Dm[pol])+LN+relu -> GEMM2(h@W2^T)+res+LN ->
// [GEMM3(x'@Sn[pol]) unless LAST]. One B-buffer re-staged per phase; h and
// x' pass through per-wave-exclusive sA rows (DS ops in-order per wave, so
// no barrier needed for the wave-local A-tile round trips).
// xres update is in-place safe: each block reads/writes only its own rows.
// ---------------------------------------------------------------------------

template <bool LAST>
__global__ __launch_bounds__(256) void fused_layer(
    const unsigned short* __restrict__ agg, const unsigned short* __restrict__ DmAll,
    const unsigned short* __restrict__ W2b, const unsigned short* __restrict__ SnAll,
    const int* __restrict__ blist, const int* __restrict__ boff,
    const int* __restrict__ tileOff, const float* __restrict__ dnorm,
    const float* __restrict__ b1v, const float* __restrict__ g1v,
    const float* __restrict__ e1v, const float* __restrict__ b2v,
    const float* __restrict__ g2v, const float* __restrict__ e2v,
    const float* __restrict__ rs_ptr, const float* __restrict__ xres,
    const float* __restrict__ x0add, float* __restrict__ OutF,
    unsigned short* __restrict__ OutXt) {
    __shared__ unsigned short sB[128 * 136];  // 34816 B (Dm -> W2 -> Sn)
    __shared__ unsigned short sA[64 * 136];   // 17408 B (agg -> h -> x' -> xt)
    __shared__ int rid[TM];
    __shared__ float dnRow[TM];

    int tid = threadIdx.x, b = blockIdx.x;
    if (b >= tileOff[P_]) return;
    int pp = 0;
    while (pp < P_ - 1 && b >= tileOff[pp + 1]) ++pp;
    int tb = b - tileOff[pp];
    int cnt = boff[pp + 1] - boff[pp];
    int nrows = min(TM, cnt - tb * TM);
    int rowbase = boff[pp] + tb * TM;

    if (tid < TM) {
        int r = (tid < nrows) ? blist[rowbase + tid] : -1;
        rid[tid] = r;
        dnRow[tid] = (r >= 0) ? dnorm[r] : 1.f;
    }
    __syncthreads();

    const unsigned short* Dm = DmAll + (size_t)pp * D_ * D_;
#pragma unroll
    for (int i = 0; i < 8; ++i) {
        int c = tid + i * 256;
        int r = c >> 4, off = c & 15;
        *(uint4*)(sB + r * 136 + off * 8) = *(const uint4*)(Dm + r * 128 + off * 8);
    }
#pragma unroll
    for (int i = 0; i < 4; ++i) {
        int c = tid + i * 256;
        int r = c >> 4, off = c & 15;
        int row = rid[r];
        uint4 v = make_uint4(0, 0, 0, 0);
        if (row >= 0) v = *(const uint4*)(agg + (size_t)row * D_ + off * 8);
        *(uint4*)(sA + r * 136 + off * 8) = v;
    }
    __syncthreads();

    int lane = tid & 63, wave = tid >> 6;
    int n = lane & 15, q = lane >> 4, wr = wave * 16;

    int rowid[4];
    float dn4[4];
#pragma unroll
    for (int r = 0; r < 4; ++r) {
        int rr = wr + q * 4 + r;
        rowid[r] = rid[rr];
        dn4[r] = dnRow[rr];
    }

    // prefetch residual x (fp32) for this lane's C elements (hidden by GEMM1)
    float xr[8][4];
#pragma unroll
    for (int t = 0; t < 8; ++t) {
        int col = t * 16 + n;
#pragma unroll
        for (int r = 0; r < 4; ++r)
            xr[t][r] = (rowid[r] >= 0) ? xres[(size_t)rowid[r] * D_ + col] : 0.f;
    }

    // ---- GEMM1: agg @ Dm ----
    f32x4 acc[8];
#pragma unroll
    for (int t = 0; t < 8; ++t) acc[t] = (f32x4){0.f, 0.f, 0.f, 0.f};
#pragma unroll
    for (int kc = 0; kc < 4; ++kc) {
        bf16x8 af = *(const bf16x8*)(sA + (wr + n) * 136 + kc * 32 + q * 8);
#pragma unroll
        for (int t = 0; t < 8; ++t) {
            bf16x8 bf = *(const bf16x8*)(sB + (t * 16 + n) * 136 + kc * 32 + q * 8);
            acc[t] = __builtin_amdgcn_mfma_f32_16x16x32_bf16(af, bf, acc[t], 0, 0, 0);
        }
    }

    // ---- LN1 + relu -> h ----
    {
        float rs1[4] = {0, 0, 0, 0}, rs2[4] = {0, 0, 0, 0};
#pragma unroll
        for (int t = 0; t < 8; ++t) {
            int col = t * 16 + n;
            float bia = b1v[col];
#pragma unroll
            for (int r = 0; r < 4; ++r) {
                float v = dn4[r] * acc[t][r] + bia;
                acc[t][r] = v;
                rs1[r] += v;
                rs2[r] += v * v;
            }
        }
#pragma unroll
        for (int mk = 1; mk < 16; mk <<= 1)
#pragma unroll
            for (int r = 0; r < 4; ++r) {
                rs1[r] += __shfl_xor(rs1[r], mk, 64);
                rs2[r] += __shfl_xor(rs2[r], mk, 64);
            }
        float mr[4], rv[4];
#pragma unroll
        for (int r = 0; r < 4; ++r) {
            float mm = rs1[r] * (1.f / 128.f);
            mr[r] = mm;
            rv[r] = rsqrtf(rs2[r] * (1.f / 128.f) - mm * mm + EPS_);
        }
#pragma unroll
        for (int t = 0; t < 8; ++t) {
            int col = t * 16 + n;
            float gg = g1v[col], bbv = e1v[col];
#pragma unroll
            for (int r = 0; r < 4; ++r)
                acc[t][r] = fmaxf((acc[t][r] - mr[r]) * rv[r] * gg + bbv, 0.f);
        }
    }

    __syncthreads();  // all waves done reading sB(Dm) & sA(agg)
    // restage sB <- W2b; write h into own sA rows (wave-exclusive)
#pragma unroll
    for (int i = 0; i < 8; ++i) {
        int c = tid + i * 256;
        int r = c >> 4, off = c & 15;
        *(uint4*)(sB + r * 136 + off * 8) = *(const uint4*)(W2b + r * 128 + off * 8);
    }
#pragma unroll
    for (int t = 0; t < 8; ++t)
#pragma unroll
        for (int r = 0; r < 4; ++r)
            sA[(wr + q * 4 + r) * 136 + t * 16 + n] = f2bf(acc[t][r]);
    __syncthreads();  // sB(W2) ready

    // ---- GEMM2: h @ W2^T ----
#pragma unroll
    for (int t = 0; t < 8; ++t) acc[t] = (f32x4){0.f, 0.f, 0.f, 0.f};
#pragma unroll
    for (int kc = 0; kc < 4; ++kc) {
        bf16x8 af = *(const bf16x8*)(sA + (wr + n) * 136 + kc * 32 + q * 8);
#pragma unroll
        for (int t = 0; t < 8; ++t) {
            bf16x8 bf = *(const bf16x8*)(sB + (t * 16 + n) * 136 + kc * 32 + q * 8);
            acc[t] = __builtin_amdgcn_mfma_f32_16x16x32_bf16(af, bf, acc[t], 0, 0, 0);
        }
    }

    // ---- residual + LN2 -> x' ----
    {
        float rs = rs_ptr[0];
        float rs1[4] = {0, 0, 0, 0}, rs2[4] = {0, 0, 0, 0};
#pragma unroll
        for (int t = 0; t < 8; ++t) {
            int col = t * 16 + n;
            float bia = b2v[col];
#pragma unroll
            for (int r = 0; r < 4; ++r) {
                float v = rs * (acc[t][r] + bia) + xr[t][r];
                acc[t][r] = v;
                rs1[r] += v;
                rs2[r] += v * v;
            }
        }
#pragma unroll
        for (int mk = 1; mk < 16; mk <<= 1)
#pragma unroll
            for (int r = 0; r < 4; ++r) {
                rs1[r] += __shfl_xor(rs1[r], mk, 64);
                rs2[r] += __shfl_xor(rs2[r], mk, 64);
            }
        float mr[4], rv[4];
#pragma unroll
        for (int r = 0; r < 4; ++r) {
            float mm = rs1[r] * (1.f / 128.f);
            mr[r] = mm;
            rv[r] = rsqrtf(rs2[r] * (1.f / 128.f) - mm * mm + EPS_);
        }
#pragma unroll
        for (int t = 0; t < 8; ++t) {
            int col = t * 16 + n;
            float gg = g2v[col], bbv = e2v[col];
#pragma unroll
            for (int r = 0; r < 4; ++r) {
                float nv = (acc[t][r] - mr[r]) * rv[r] * gg + bbv;
                if constexpr (LAST) {
                    if (rowid[r] >= 0) nv += x0add[(size_t)rowid[r] * D_ + col];
                }
                acc[t][r] = nv;
                // scattered fp32 store: 16 lanes -> 64B contiguous, aligned
                if (rowid[r] >= 0) OutF[(size_t)rowid[r] * D_ + col] = nv;
            }
        }
    }

    if constexpr (!LAST) {
        __syncthreads();  // all waves done reading sB(W2)
        const unsigned short* Sn = SnAll + (size_t)pp * D_ * D_;
#pragma unroll
        for (int i = 0; i < 8; ++i) {
            int c = tid + i * 256;
            int r = c >> 4, off = c & 15;
            *(uint4*)(sB + r * 136 + off * 8) = *(const uint4*)(Sn + r * 128 + off * 8);
        }
#pragma unroll
        for (int t = 0; t < 8; ++t)
#pragma unroll
            for (int r = 0; r < 4; ++r)
                sA[(wr + q * 4 + r) * 136 + t * 16 + n] = f2bf(acc[t][r]);
        __syncthreads();  // sB(Sn) ready

        // ---- GEMM3: x' @ Sn ----
#pragma unroll
        for (int t = 0; t < 8; ++t) acc[t] = (f32x4){0.f, 0.f, 0.f, 0.f};
#pragma unroll
        for (int kc = 0; kc < 4; ++kc) {
            bf16x8 af = *(const bf16x8*)(sA + (wr + n) * 136 + kc * 32 + q * 8);
#pragma unroll
            for (int t = 0; t < 8; ++t) {
                bf16x8 bf = *(const bf16x8*)(sB + (t * 16 + n) * 136 + kc * 32 + q * 8);
                acc[t] = __builtin_amdgcn_mfma_f32_16x16x32_bf16(af, bf, acc[t], 0, 0, 0);
            }
        }
        // stage xt (own rows), then cooperative coalesced store
#pragma unroll
        for (int t = 0; t < 8; ++t)
#pragma unroll
            for (int r = 0; r < 4; ++r)
                sA[(wr + q * 4 + r) * 136 + t * 16 + n] = f2bf(acc[t][r]);
        __syncthreads();
#pragma unroll
        for (int i = 0; i < 4; ++i) {
            int c = tid + i * 256;
            int r = c >> 4, off = c & 15;
            int row = rid[r];
            if (row >= 0)
                *(uint4*)(OutXt + (size_t)row * D_ + off * 8) =
                    *(const uint4*)(sA + r * 136 + off * 8);
        }
    }
}

// ---------------------------------------------------------------------------
// Host launch
// ---------------------------------------------------------------------------

extern "C" void kernel_launch(void* const* d_in, const int* in_sizes, int n_in,
                              void* d_out, int out_size, void* d_ws, size_t ws_size,
                              hipStream_t stream) {
    const float* x0 = (const float*)d_in[0];
    const int* ei = (const int*)d_in[1];
    const int* ring = (const int*)d_in[2];
    const float* Wr = (const float*)d_in[3];
    const float* S = (const float*)d_in[4];
    const float* dS = (const float*)d_in[5];
    const float* R = (const float*)d_in[6];
    const float* dR = (const float*)d_in[7];
    const float* rsc = (const float*)d_in[8];
    const float* W1 = (const float*)d_in[9];
    const float* b1 = (const float*)d_in[10];
    const float* lng = (const float*)d_in[11];
    const float* lnb = (const float*)d_in[12];
    const float* W2 = (const float*)d_in[13];
    const float* b2 = (const float*)d_in[14];
    const float* ng = (const float*)d_in[15];
    const float* nb = (const float*)d_in[16];
    float* out = (float*)d_out;

    char* w = (char*)d_ws;
    auto alloc = [&](size_t bytes) {
        char* p = w;
        w += (bytes + 15) & ~(size_t)15;
        return p;
    };
    unsigned short* xb = (unsigned short*)alloc((size_t)N_ * D_ * 2);          // bf16 x0
    unsigned short* bufAb = (unsigned short*)alloc((size_t)(N_ + 1) * D_ * 2); // xt (+zero row)
    unsigned short* bufBb = (unsigned short*)alloc((size_t)N_ * D_ * 2);       // agg
    float* xbuf = (float*)alloc((size_t)N_ * D_ * 4);                          // fp32 x (in-place)
    unsigned short* Sb = (unsigned short*)alloc((size_t)L_ * P_ * D_ * D_ * 2);
    unsigned short* Dmb = (unsigned short*)alloc((size_t)L_ * P_ * D_ * D_ * 2);
    unsigned short* W2b = (unsigned short*)alloc((size_t)L_ * D_ * D_ * 2);
    unsigned short* Arh = (unsigned short*)alloc((size_t)MAT * 16384 * 2);
    unsigned short* Arl = (unsigned short*)alloc((size_t)MAT * 16384 * 2);
    unsigned short* W1h = (unsigned short*)alloc((size_t)3 * 16384 * 2);
    unsigned short* W1l = (unsigned short*)alloc((size_t)3 * 16384 * 2);
    unsigned short* Wrth = (unsigned short*)alloc((size_t)3 * 16384 * 2);
    unsigned short* Wrtl = (unsigned short*)alloc((size_t)3 * 16384 * 2);
    unsigned short* T1th = (unsigned short*)alloc((size_t)MAT * 16384 * 2);
    unsigned short* T1tl = (unsigned short*)alloc((size_t)MAT * 16384 * 2);
    float* dnorm = (float*)alloc((size_t)N_ * 4);
    int* histG = (int*)alloc((size_t)HTOT * 4);
    unsigned* bufT = (unsigned*)alloc((size_t)E_ * 4);
    unsigned char* bufS8 = (unsigned char*)alloc((size_t)E_);
    unsigned short* eSrc = (unsigned short*)alloc((size_t)E_ * 2);
    int* offT = (int*)alloc((size_t)(N_ + 1) * 4);
    int* pol = (int*)alloc((size_t)N_ * 4);
    int* boff = (int*)alloc((size_t)(P_ + 1) * 4);
    int* tileOff = (int*)alloc((size_t)(P_ + 1) * 4);
    int* blist = (int*)alloc((size_t)N_ * 4);
    int* blkSum = (int*)alloc((size_t)NSB * 4);
    int* blkOff = (int*)alloc((size_t)NSB * 4);
    int* bcnt = (int*)alloc((size_t)2 * P_ * 4);  // zeroed region: bcnt + bcur
    int* bcur = bcnt + P_;

    hipMemsetAsync(bcnt, 0, (size_t)2 * P_ * 4, stream);

    const int BTILES = N_ / TM + P_;  // 790, upper bound on bucketed tiles

    setup_nk<<<NBK, 256, 0, stream>>>(ring, pol, bcnt, ei, histG);
    scanH1<<<NSB, 1024, 0, stream>>>(histG, blkSum);
    scanH2<<<1, 64, 0, stream>>>(blkSum, blkOff, offT, bcnt, boff, tileOff);
    scanH3<<<NSB, 1024, 0, stream>>>(histG, blkOff);
    scatterTS<<<NBK, 256, 0, stream>>>(ei, histG, bufT, bufS8);
    finalize3<<<3 * NBUK, 256, 0, stream>>>(bufT, bufS8, histG, offT, eSrc, dnorm,
                                            pol, boff, bcur, blist);
    prep_all<<<GPREP, 256, 0, stream>>>(x0, xb, bufAb, S, dS, Sb, W2, W2b,
                                        R, dR, W1, Wr, Arh, Arl, W1h, W1l, Wrth, Wrtl);
    // T1t[mat][k][i] = sum_j W1[l][k][j] * (R+dR)[mat][i][j]
    small_mfma<false, true, true><<<2 * MAT, 256, 0, stream>>>(
        W1h, W1l, Arh, Arl, T1th, T1tl);
    // Dmb[mat][k][d] = sum_i T1t[mat][k][i] * Wr^T[l][d][i]
    small_mfma<true, false, false><<<2 * MAT, 256, 0, stream>>>(
        T1th, T1tl, Wrth, Wrtl, Dmb, nullptr);

    // layer 0 send-transform: xt0 = x0 @ (S+dS)[0][pol]
    gemm_xt0<<<BTILES, 256, 0, stream>>>(xb, Sb, bufAb, blist, boff, tileOff);

    for (int l = 0; l < L_; ++l) {
        const size_t lPDD = (size_t)l * P_ * D_ * D_;
        const size_t lDD = (size_t)l * D_ * D_;
        const size_t lD = (size_t)l * D_;
        aggregate_bf<<<N_ / 4, 256, 0, stream>>>(bufAb, offT, eSrc, bufBb);
        const float* xr = (l == 0) ? x0 : xbuf;
        if (l < L_ - 1) {
            fused_layer<false><<<BTILES, 256, 0, stream>>>(
                bufBb, Dmb + lPDD, W2b + lDD, Sb + lPDD + (size_t)P_ * D_ * D_,
                blist, boff, tileOff, dnorm,
                b1 + lD, lng + lD, lnb + lD, b2 + lD, ng + lD, nb + lD,
                rsc + l, xr, nullptr, xbuf, bufAb);
        } else {
            fused_layer<true><<<BTILES, 256, 0, stream>>>(
                bufBb, Dmb + lPDD, W2b + lDD, nullptr,
                blist, boff, tileOff, dnorm,
                b1 + lD, lng + lD, lnb + lD, b2 + lD, ng + lD, nb + lD,
                rsc + l, xr, x0, out, nullptr);
        }
    }
}

// Round 8
// 378.597 us; speedup vs baseline: 3.4281x; 1.0076x over previous
//
#include <hip/hip_runtime.h>
#include <hip/hip_bf16.h>

// Problem constants
constexpr int N_ = 50000;
constexpr int D_ = 128;
constexpr int E_ = 800000;
constexpr int P_ = 9;
constexpr int L_ = 3;
constexpr float EPS_ = 1e-5f;

constexpr int TM = 64;    // rows per GEMM block
constexpr int CHUNK = 4096;                    // edges per hist/scatter block
constexpr int NBK = (E_ + CHUNK - 1) / CHUNK;  // 196 edge chunks
constexpr int NBUK = 196;                      // node buckets (50000>>8 = 195 max)
constexpr int HHALF = 256 * NBK;               // 50176 (per-half hist size)
constexpr int HTOT = 2 * HHALF;                // 100352 = 98 * 1024 exactly
constexpr int NSB = HTOT / 1024;               // 98 scan blocks
constexpr int MAT = L_ * P_;                   // 27 small matrices

typedef short bf16x8 __attribute__((ext_vector_type(8)));
typedef float f32x4 __attribute__((ext_vector_type(4)));

// async 16B global->LDS copy; lds base must be wave-uniform, data lands at
// base + lane*16  [guide §5, m97]
#define GLD16(gp, lp)                                                        \
    __builtin_amdgcn_global_load_lds(                                        \
        (const __attribute__((address_space(1))) unsigned int*)(gp),         \
        (__attribute__((address_space(3))) unsigned int*)(lp), 16, 0, 0)

__device__ inline unsigned short f2bf(float f) {
    __hip_bfloat16 h = __float2bfloat16(f);
    return *reinterpret_cast<unsigned short*>(&h);
}
__device__ inline float bflo(unsigned u) { return __uint_as_float(u << 16); }
__device__ inline float bfhi(unsigned u) { return __uint_as_float(u & 0xffff0000u); }
__device__ inline float bf2f(unsigned short h) {
    return __uint_as_float((unsigned)h << 16);
}

// ---------------------------------------------------------------------------
// setup_nk: node polarity init + edge histograms (merged)
// ---------------------------------------------------------------------------

__global__ __launch_bounds__(256) void setup_nk(const int* __restrict__ ring,
                                                int* __restrict__ pol,
                                                int* __restrict__ bcnt,
                                                const int* __restrict__ ei,
                                                int* __restrict__ histG) {
    __shared__ int h[P_];
    __shared__ int hT[256], hS[256];
    int blk = blockIdx.x, tid = threadIdx.x;
    if (tid < P_) h[tid] = 0;
    hT[tid] = 0;
    hS[tid] = 0;
    __syncthreads();
    int n = blk * 256 + tid;
    if (n < N_) {
        int p = ring[n] % P_;
        pol[n] = p;
        atomicAdd(&h[p], 1);
    }
    int base = blk * CHUNK;
#pragma unroll
    for (int i = 0; i < CHUNK / 256; ++i) {
        int e = base + tid + i * 256;
        if (e < E_) {
            atomicAdd(&hS[ei[e] >> 8], 1);
            atomicAdd(&hT[ei[E_ + e] >> 8], 1);
        }
    }
    __syncthreads();
    if (tid < P_ && h[tid] > 0) atomicAdd(&bcnt[tid], h[tid]);
    histG[tid * NBK + blk] = hT[tid];
    histG[HHALF + tid * NBK + blk] = hS[tid];
}

// ---------------------------------------------------------------------------
// 3-phase exclusive scan of histG[HTOT]
// ---------------------------------------------------------------------------

__global__ __launch_bounds__(1024) void scanH1(int* __restrict__ a,
                                               int* __restrict__ blkSum) {
    __shared__ int wsum[16];
    int tid = threadIdx.x, lane = tid & 63, wid = tid >> 6;
    int idx = blockIdx.x * 1024 + tid;
    int v = a[idx];
    int inc = v;
#pragma unroll
    for (int o = 1; o < 64; o <<= 1) {
        int t = __shfl_up(inc, o, 64);
        if (lane >= o) inc += t;
    }
    if (lane == 63) wsum[wid] = inc;
    __syncthreads();
    if (tid < 16) {
        int s = wsum[tid];
#pragma unroll
        for (int o = 1; o < 16; o <<= 1) {
            int t = __shfl_up(s, o, 64);
            if (tid >= o) s += t;
        }
        wsum[tid] = s;
    }
    __syncthreads();
    int wexcl = (wid == 0) ? 0 : wsum[wid - 1];
    a[idx] = wexcl + inc - v;
    if (tid == 1023) blkSum[blockIdx.x] = wsum[15];
}

__global__ void scanH2(const int* __restrict__ blkSum, int* __restrict__ blkOff,
                       int* __restrict__ offT, const int* __restrict__ bcnt,
                       int* __restrict__ boff, int* __restrict__ tileOff) {
    if (threadIdx.x != 0) return;
    int run = 0;
    for (int i = 0; i < NSB; ++i) {
        blkOff[i] = run;
        run += blkSum[i];
    }
    offT[N_] = E_;
    boff[0] = 0;
    tileOff[0] = 0;
    for (int p = 0; p < P_; ++p) {
        boff[p + 1] = boff[p] + bcnt[p];
        tileOff[p + 1] = tileOff[p] + (bcnt[p] + TM - 1) / TM;
    }
}

__global__ __launch_bounds__(1024) void scanH3(int* __restrict__ a,
                                               const int* __restrict__ blkOff) {
    int idx = blockIdx.x * 1024 + threadIdx.x;
    a[idx] += blkOff[blockIdx.x];
}

// ---------------------------------------------------------------------------
// scatter into tgt-buckets (packed) and src-buckets (low byte)
// ---------------------------------------------------------------------------

__global__ __launch_bounds__(256) void scatterTS(const int* __restrict__ ei,
                                                 const int* __restrict__ histG,
                                                 unsigned* __restrict__ bufT,
                                                 unsigned char* __restrict__ bufS8) {
    __shared__ int ldsT[256], ldsS[256];
    int blk = blockIdx.x, tid = threadIdx.x;
    ldsT[tid] = histG[tid * NBK + blk];
    ldsS[tid] = histG[HHALF + tid * NBK + blk] - E_;
    __syncthreads();
    int base = blk * CHUNK;
#pragma unroll
    for (int i = 0; i < CHUNK / 256; ++i) {
        int e = base + tid + i * 256;
        if (e < E_) {
            int s = ei[e], t = ei[E_ + e];
            int pT = atomicAdd(&ldsT[t >> 8], 1);
            bufT[pT] = ((unsigned)t << 16) | (unsigned)s;
            int pS = atomicAdd(&ldsS[s >> 8], 1);
            bufS8[pS] = (unsigned char)(s & 255);
        }
    }
}

// ---------------------------------------------------------------------------
// finalize3: finalizeT | finalizeS | bucket_fill (role by blockIdx)
// ---------------------------------------------------------------------------

__global__ __launch_bounds__(256) void finalize3(
    const unsigned* __restrict__ bufT, const unsigned char* __restrict__ bufS8,
    const int* __restrict__ histG, int* __restrict__ offT,
    unsigned short* __restrict__ eSrc, float* __restrict__ dnorm,
    const int* __restrict__ pol, const int* __restrict__ boff,
    int* __restrict__ bcur, int* __restrict__ blist) {
    __shared__ int s0[256];
    __shared__ int s1[256];
    int bb = blockIdx.x, tid = threadIdx.x;

    if (bb < NBUK) {
        int b = bb;
        int start = histG[b * NBK];
        int end = histG[(b + 1) * NBK];
        s0[tid] = 0;
        __syncthreads();
        for (int i = start + tid; i < end; i += 256)
            atomicAdd(&s0[(bufT[i] >> 16) & 255], 1);
        __syncthreads();
        if (tid < 64) {
            int b0 = 4 * tid;
            int v0 = s0[b0], v1 = s0[b0 + 1], v2 = s0[b0 + 2], v3 = s0[b0 + 3];
            int lsum = v0 + v1 + v2 + v3;
            int inc = lsum;
#pragma unroll
            for (int o = 1; o < 64; o <<= 1) {
                int t = __shfl_up(inc, o, 64);
                if (tid >= o) inc += t;
            }
            int excl = inc - lsum;
            s1[b0] = excl;
            s1[b0 + 1] = excl + v0;
            s1[b0 + 2] = excl + v0 + v1;
            s1[b0 + 3] = excl + v0 + v1 + v2;
        }
        __syncthreads();
        int node = (b << 8) + tid;
        if (node < N_) offT[node] = start + s1[tid];
        __syncthreads();
        for (int i = start + tid; i < end; i += 256) {
            unsigned pk = bufT[i];
            int pos = start + atomicAdd(&s1[(pk >> 16) & 255], 1);
            eSrc[pos] = (unsigned short)(pk & 0xFFFF);
        }
    } else if (bb < 2 * NBUK) {
        int b = bb - NBUK;
        int start = histG[HHALF + b * NBK] - E_;
        int end = histG[HHALF + (b + 1) * NBK] - E_;
        s0[tid] = 0;
        __syncthreads();
        for (int i = start + tid; i < end; i += 256) atomicAdd(&s0[bufS8[i]], 1);
        __syncthreads();
        int node = (b << 8) + tid;
        if (node < N_) {
            int dg = s0[tid];
            dnorm[node] = 1.f / (float)(dg > 1 ? dg : 1);
        }
    } else {
        int b = bb - 2 * NBUK;
        if (tid < P_) s0[tid] = 0;
        __syncthreads();
        int n = b * 256 + tid;
        int p = 0, loc = 0;
        bool act = (n < N_);
        if (act) {
            p = pol[n];
            loc = atomicAdd(&s0[p], 1);
        }
        __syncthreads();
        if (tid < P_ && s0[tid] > 0) s1[tid] = atomicAdd(&bcur[tid], s0[tid]);
        __syncthreads();
        if (act) blist[boff[p] + s1[p] + loc] = n;
    }
}

// ---------------------------------------------------------------------------
// prep_all: conv4 | zero rows | prep_S | prep_W2 | prep_split merged
// ---------------------------------------------------------------------------

constexpr int GCONV = N_ * D_ / 4 / 256;       // 6250
constexpr int GS = L_ * P_ * D_ * D_ / 256;    // 1728
constexpr int GW2 = L_ * D_ * D_ / 256;        // 192
constexpr int GSPL = (MAT + 6) * 16384 / 256;  // 2112
constexpr int GPREP = GCONV + 1 + GS + GW2 + GSPL;

__global__ __launch_bounds__(256) void prep_all(
    const float* __restrict__ x, unsigned short* __restrict__ xb,
    unsigned short* __restrict__ bufAb, unsigned short* __restrict__ bufBb,
    const float* __restrict__ S, const float* __restrict__ dS,
    unsigned short* __restrict__ Sb,
    const float* __restrict__ W2, unsigned short* __restrict__ W2b,
    const float* __restrict__ R, const float* __restrict__ dR,
    const float* __restrict__ W1, const float* __restrict__ Wr,
    unsigned short* __restrict__ Arh, unsigned short* __restrict__ Arl,
    unsigned short* __restrict__ W1h, unsigned short* __restrict__ W1l,
    unsigned short* __restrict__ Wrth, unsigned short* __restrict__ Wrtl) {
    int b = blockIdx.x, tid = threadIdx.x;
    if (b < GCONV) {
        int i = b * 256 + tid;
        float4 v = ((const float4*)x)[i];
        ushort4 o;
        o.x = f2bf(v.x); o.y = f2bf(v.y); o.z = f2bf(v.z); o.w = f2bf(v.w);
        ((ushort4*)xb)[i] = o;
    } else if (b < GCONV + 1) {
        if (tid < 64) {
            ((unsigned*)(xb + (size_t)N_ * D_))[tid] = 0;
            ((unsigned*)(bufAb + (size_t)N_ * D_))[tid] = 0;
            ((unsigned*)(bufBb + (size_t)N_ * D_))[tid] = 0;
        }
    } else if (b < GCONV + 1 + GS) {
        int idx = (b - GCONV - 1) * 256 + tid;
        int base = idx / (D_ * D_);
        int rem = idx % (D_ * D_);
        int c = rem / D_, d = rem % D_;
        size_t in = (size_t)base * D_ * D_ + (size_t)d * D_ + c;
        Sb[idx] = f2bf(S[in] + dS[in]);
    } else if (b < GCONV + 1 + GS + GW2) {
        int idx = (b - GCONV - 1 - GS) * 256 + tid;
        W2b[idx] = f2bf(W2[idx]);
    } else {
        constexpr int SZ1 = MAT * 16384;
        constexpr int SZ2 = SZ1 + 3 * 16384;
        int idx = (b - GCONV - 1 - GS - GW2) * 256 + tid;
        float v;
        unsigned short* oh;
        unsigned short* ol;
        int j;
        if (idx < SZ1) {
            v = R[idx] + dR[idx];
            oh = Arh; ol = Arl; j = idx;
        } else if (idx < SZ2) {
            j = idx - SZ1;
            v = W1[j];
            oh = W1h; ol = W1l;
        } else {
            j = idx - SZ2;
            int l = j >> 14, rem = j & 16383;
            int d = rem >> 7, i = rem & 127;
            v = Wr[(l << 14) + i * 128 + d];
            oh = Wrth; ol = Wrtl;
        }
        unsigned short h = f2bf(v);
        oh[j] = h;
        ol[j] = f2bf(v - bf2f(h));
    }
}

// ---------------------------------------------------------------------------
// Batched small MFMA GEMM (fp32-equivalent via 2-term bf16 split)
// ---------------------------------------------------------------------------

template <bool APM, bool BPM, bool OUT_SPLIT>
__global__ __launch_bounds__(256) void small_mfma(
    const unsigned short* __restrict__ Ah, const unsigned short* __restrict__ Al,
    const unsigned short* __restrict__ Bh, const unsigned short* __restrict__ Bl,
    unsigned short* __restrict__ Oh, unsigned short* __restrict__ Ol) {
    __shared__ unsigned short stg[(OUT_SPLIT ? 2 : 1) * 64 * 136];
    int tid = threadIdx.x, b = blockIdx.x;
    int mat = b >> 1, rb = b & 1;
    int l = mat / P_;
    size_t aoff = (size_t)(APM ? mat : l) * 16384 + (size_t)rb * 8192;
    size_t boff = (size_t)(BPM ? mat : l) * 16384;
    const unsigned short* ahp = Ah + aoff;
    const unsigned short* alp = Al + aoff;
    const unsigned short* bhp = Bh + boff;
    const unsigned short* blp = Bl + boff;

    int lane = tid & 63, wave = tid >> 6;
    int n = lane & 15, q = lane >> 4;
    int wr = wave * 16;

    f32x4 acc[8];
#pragma unroll
    for (int t = 0; t < 8; ++t) acc[t] = (f32x4){0.f, 0.f, 0.f, 0.f};

    int arow = (wr + n) * 128;
#pragma unroll
    for (int kc = 0; kc < 4; ++kc) {
        int ko = kc * 32 + q * 8;
        bf16x8 avh = *(const bf16x8*)(ahp + arow + ko);
        bf16x8 avl = *(const bf16x8*)(alp + arow + ko);
#pragma unroll
        for (int t = 0; t < 8; ++t) {
            int brow = (t * 16 + n) * 128;
            bf16x8 bvh = *(const bf16x8*)(bhp + brow + ko);
            bf16x8 bvl = *(const bf16x8*)(blp + brow + ko);
            acc[t] = __builtin_amdgcn_mfma_f32_16x16x32_bf16(avh, bvh, acc[t], 0, 0, 0);
            acc[t] = __builtin_amdgcn_mfma_f32_16x16x32_bf16(avh, bvl, acc[t], 0, 0, 0);
            acc[t] = __builtin_amdgcn_mfma_f32_16x16x32_bf16(avl, bvh, acc[t], 0, 0, 0);
        }
    }
#pragma unroll
    for (int t = 0; t < 8; ++t)
#pragma unroll
        for (int r = 0; r < 4; ++r) {
            int row = wr + q * 4 + r;
            float v = acc[t][r];
            unsigned short h = f2bf(v);
            stg[row * 136 + t * 16 + n] = h;
            if constexpr (OUT_SPLIT)
                stg[64 * 136 + row * 136 + t * 16 + n] = f2bf(v - bf2f(h));
        }
    __syncthreads();
    size_t obase = (size_t)mat * 16384 + (size_t)rb * 8192;
#pragma unroll
    for (int i = 0; i < 4; ++i) {
        int c = tid + i * 256;
        int r = c >> 4, off = c & 15;
        *(uint4*)(Oh + obase + r * 128 + off * 8) =
            *(const uint4*)(stg + r * 136 + off * 8);
        if constexpr (OUT_SPLIT)
            *(uint4*)(Ol + obase + r * 128 + off * 8) =
                *(const uint4*)(stg + 64 * 136 + r * 136 + off * 8);
    }
}

// ---------------------------------------------------------------------------
// CSR aggregation: 4 dwordx4 gathers in flight, lane-preloaded indices
// ---------------------------------------------------------------------------

__device__ inline void accum_row(float* acc, uint4 r) {
    acc[0] += bflo(r.x); acc[1] += bfhi(r.x);
    acc[2] += bflo(r.y); acc[3] += bfhi(r.y);
    acc[4] += bflo(r.z); acc[5] += bfhi(r.z);
    acc[6] += bflo(r.w); acc[7] += bfhi(r.w);
}

__global__ __launch_bounds__(256) void aggregate_bf(const unsigned short* __restrict__ xt,
                                                    const int* __restrict__ offT,
                                                    const unsigned short* __restrict__ eSrc,
                                                    unsigned short* __restrict__ agg) {
    int nd = blockIdx.x * 4 + (threadIdx.x >> 6);
    if (nd >= N_) return;
    int l = threadIdx.x & 63;
    int g = l >> 4, c16 = l & 15;
    int beg = offT[nd], end = offT[nd + 1];

    float acc[8];
#pragma unroll
    for (int k = 0; k < 8; ++k) acc[k] = 0.f;

    for (int base = beg; base < end; base += 64) {
        int cnt = min(64, end - base);
        int idxv = (l < cnt) ? (int)eSrc[base + l] : 0;
        int steps = (cnt + 3) >> 2;
        int j = 0;
        for (; j + 3 < steps; j += 4) {
            int e0 = 4 * j + g, e1 = e0 + 4, e2 = e0 + 8, e3 = e0 + 12;
            int i0 = __shfl(idxv, e0, 64);
            int i1 = __shfl(idxv, e1, 64);
            int i2 = __shfl(idxv, e2, 64);
            int i3 = __shfl(idxv, e3, 64);
            int r0 = (e0 < cnt) ? i0 : N_;
            int r1 = (e1 < cnt) ? i1 : N_;
            int r2 = (e2 < cnt) ? i2 : N_;
            int r3 = (e3 < cnt) ? i3 : N_;
            uint4 v0 = ((const uint4*)(xt + (size_t)r0 * D_))[c16];
            uint4 v1 = ((const uint4*)(xt + (size_t)r1 * D_))[c16];
            uint4 v2 = ((const uint4*)(xt + (size_t)r2 * D_))[c16];
            uint4 v3 = ((const uint4*)(xt + (size_t)r3 * D_))[c16];
            accum_row(acc, v0);
            accum_row(acc, v1);
            accum_row(acc, v2);
            accum_row(acc, v3);
        }
        for (; j < steps; ++j) {
            int e0 = 4 * j + g;
            int i0 = __shfl(idxv, e0, 64);
            int r0 = (e0 < cnt) ? i0 : N_;
            uint4 v0 = ((const uint4*)(xt + (size_t)r0 * D_))[c16];
            accum_row(acc, v0);
        }
    }
#pragma unroll
    for (int k = 0; k < 8; ++k) {
        acc[k] += __shfl_xor(acc[k], 16, 64);
        acc[k] += __shfl_xor(acc[k], 32, 64);
    }
    if (g == 0) {
        uint4 o;
        o.x = (unsigned)f2bf(acc[0]) | ((unsigned)f2bf(acc[1]) << 16);
        o.y = (unsigned)f2bf(acc[2]) | ((unsigned)f2bf(acc[3]) << 16);
        o.z = (unsigned)f2bf(acc[4]) | ((unsigned)f2bf(acc[5]) << 16);
        o.w = (unsigned)f2bf(acc[6]) | ((unsigned)f2bf(acc[7]) << 16);
        ((uint4*)(agg + (size_t)nd * D_))[c16] = o;
    }
}

// ---------------------------------------------------------------------------
// LDS layout helpers: zero-padded rows (128 shorts), 16B chunk c of row r
// stored at chunk c ^ (r & 15). MFMA b128 reads and transpose b16 writes both
// spread across all 32 banks (derived; was 4-way conflicted at stride 136).
// Staging via global_load_lds: LDS side linear (base + lane*16), swizzle
// folded into the per-lane GLOBAL address.
// ---------------------------------------------------------------------------

// stage one 128x128 bf16 matrix (natural layout) into sB, async
__device__ inline void stage_B_async(const unsigned short* __restrict__ B,
                                     unsigned short* sB, int wave, int lane) {
    int rsub = lane >> 4, cl = lane & 15;
#pragma unroll
    for (int j = 0; j < 8; ++j) {
        int seg = wave * 8 + j;
        int row = seg * 4 + rsub;
        GLD16(B + row * 128 + ((cl ^ (row & 15)) << 3), sB + seg * 512);
    }
}

// stage 64 gathered rows (rid; <0 -> zero row at N_) into sA, async
__device__ inline void stage_A_async(const unsigned short* __restrict__ A,
                                     const int* rid, unsigned short* sA,
                                     int wave, int lane) {
    int rsub = lane >> 4, cl = lane & 15;
#pragma unroll
    for (int j = 0; j < 4; ++j) {
        int seg = wave * 4 + j;
        int rloc = seg * 4 + rsub;
        int rw = rid[rloc];
        size_t grow = (rw >= 0) ? (size_t)rw : (size_t)N_;
        GLD16(A + grow * 128 + ((cl ^ (rloc & 15)) << 3), sA + seg * 512);
    }
}

// ---------------------------------------------------------------------------
// gemm_xt0: xt = xb @ Sb[0][pol], bucketed
// ---------------------------------------------------------------------------

__global__ __launch_bounds__(256) void gemm_xt0(
    const unsigned short* __restrict__ A, const unsigned short* __restrict__ Bw,
    unsigned short* __restrict__ OutB, const int* __restrict__ blist,
    const int* __restrict__ boff, const int* __restrict__ tileOff) {
    __shared__ unsigned short sB[128 * 128];
    __shared__ unsigned short sA[64 * 128];
    __shared__ int rid[TM];
    int tid = threadIdx.x, b = blockIdx.x;
    if (b >= tileOff[P_]) return;
    int pp = 0;
    while (pp < P_ - 1 && b >= tileOff[pp + 1]) ++pp;
    int tb = b - tileOff[pp];
    int cnt = boff[pp + 1] - boff[pp];
    int nrows = min(TM, cnt - tb * TM);
    int rowbase = boff[pp] + tb * TM;

    if (tid < TM)
        rid[tid] = (tid < nrows) ? blist[rowbase + tid] : -1;
    __syncthreads();

    int lane = tid & 63, wave = tid >> 6;
    stage_B_async(Bw + (size_t)pp * D_ * D_, sB, wave, lane);
    stage_A_async(A, rid, sA, wave, lane);
    __syncthreads();

    int n = lane & 15, q = lane >> 4, wr = wave * 16;

    f32x4 acc[8];
#pragma unroll
    for (int t = 0; t < 8; ++t) acc[t] = (f32x4){0.f, 0.f, 0.f, 0.f};
#pragma unroll
    for (int kc = 0; kc < 4; ++kc) {
        int cs = (((kc << 2) + q) ^ n) << 3;
        bf16x8 af = *(const bf16x8*)(sA + (wr + n) * 128 + cs);
#pragma unroll
        for (int t = 0; t < 8; ++t) {
            bf16x8 bf = *(const bf16x8*)(sB + (t * 16 + n) * 128 + cs);
            acc[t] = __builtin_amdgcn_mfma_f32_16x16x32_bf16(af, bf, acc[t], 0, 0, 0);
        }
    }
    __syncthreads();
#pragma unroll
    for (int t = 0; t < 8; ++t)
#pragma unroll
        for (int r = 0; r < 4; ++r) {
            int rl = q * 4 + r;
            int c = ((t * 16 + n) >> 3);
            sA[(wr + rl) * 128 + ((c ^ rl) << 3) + (n & 7)] = f2bf(acc[t][r]);
        }
    __syncthreads();
#pragma unroll
    for (int i = 0; i < 4; ++i) {
        int cth = tid + i * 256;
        int r = cth >> 4, cl = cth & 15;
        int row = rid[r];
        if (row >= 0)
            *(uint4*)(OutB + (size_t)row * D_ + (cl << 3)) =
                *(const uint4*)(sA + r * 128 + ((cl ^ (r & 15)) << 3));
    }
}

// ---------------------------------------------------------------------------
// fused_layer: GEMM1(agg@Dm[pol])+LN+relu -> GEMM2(h@W2^T)+res+LN ->
// [GEMM3(x'@Sn[pol]) unless LAST]. Swizzled LDS + async staging/restaging.
// ---------------------------------------------------------------------------

template <bool LAST>
__global__ __launch_bounds__(256) void fused_layer(
    const unsigned short* __restrict__ agg, const unsigned short* __restrict__ DmAll,
    const unsigned short* __restrict__ W2b, const unsigned short* __restrict__ SnAll,
    const int* __restrict__ blist, const int* __restrict__ boff,
    const int* __restrict__ tileOff, const float* __restrict__ dnorm,
    const float* __restrict__ b1v, const float* __restrict__ g1v,
    const float* __restrict__ e1v, const float* __restrict__ b2v,
    const float* __restrict__ g2v, const float* __restrict__ e2v,
    const float* __restrict__ rs_ptr, const float* __restrict__ xres,
    const float* __restrict__ x0add, float* __restrict__ OutF,
    unsigned short* __restrict__ OutXt) {
    __shared__ unsigned short sB[128 * 128];  // 32768 B (Dm -> W2 -> Sn)
    __shared__ unsigned short sA[64 * 128];   // 16384 B (agg -> h -> x' -> xt)
    __shared__ int rid[TM];
    __shared__ float dnRow[TM];

    int tid = threadIdx.x, b = blockIdx.x;
    if (b >= tileOff[P_]) return;
    int pp = 0;
    while (pp < P_ - 1 && b >= tileOff[pp + 1]) ++pp;
    int tb = b - tileOff[pp];
    int cnt = boff[pp + 1] - boff[pp];
    int nrows = min(TM, cnt - tb * TM);
    int rowbase = boff[pp] + tb * TM;

    if (tid < TM) {
        int r = (tid < nrows) ? blist[rowbase + tid] : -1;
        rid[tid] = r;
        dnRow[tid] = (r >= 0) ? dnorm[r] : 1.f;
    }
    __syncthreads();

    int lane = tid & 63, wave = tid >> 6;
    stage_B_async(DmAll + (size_t)pp * D_ * D_, sB, wave, lane);
    stage_A_async(agg, rid, sA, wave, lane);

    int n = lane & 15, q = lane >> 4, wr = wave * 16;

    int rowid[4];
    float dn4[4];
#pragma unroll
    for (int r = 0; r < 4; ++r) {
        int rr = wr + q * 4 + r;
        rowid[r] = rid[rr];
        dn4[r] = dnRow[rr];
    }

    // residual prefetch (overlaps async staging + GEMM1)
    float xr[8][4];
#pragma unroll
    for (int t = 0; t < 8; ++t) {
        int col = t * 16 + n;
#pragma unroll
        for (int r = 0; r < 4; ++r)
            xr[t][r] = (rowid[r] >= 0) ? xres[(size_t)rowid[r] * D_ + col] : 0.f;
    }
    __syncthreads();  // drains async stages

    // ---- GEMM1: agg @ Dm ----
    f32x4 acc[8];
#pragma unroll
    for (int t = 0; t < 8; ++t) acc[t] = (f32x4){0.f, 0.f, 0.f, 0.f};
#pragma unroll
    for (int kc = 0; kc < 4; ++kc) {
        int cs = (((kc << 2) + q) ^ n) << 3;
        bf16x8 af = *(const bf16x8*)(sA + (wr + n) * 128 + cs);
#pragma unroll
        for (int t = 0; t < 8; ++t) {
            bf16x8 bf = *(const bf16x8*)(sB + (t * 16 + n) * 128 + cs);
            acc[t] = __builtin_amdgcn_mfma_f32_16x16x32_bf16(af, bf, acc[t], 0, 0, 0);
        }
    }

    // ---- LN1 + relu -> h ----
    {
        float rs1[4] = {0, 0, 0, 0}, rs2[4] = {0, 0, 0, 0};
#pragma unroll
        for (int t = 0; t < 8; ++t) {
            int col = t * 16 + n;
            float bia = b1v[col];
#pragma unroll
            for (int r = 0; r < 4; ++r) {
                float v = dn4[r] * acc[t][r] + bia;
                acc[t][r] = v;
                rs1[r] += v;
                rs2[r] += v * v;
            }
        }
#pragma unroll
        for (int mk = 1; mk < 16; mk <<= 1)
#pragma unroll
            for (int r = 0; r < 4; ++r) {
                rs1[r] += __shfl_xor(rs1[r], mk, 64);
                rs2[r] += __shfl_xor(rs2[r], mk, 64);
            }
        float mr[4], rv[4];
#pragma unroll
        for (int r = 0; r < 4; ++r) {
            float mm = rs1[r] * (1.f / 128.f);
            mr[r] = mm;
            rv[r] = rsqrtf(rs2[r] * (1.f / 128.f) - mm * mm + EPS_);
        }
#pragma unroll
        for (int t = 0; t < 8; ++t) {
            int col = t * 16 + n;
            float gg = g1v[col], bbv = e1v[col];
#pragma unroll
            for (int r = 0; r < 4; ++r)
                acc[t][r] = fmaxf((acc[t][r] - mr[r]) * rv[r] * gg + bbv, 0.f);
        }
    }

    __syncthreads();  // all waves done reading sB(Dm) & sA(agg)
    stage_B_async(W2b, sB, wave, lane);  // async restage overlaps transpose
#pragma unroll
    for (int t = 0; t < 8; ++t)
#pragma unroll
        for (int r = 0; r < 4; ++r) {
            int rl = q * 4 + r;
            int c = ((t * 16 + n) >> 3);
            sA[(wr + rl) * 128 + ((c ^ rl) << 3) + (n & 7)] = f2bf(acc[t][r]);
        }
    __syncthreads();  // sB(W2) + h ready

    // ---- GEMM2: h @ W2^T ----
#pragma unroll
    for (int t = 0; t < 8; ++t) acc[t] = (f32x4){0.f, 0.f, 0.f, 0.f};
#pragma unroll
    for (int kc = 0; kc < 4; ++kc) {
        int cs = (((kc << 2) + q) ^ n) << 3;
        bf16x8 af = *(const bf16x8*)(sA + (wr + n) * 128 + cs);
#pragma unroll
        for (int t = 0; t < 8; ++t) {
            bf16x8 bf = *(const bf16x8*)(sB + (t * 16 + n) * 128 + cs);
            acc[t] = __builtin_amdgcn_mfma_f32_16x16x32_bf16(af, bf, acc[t], 0, 0, 0);
        }
    }

    // ---- residual + LN2 -> x' ----
    {
        float rs = rs_ptr[0];
        float rs1[4] = {0, 0, 0, 0}, rs2[4] = {0, 0, 0, 0};
#pragma unroll
        for (int t = 0; t < 8; ++t) {
            int col = t * 16 + n;
            float bia = b2v[col];
#pragma unroll
            for (int r = 0; r < 4; ++r) {
                float v = rs * (acc[t][r] + bia) + xr[t][r];
                acc[t][r] = v;
                rs1[r] += v;
                rs2[r] += v * v;
            }
        }
#pragma unroll
        for (int mk = 1; mk < 16; mk <<= 1)
#pragma unroll
            for (int r = 0; r < 4; ++r) {
                rs1[r] += __shfl_xor(rs1[r], mk, 64);
                rs2[r] += __shfl_xor(rs2[r], mk, 64);
            }
        float mr[4], rv[4];
#pragma unroll
        for (int r = 0; r < 4; ++r) {
            float mm = rs1[r] * (1.f / 128.f);
            mr[r] = mm;
            rv[r] = rsqrtf(rs2[r] * (1.f / 128.f) - mm * mm + EPS_);
        }
#pragma unroll
        for (int t = 0; t < 8; ++t) {
            int col = t * 16 + n;
            float gg = g2v[col], bbv = e2v[col];
#pragma unroll
            for (int r = 0; r < 4; ++r) {
                float nv = (acc[t][r] - mr[r]) * rv[r] * gg + bbv;
                if constexpr (LAST) {
                    if (rowid[r] >= 0) nv += x0add[(size_t)rowid[r] * D_ + col];
                }
                acc[t][r] = nv;
                if (rowid[r] >= 0) OutF[(size_t)rowid[r] * D_ + col] = nv;
            }
        }
    }

    if constexpr (!LAST) {
        __syncthreads();  // all waves done reading sB(W2)
        stage_B_async(SnAll + (size_t)pp * D_ * D_, sB, wave, lane);
#pragma unroll
        for (int t = 0; t < 8; ++t)
#pragma unroll
            for (int r = 0; r < 4; ++r) {
                int rl = q * 4 + r;
                int c = ((t * 16 + n) >> 3);
                sA[(wr + rl) * 128 + ((c ^ rl) << 3) + (n & 7)] = f2bf(acc[t][r]);
            }
        __syncthreads();  // sB(Sn) + x' ready

        // ---- GEMM3: x' @ Sn ----
#pragma unroll
        for (int t = 0; t < 8; ++t) acc[t] = (f32x4){0.f, 0.f, 0.f, 0.f};
#pragma unroll
        for (int kc = 0; kc < 4; ++kc) {
            int cs = (((kc << 2) + q) ^ n) << 3;
            bf16x8 af = *(const bf16x8*)(sA + (wr + n) * 128 + cs);
#pragma unroll
            for (int t = 0; t < 8; ++t) {
                bf16x8 bf = *(const bf16x8*)(sB + (t * 16 + n) * 128 + cs);
                acc[t] = __builtin_amdgcn_mfma_f32_16x16x32_bf16(af, bf, acc[t], 0, 0, 0);
            }
        }
#pragma unroll
        for (int t = 0; t < 8; ++t)
#pragma unroll
            for (int r = 0; r < 4; ++r) {
                int rl = q * 4 + r;
                int c = ((t * 16 + n) >> 3);
                sA[(wr + rl) * 128 + ((c ^ rl) << 3) + (n & 7)] = f2bf(acc[t][r]);
            }
        __syncthreads();
#pragma unroll
        for (int i = 0; i < 4; ++i) {
            int cth = tid + i * 256;
            int r = cth >> 4, cl = cth & 15;
            int row = rid[r];
            if (row >= 0)
                *(uint4*)(OutXt + (size_t)row * D_ + (cl << 3)) =
                    *(const uint4*)(sA + r * 128 + ((cl ^ (r & 15)) << 3));
        }
    }
}

// ---------------------------------------------------------------------------
// Host launch
// ---------------------------------------------------------------------------

extern "C" void kernel_launch(void* const* d_in, const int* in_sizes, int n_in,
                              void* d_out, int out_size, void* d_ws, size_t ws_size,
                              hipStream_t stream) {
    const float* x0 = (const float*)d_in[0];
    const int* ei = (const int*)d_in[1];
    const int* ring = (const int*)d_in[2];
    const float* Wr = (const float*)d_in[3];
    const float* S = (const float*)d_in[4];
    const float* dS = (const float*)d_in[5];
    const float* R = (const float*)d_in[6];
    const float* dR = (const float*)d_in[7];
    const float* rsc = (const float*)d_in[8];
    const float* W1 = (const float*)d_in[9];
    const float* b1 = (const float*)d_in[10];
    const float* lng = (const float*)d_in[11];
    const float* lnb = (const float*)d_in[12];
    const float* W2 = (const float*)d_in[13];
    const float* b2 = (const float*)d_in[14];
    const float* ng = (const float*)d_in[15];
    const float* nb = (const float*)d_in[16];
    float* out = (float*)d_out;

    char* w = (char*)d_ws;
    auto alloc = [&](size_t bytes) {
        char* p = w;
        w += (bytes + 15) & ~(size_t)15;
        return p;
    };
    unsigned short* xb = (unsigned short*)alloc((size_t)(N_ + 1) * D_ * 2);    // bf16 x0 (+zero row)
    unsigned short* bufAb = (unsigned short*)alloc((size_t)(N_ + 1) * D_ * 2); // xt (+zero row)
    unsigned short* bufBb = (unsigned short*)alloc((size_t)(N_ + 1) * D_ * 2); // agg (+zero row)
    float* xbuf = (float*)alloc((size_t)N_ * D_ * 4);                          // fp32 x (in-place)
    unsigned short* Sb = (unsigned short*)alloc((size_t)L_ * P_ * D_ * D_ * 2);
    unsigned short* Dmb = (unsigned short*)alloc((size_t)L_ * P_ * D_ * D_ * 2);
    unsigned short* W2b = (unsigned short*)alloc((size_t)L_ * D_ * D_ * 2);
    unsigned short* Arh = (unsigned short*)alloc((size_t)MAT * 16384 * 2);
    unsigned short* Arl = (unsigned short*)alloc((size_t)MAT * 16384 * 2);
    unsigned short* W1h = (unsigned short*)alloc((size_t)3 * 16384 * 2);
    unsigned short* W1l = (unsigned short*)alloc((size_t)3 * 16384 * 2);
    unsigned short* Wrth = (unsigned short*)alloc((size_t)3 * 16384 * 2);
    unsigned short* Wrtl = (unsigned short*)alloc((size_t)3 * 16384 * 2);
    unsigned short* T1th = (unsigned short*)alloc((size_t)MAT * 16384 * 2);
    unsigned short* T1tl = (unsigned short*)alloc((size_t)MAT * 16384 * 2);
    float* dnorm = (float*)alloc((size_t)N_ * 4);
    int* histG = (int*)alloc((size_t)HTOT * 4);
    unsigned* bufT = (unsigned*)alloc((size_t)E_ * 4);
    unsigned char* bufS8 = (unsigned char*)alloc((size_t)E_);
    unsigned short* eSrc = (unsigned short*)alloc((size_t)E_ * 2);
    int* offT = (int*)alloc((size_t)(N_ + 1) * 4);
    int* pol = (int*)alloc((size_t)N_ * 4);
    int* boff = (int*)alloc((size_t)(P_ + 1) * 4);
    int* tileOff = (int*)alloc((size_t)(P_ + 1) * 4);
    int* blist = (int*)alloc((size_t)N_ * 4);
    int* blkSum = (int*)alloc((size_t)NSB * 4);
    int* blkOff = (int*)alloc((size_t)NSB * 4);
    int* bcnt = (int*)alloc((size_t)2 * P_ * 4);  // zeroed region: bcnt + bcur
    int* bcur = bcnt + P_;

    hipMemsetAsync(bcnt, 0, (size_t)2 * P_ * 4, stream);

    const int BTILES = N_ / TM + P_;  // 790, upper bound on bucketed tiles

    setup_nk<<<NBK, 256, 0, stream>>>(ring, pol, bcnt, ei, histG);
    scanH1<<<NSB, 1024, 0, stream>>>(histG, blkSum);
    scanH2<<<1, 64, 0, stream>>>(blkSum, blkOff, offT, bcnt, boff, tileOff);
    scanH3<<<NSB, 1024, 0, stream>>>(histG, blkOff);
    scatterTS<<<NBK, 256, 0, stream>>>(ei, histG, bufT, bufS8);
    finalize3<<<3 * NBUK, 256, 0, stream>>>(bufT, bufS8, histG, offT, eSrc, dnorm,
                                            pol, boff, bcur, blist);
    prep_all<<<GPREP, 256, 0, stream>>>(x0, xb, bufAb, bufBb, S, dS, Sb, W2, W2b,
                                        R, dR, W1, Wr, Arh, Arl, W1h, W1l, Wrth, Wrtl);
    // T1t[mat][k][i] = sum_j W1[l][k][j] * (R+dR)[mat][i][j]
    small_mfma<false, true, true><<<2 * MAT, 256, 0, stream>>>(
        W1h, W1l, Arh, Arl, T1th, T1tl);
    // Dmb[mat][k][d] = sum_i T1t[mat][k][i] * Wr^T[l][d][i]
    small_mfma<true, false, false><<<2 * MAT, 256, 0, stream>>>(
        T1th, T1tl, Wrth, Wrtl, Dmb, nullptr);

    // layer 0 send-transform: xt0 = x0 @ (S+dS)[0][pol]
    gemm_xt0<<<BTILES, 256, 0, stream>>>(xb, Sb, bufAb, blist, boff, tileOff);

    for (int l = 0; l < L_; ++l) {
        const size_t lPDD = (size_t)l * P_ * D_ * D_;
        const size_t lDD = (size_t)l * D_ * D_;
        const size_t lD = (size_t)l * D_;
        aggregate_bf<<<N_ / 4, 256, 0, stream>>>(bufAb, offT, eSrc, bufBb);
        const float* xr = (l == 0) ? x0 : xbuf;
        if (l < L_ - 1) {
            fused_layer<false><<<BTILES, 256, 0, stream>>>(
                bufBb, Dmb + lPDD, W2b + lDD, Sb + lPDD + (size_t)P_ * D_ * D_,
                blist, boff, tileOff, dnorm,
                b1 + lD, lng + lD, lnb + lD, b2 + lD, ng + lD, nb + lD,
                rsc + l, xr, nullptr, xbuf, bufAb);
        } else {
            fused_layer<true><<<BTILES, 256, 0, stream>>>(
                bufBb, Dmb + lPDD, W2b + lDD, nullptr,
                blist, boff, tileOff, dnorm,
                b1 + lD, lng + lD, lnb + lD, b2 + lD, ng + lD, nb + lD,
                rsc + l, xr, x0, out, nullptr);
        }
    }
}